// Round 1
// baseline (6347.806 us; speedup 1.0000x reference)
//
#include <hip/hip_runtime.h>
#include <math.h>

// Problem constants
constexpr int kB   = 2;
constexpr int kT   = 2048;
constexpr int kD   = 1024;
constexpr int kH   = 16;    // heads
constexpr int kNH  = 3;     // delta-product sub-steps per token
constexpr int kC   = 64;    // chunk size
constexpr int kNc  = 32;    // T / C
constexpr int kLVL = 16;    // levels allocated
constexpr int kLU  = 6;     // levels actually reachable: max ctz(i+1), i<32 -> 5, so 0..5
constexpr int kM   = kB * kT;   // 4096 rows
constexpr int kGK  = 1024;      // K of every GEMM here

// ---------------------------------------------------------------------------
// f32 NT-GEMM: C[m,n] = act( sum_d A[m,d] * W[n,d] )
// A: (M, 1024) row-major, W: (N, 1024) row-major. 128x128 tile, BK=16, 8x8/thread.
// LDS stored transposed As[k][r] with XOR swizzle on row bits 2-3 so both the
// scalar stores and the ds_read_b128 fragment reads avoid systematic conflicts.
// MODE: 0 none, 1 silu, 2 sigmoid, 4 softplus(Lp[n]*x)
// ---------------------------------------------------------------------------
template <int MODE>
__global__ __launch_bounds__(256) void gemm_nt(const float* __restrict__ A,
                                               const float* __restrict__ W,
                                               float* __restrict__ Cmat,
                                               int M, int N,
                                               const float* __restrict__ Lp) {
  __shared__ float As[16][128];
  __shared__ float Bs[16][128];
  const int tid = threadIdx.x;
  const int bm = blockIdx.y * 128, bn = blockIdx.x * 128;
  const int lr = tid >> 2;          // 0..63  (load row)
  const int lc = (tid & 3) << 2;    // 0,4,8,12 (load col group)
  const int ty = tid >> 4, tx = tid & 15;

  float acc[8][8];
#pragma unroll
  for (int i = 0; i < 8; i++)
#pragma unroll
    for (int j = 0; j < 8; j++) acc[i][j] = 0.f;

  const float4 f4z = make_float4(0.f, 0.f, 0.f, 0.f);

  for (int k0 = 0; k0 < kGK; k0 += 16) {
    const int ra0 = bm + lr, ra1 = bm + lr + 64;
    const int rb0 = bn + lr, rb1 = bn + lr + 64;
    float4 a0 = (ra0 < M) ? *(const float4*)(A + (size_t)ra0 * kGK + k0 + lc) : f4z;
    float4 a1 = (ra1 < M) ? *(const float4*)(A + (size_t)ra1 * kGK + k0 + lc) : f4z;
    float4 b0 = (rb0 < N) ? *(const float4*)(W + (size_t)rb0 * kGK + k0 + lc) : f4z;
    float4 b1 = (rb1 < N) ? *(const float4*)(W + (size_t)rb1 * kGK + k0 + lc) : f4z;

    __syncthreads();  // previous iteration's readers done
#pragma unroll
    for (int i = 0; i < 4; i++) {
      const int kk = lc + i;
      const int sw = ((kk >> 2) & 3) << 2;
      As[kk][(lr)      ^ sw] = ((const float*)&a0)[i];
      As[kk][(lr + 64) ^ sw] = ((const float*)&a1)[i];
      Bs[kk][(lr)      ^ sw] = ((const float*)&b0)[i];
      Bs[kk][(lr + 64) ^ sw] = ((const float*)&b1)[i];
    }
    __syncthreads();

#pragma unroll
    for (int kk = 0; kk < 16; kk++) {
      const int sw = ((kk >> 2) & 3) << 2;
      float4 av0 = *(const float4*)&As[kk][(ty * 8)     ^ sw];
      float4 av1 = *(const float4*)&As[kk][(ty * 8 + 4) ^ sw];
      float4 bv0 = *(const float4*)&Bs[kk][(tx * 8)     ^ sw];
      float4 bv1 = *(const float4*)&Bs[kk][(tx * 8 + 4) ^ sw];
      float a[8]  = {av0.x, av0.y, av0.z, av0.w, av1.x, av1.y, av1.z, av1.w};
      float bb[8] = {bv0.x, bv0.y, bv0.z, bv0.w, bv1.x, bv1.y, bv1.z, bv1.w};
#pragma unroll
      for (int i = 0; i < 8; i++)
#pragma unroll
        for (int j = 0; j < 8; j++) acc[i][j] = fmaf(a[i], bb[j], acc[i][j]);
    }
  }

#pragma unroll
  for (int i = 0; i < 8; i++) {
    const int r = bm + ty * 8 + i;
    if (r >= M) continue;
#pragma unroll
    for (int j = 0; j < 8; j++) {
      const int c = bn + tx * 8 + j;
      if (c >= N) continue;
      float vx = acc[i][j];
      if (MODE == 1) {                 // silu
        vx = vx / (1.f + expf(-vx));
      } else if (MODE == 2) {          // sigmoid
        vx = 1.f / (1.f + expf(-vx));
      } else if (MODE == 4) {          // softplus(Lp*x), numerically stable
        float y = Lp[c] * vx;
        vx = fmaxf(y, 0.f) + log1pf(expf(-fabsf(y)));
      }
      Cmat[(size_t)r * N + c] = vx;
    }
  }
}

// ---------------------------------------------------------------------------
// lwc = mean over the 64 tokens of each chunk of lw (B,T,H,16) -> (B,Nc,H,16)
// ---------------------------------------------------------------------------
__global__ void lwc_mean(const float* __restrict__ lw, float* __restrict__ lwc) {
  const int idx = blockIdx.x * 256 + threadIdx.x;  // ((b*32+c)*16+h)*16+l
  if (idx >= kB * kNc * kH * kLVL) return;
  const int l = idx & 15;
  const int h = (idx >> 4) & 15;
  const int c = (idx >> 8) & 31;
  const int b = idx >> 13;
  size_t base = ((size_t)b * kT + (size_t)c * kC) * 256 + h * 16 + l;
  float s = 0.f;
  for (int tt = 0; tt < kC; tt++) s += lw[base + (size_t)tt * 256];
  lwc[idx] = s * (1.f / 64.f);
}

// ---------------------------------------------------------------------------
// Sequential gated delta-product recurrence. One block per (b,h).
// 256 threads = 4 waves; wave w owns k-rows [16w,16w+16), lane owns v-column.
// State S[k][v] lives in registers: s[16] per thread.
// Hierarchical level states (only levels 0..5 are ever non-zero) in global ws.
// dec[] holds sigmoid(x@Wa) == exp(log_sigmoid(x@Wa)) (the per-token decay).
// ---------------------------------------------------------------------------
__global__ __launch_bounds__(256) void recurrence(
    const float* __restrict__ q, const float* __restrict__ k,
    const float* __restrict__ v, const float* __restrict__ bet,
    const float* __restrict__ dec, const float* __restrict__ lwc,
    float* __restrict__ states, float* __restrict__ o) {
  const int bh = blockIdx.x;
  const int b = bh >> 4, h = bh & 15;
  const int tid = threadIdx.x;
  const int w = tid >> 6, lane = tid & 63;

  __shared__ float tok[452];        // [0,64)=q [64,256)=k [256,448)=v [448,451)=beta [451]=dec
  __shared__ float kSp[2][4][64];   // double-buffered per-wave partial sums

  const size_t stStride = (size_t)kH * 4096;  // one level stride
  float* st = states + ((size_t)b * kLVL * kH + h) * 4096;

  float s[16];

  // zero the reachable levels of our (b,h) slice (ws is poisoned, not zeroed)
  for (int l = 0; l < kLU; l++) {
#pragma unroll
    for (int kk = 0; kk < 16; kk++)
      st[l * stStride + (size_t)(w * 16 + kk) * 64 + lane] = 0.f;
  }

  for (int c = 0; c < kNc; c++) {
    // S0 = sum_l lw[l] * states[l]
    const float* lwp = lwc + ((size_t)(b * kNc + c) * kH + h) * 16;
#pragma unroll
    for (int kk = 0; kk < 16; kk++) s[kk] = 0.f;
    for (int l = 0; l < kLU; l++) {
      const float lwv = lwp[l];
#pragma unroll
      for (int kk = 0; kk < 16; kk++)
        s[kk] = fmaf(lwv, st[l * stStride + (size_t)(w * 16 + kk) * 64 + lane], s[kk]);
    }

    for (int tt = 0; tt < kC; tt++) {
      const size_t m = (size_t)b * kT + (size_t)c * kC + tt;
      __syncthreads();  // protect tok/kSp from previous token's readers
      for (int i = tid; i < 452; i += 256) {
        float val;
        if (i < 64)        val = q[m * 1024 + h * 64 + i];
        else if (i < 256)  val = k[m * 3072 + h * 192 + (i - 64)];
        else if (i < 448)  val = v[m * 3072 + h * 192 + (i - 256)];
        else if (i < 451)  val = bet[m * 48 + h * 3 + (i - 448)];
        else               val = dec[m * 16 + h];
        tok[i] = val;
      }
      __syncthreads();

      const float eg = tok[451];
#pragma unroll
      for (int kk = 0; kk < 16; kk++) s[kk] *= eg;

#pragma unroll
      for (int j = 0; j < kNH; j++) {
        float p = 0.f;
#pragma unroll
        for (int kk = 0; kk < 16; kk++)
          p = fmaf(tok[64 + (w * 16 + kk) * 3 + j], s[kk], p);
        kSp[j & 1][w][lane] = p;
        __syncthreads();
        const float kS = kSp[j & 1][0][lane] + kSp[j & 1][1][lane] +
                         kSp[j & 1][2][lane] + kSp[j & 1][3][lane];
        const float coef = tok[448 + j] * (tok[256 + lane * 3 + j] - kS);
#pragma unroll
        for (int kk = 0; kk < 16; kk++)
          s[kk] = fmaf(tok[64 + (w * 16 + kk) * 3 + j], coef, s[kk]);
      }

      // o[v] = q . S[:,v]
      float p = 0.f;
#pragma unroll
      for (int kk = 0; kk < 16; kk++) p = fmaf(tok[w * 16 + kk], s[kk], p);
      kSp[1][w][lane] = p;  // j-loop ended on buffer 0; use buffer 1
      __syncthreads();
      if (w == 0) {
        const float ov = kSp[1][0][lane] + kSp[1][1][lane] +
                         kSp[1][2][lane] + kSp[1][3][lane];
        o[m * 1024 + h * 64 + lane] = ov;
      }
    }

    // level merge: lev = ctz(c+1); merged = Sf + sum_{l<lev} st[l];
    // st[lev] = merged; st[l<lev] = 0; st[l>lev] unchanged.
    const int lev = __builtin_ctz(c + 1);
    for (int l = 0; l < lev; l++) {
#pragma unroll
      for (int kk = 0; kk < 16; kk++) {
        const size_t idx = l * stStride + (size_t)(w * 16 + kk) * 64 + lane;
        s[kk] += st[idx];
        st[idx] = 0.f;
      }
    }
#pragma unroll
    for (int kk = 0; kk < 16; kk++)
      st[lev * stStride + (size_t)(w * 16 + kk) * 64 + lane] = s[kk];
  }
}

// ---------------------------------------------------------------------------
// GroupNorm stats per (b,h) over (HEAD_V, T) = 131072 elements of o
// ---------------------------------------------------------------------------
__global__ __launch_bounds__(256) void gn_stats(const float* __restrict__ o,
                                                float* __restrict__ stats) {
  const int bh = blockIdx.x;
  const int b = bh >> 4, h = bh & 15;
  double sum = 0.0, sumsq = 0.0;
  for (int idx = threadIdx.x; idx < kT * 64; idx += 256) {
    const int t = idx >> 6, vv = idx & 63;
    const float val = o[((size_t)b * kT + t) * 1024 + h * 64 + vv];
    sum += val;
    sumsq += (double)val * val;
  }
  __shared__ double sred[256], qred[256];
  sred[threadIdx.x] = sum;
  qred[threadIdx.x] = sumsq;
  __syncthreads();
  for (int stp = 128; stp > 0; stp >>= 1) {
    if (threadIdx.x < stp) {
      sred[threadIdx.x] += sred[threadIdx.x + stp];
      qred[threadIdx.x] += qred[threadIdx.x + stp];
    }
    __syncthreads();
  }
  if (threadIdx.x == 0) {
    const double n = (double)kT * 64.0;
    const double mu = sred[0] / n;
    const double var = qred[0] / n - mu * mu;
    stats[bh * 2]     = (float)mu;
    stats[bh * 2 + 1] = (float)(1.0 / sqrt(var + 1e-5));
  }
}

// ---------------------------------------------------------------------------
// z = ((o - mu)*rstd*gamma + beta) * sigmoid(og)
// ---------------------------------------------------------------------------
__global__ void gate_kernel(const float* __restrict__ o, const float* __restrict__ og,
                            const float* __restrict__ gamma, const float* __restrict__ gbeta,
                            const float* __restrict__ stats, float* __restrict__ z) {
  const size_t idx = (size_t)blockIdx.x * 256 + threadIdx.x;
  if (idx >= (size_t)kM * 1024) return;
  const int cidx = (int)(idx & 1023);
  const int h = cidx >> 6;
  const size_t m = idx >> 10;
  const int b = (int)(m >> 11);  // m / kT
  const float mu = stats[(b * 16 + h) * 2];
  const float rstd = stats[(b * 16 + h) * 2 + 1];
  const float val = (o[idx] - mu) * rstd * gamma[cidx] + gbeta[cidx];
  const float gt = og[idx];
  z[idx] = val * (1.f / (1.f + expf(-gt)));
}

// ---------------------------------------------------------------------------
extern "C" void kernel_launch(void* const* d_in, const int* in_sizes, int n_in,
                              void* d_out, int out_size, void* d_ws, size_t ws_size,
                              hipStream_t stream) {
  const float* x     = (const float*)d_in[0];
  // d_in[1]=cos, d_in[2]=sin: unused by the reference forward
  const float* Wq    = (const float*)d_in[3];
  const float* Wk    = (const float*)d_in[4];
  const float* Wv    = (const float*)d_in[5];
  const float* Wb    = (const float*)d_in[6];
  const float* Wa    = (const float*)d_in[7];
  const float* Wg    = (const float*)d_in[8];
  const float* Wo    = (const float*)d_in[9];
  const float* Wl    = (const float*)d_in[10];
  const float* Lp    = (const float*)d_in[11];
  const float* gamma = (const float*)d_in[12];
  const float* gbeta = (const float*)d_in[13];
  float* out = (float*)d_out;

  float* ws = (float*)d_ws;
  size_t off = 0;
  float* qb   = ws + off; off += (size_t)kM * 1024;
  float* kb   = ws + off; off += (size_t)kM * 3072;
  float* vb   = ws + off; off += (size_t)kM * 3072;
  float* betb = ws + off; off += (size_t)kM * 48;
  float* decb = ws + off; off += (size_t)kM * 16;
  float* ogb  = ws + off; off += (size_t)kM * 1024;
  float* lwb  = ws + off; off += (size_t)kM * 256;
  float* lwcb = ws + off; off += (size_t)kB * kNc * kH * kLVL;
  float* stb  = ws + off; off += (size_t)kB * kLVL * kH * 4096;
  float* ob   = ws + off; off += (size_t)kM * 1024;
  float* zb   = ws + off; off += (size_t)kM * 1024;
  float* statb= ws + off; off += 64;
  (void)ws_size;  // ~181.5 MB of float scratch used

  const dim3 blk(256);
  const int mt = kM / 128;  // 32 M-tiles

  // Projections
  gemm_nt<0><<<dim3(1024 / 128, mt), blk, 0, stream>>>(x, Wq, qb, kM, 1024, nullptr);
  gemm_nt<1><<<dim3(3072 / 128, mt), blk, 0, stream>>>(x, Wk, kb, kM, 3072, nullptr);
  gemm_nt<1><<<dim3(3072 / 128, mt), blk, 0, stream>>>(x, Wv, vb, kM, 3072, nullptr);
  gemm_nt<2><<<dim3(1, mt),          blk, 0, stream>>>(x, Wb, betb, kM, 48, nullptr);
  gemm_nt<2><<<dim3(1, mt),          blk, 0, stream>>>(x, Wa, decb, kM, 16, nullptr);  // sigmoid == exp(logsigmoid)
  gemm_nt<0><<<dim3(1024 / 128, mt), blk, 0, stream>>>(x, Wg, ogb, kM, 1024, nullptr);
  gemm_nt<4><<<dim3(2, mt),          blk, 0, stream>>>(x, Wl, lwb, kM, 256, Lp);

  // chunk-mean of level weights
  lwc_mean<<<dim3((kB * kNc * kH * kLVL + 255) / 256), blk, 0, stream>>>(lwb, lwcb);

  // sequential recurrence (one block per (b,h))
  recurrence<<<dim3(kB * kH), blk, 0, stream>>>(qb, kb, vb, betb, decb, lwcb, stb, ob);

  // group norm + gate
  gn_stats<<<dim3(kB * kH), blk, 0, stream>>>(ob, statb);
  gate_kernel<<<dim3((kM * 1024 + 255) / 256), blk, 0, stream>>>(ob, ogb, gamma, gbeta, statb, zb);

  // final projection
  gemm_nt<0><<<dim3(1024 / 128, mt), blk, 0, stream>>>(zb, Wo, out, kM, 1024, nullptr);
}

// Round 2
// 4036.228 us; speedup vs baseline: 1.5727x; 1.5727x over previous
//
#include <hip/hip_runtime.h>
#include <hip/hip_bf16.h>
#include <math.h>

// Problem constants
constexpr int kB   = 2;
constexpr int kT   = 2048;
constexpr int kH   = 16;    // heads
constexpr int kNH  = 3;     // delta-product sub-steps per token
constexpr int kC   = 64;    // chunk size
constexpr int kNc  = 32;    // T / C
constexpr int kLVL = 16;    // levels allocated
constexpr int kLU  = 6;     // levels reachable (max ctz(i+1), i<32 -> 5)
constexpr int kM   = kB * kT;   // 4096 rows
constexpr int kK   = 1024;      // K of every GEMM here

using bf16x8 = __attribute__((ext_vector_type(8))) short;  // 8 bf16 (4 VGPRs)
using f32x4  = __attribute__((ext_vector_type(4))) float;

__device__ __forceinline__ void glds16(const void* g, void* l) {
  __builtin_amdgcn_global_load_lds(
      (const __attribute__((address_space(1))) unsigned int*)g,
      (__attribute__((address_space(3))) unsigned int*)l, 16, 0, 0);
}

// ---------------------------------------------------------------------------
// bf16 MFMA NT-GEMM: C[m,n] = act( sum_k A[m,k] * W[n,k] ), K = 1024.
// A (M,1024) bf16 row-major, W (N,1024) bf16 row-major (i.e. B^T layout).
// 128x128 tile, BK=32, 4 waves in 2x2, each wave 64x64 via 4x4 16x16x32 frags.
// Staging: global_load_lds width=16, linear LDS dest; the XOR chunk swizzle
// (chunk ^= (row>>1)&3) is applied to the GLOBAL source address and to the
// ds_read_b128 fragment reads (both-sides swizzle, m173/m201 pattern), which
// spreads the 16 rows of a fragment read across 8 bank slots (~2-way, free).
// MODE: 0 none, 1 silu, 3 split sigmoid (cols<48 -> Cmat[48], cols 48..63 ->
// C2[16], rest dropped), 4 softplus(Lp[n]*x)
// ---------------------------------------------------------------------------
template <int MODE>
__global__ __launch_bounds__(256) void gemm_bf16(
    const __hip_bfloat16* __restrict__ A, const __hip_bfloat16* __restrict__ W,
    float* __restrict__ Cmat, float* __restrict__ C2, int N,
    const float* __restrict__ Lp) {
  __shared__ __hip_bfloat16 As[128 * 32];
  __shared__ __hip_bfloat16 Bs[128 * 32];
  const int tid = threadIdx.x;
  const int w = tid >> 6, lane = tid & 63;
  const int bm = blockIdx.y * 128, bn = blockIdx.x * 128;

  // staging: thread -> (row sr / sr+64, physical 16B chunk sp); the data the
  // read expects at physical chunk p of row r is logical chunk p ^ ((r>>1)&3).
  // Note ((sr+64)>>1)&3 == (sr>>1)&3, so one g0 serves both halves.
  const int sr = tid >> 2, sp = tid & 3;
  const int g0 = sp ^ ((sr >> 1) & 3);
  const __hip_bfloat16* a0 = A + (size_t)(bm + sr) * kK + g0 * 8;
  const __hip_bfloat16* a1 = A + (size_t)(bm + sr + 64) * kK + g0 * 8;
  const __hip_bfloat16* b0 = W + (size_t)(bn + sr) * kK + g0 * 8;
  const __hip_bfloat16* b1 = W + (size_t)(bn + sr + 64) * kK + g0 * 8;
  char* AsB = (char*)As + w * 1024;  // wave-uniform LDS dest (+ lane*16 in HW)
  char* BsB = (char*)Bs + w * 1024;

  // fragment read byte offsets. A-frag (16x16x32): lane holds row (lane&15),
  // k-chunk (lane>>4)*8; B-frag: col (lane&15), same k-chunk.
  const int wr = w >> 1, wc = w & 1;
  const int fr = lane & 15, fc = lane >> 4;
  int aOff[4], bOff[4];
#pragma unroll
  for (int f = 0; f < 4; f++) {
    const int ra = wr * 64 + f * 16 + fr;
    aOff[f] = ra * 64 + ((fc ^ ((ra >> 1) & 3)) * 16);
    const int rb = wc * 64 + f * 16 + fr;
    bOff[f] = rb * 64 + ((fc ^ ((rb >> 1) & 3)) * 16);
  }

  f32x4 acc[4][4];
#pragma unroll
  for (int i = 0; i < 4; i++)
#pragma unroll
    for (int j = 0; j < 4; j++) acc[i][j] = (f32x4){0.f, 0.f, 0.f, 0.f};

  for (int k0 = 0; k0 < kK; k0 += 32) {
    __syncthreads();  // previous iteration's ds_reads done before overwrite
    glds16(a0 + k0, AsB);
    glds16(a1 + k0, AsB + 4096);
    glds16(b0 + k0, BsB);
    glds16(b1 + k0, BsB + 4096);
    __syncthreads();  // drains vmcnt(0): staged data visible

    bf16x8 af[4], bfr[4];
#pragma unroll
    for (int f = 0; f < 4; f++) af[f] = *(const bf16x8*)((const char*)As + aOff[f]);
#pragma unroll
    for (int f = 0; f < 4; f++) bfr[f] = *(const bf16x8*)((const char*)Bs + bOff[f]);
#pragma unroll
    for (int i = 0; i < 4; i++)
#pragma unroll
      for (int j = 0; j < 4; j++)
        acc[i][j] = __builtin_amdgcn_mfma_f32_16x16x32_bf16(af[i], bfr[j], acc[i][j], 0, 0, 0);
  }

  // C/D layout: col = lane&15, row = (lane>>4)*4 + e  [m89 verified]
  const int r0 = bm + wr * 64, c0 = bn + wc * 64;
#pragma unroll
  for (int i = 0; i < 4; i++)
#pragma unroll
    for (int j = 0; j < 4; j++)
#pragma unroll
      for (int e = 0; e < 4; e++) {
        const int rr = r0 + i * 16 + fc * 4 + e;
        const int cc = c0 + j * 16 + fr;
        float vx = acc[i][j][e];
        if constexpr (MODE == 1) {            // silu
          vx = vx / (1.f + expf(-vx));
        }
        if constexpr (MODE == 4) {            // softplus(Lp*x)
          const float y = Lp[cc] * vx;
          vx = fmaxf(y, 0.f) + log1pf(expf(-fabsf(y)));
        }
        if constexpr (MODE == 3) {            // beta (48) + dec (16), sigmoid
          const float s = 1.f / (1.f + expf(-vx));
          if (cc < 48)       Cmat[(size_t)rr * 48 + cc] = s;
          else if (cc < 64)  C2[(size_t)rr * 16 + (cc - 48)] = s;
        } else {
          Cmat[(size_t)rr * N + cc] = vx;
        }
      }
}

// ---------------------------------------------------------------------------
// f32 -> bf16 cast (n multiple of 4)
// ---------------------------------------------------------------------------
__global__ void cast_bf16(const float* __restrict__ in, __hip_bfloat16* __restrict__ out, int n) {
  const int i = (blockIdx.x * 256 + threadIdx.x) * 4;
  if (i >= n) return;
  const float4 v = *(const float4*)(in + i);
  __hip_bfloat16 tmp[4] = {__float2bfloat16(v.x), __float2bfloat16(v.y),
                           __float2bfloat16(v.z), __float2bfloat16(v.w)};
  *(ushort4*)(out + i) = *(ushort4*)tmp;
}

// Combined beta/dec weight tile: rows 0..47 = Wb, 48..63 = Wa, 64..127 = 0
__global__ void cast_bd(const float* __restrict__ Wb, const float* __restrict__ Wa,
                        __hip_bfloat16* __restrict__ out) {
  const int idx = blockIdx.x * 256 + threadIdx.x;  // 128*1024
  if (idx >= 128 * 1024) return;
  const int r = idx >> 10, k = idx & 1023;
  const float val = (r < 48) ? Wb[r * 1024 + k] : ((r < 64) ? Wa[(r - 48) * 1024 + k] : 0.f);
  out[idx] = __float2bfloat16(val);
}

// ---------------------------------------------------------------------------
// lwc = mean over the 64 tokens of each chunk of lw (B,T,H,16) -> (B,Nc,H,16)
// ---------------------------------------------------------------------------
__global__ void lwc_mean(const float* __restrict__ lw, float* __restrict__ lwc) {
  const int idx = blockIdx.x * 256 + threadIdx.x;  // ((b*32+c)*16+h)*16+l
  if (idx >= kB * kNc * kH * kLVL) return;
  const int l = idx & 15;
  const int h = (idx >> 4) & 15;
  const int c = (idx >> 8) & 31;
  const int b = idx >> 13;
  size_t base = ((size_t)b * kT + (size_t)c * kC) * 256 + h * 16 + l;
  float s = 0.f;
  for (int tt = 0; tt < kC; tt++) s += lw[base + (size_t)tt * 256];
  lwc[idx] = s * (1.f / 64.f);
}

// ---------------------------------------------------------------------------
// Sequential gated delta-product recurrence (unchanged from round 1, verified).
// One block per (b,h); 4 waves; wave w owns k-rows [16w,16w+16), lane = v-col.
// ---------------------------------------------------------------------------
__global__ __launch_bounds__(256) void recurrence(
    const float* __restrict__ q, const float* __restrict__ k,
    const float* __restrict__ v, const float* __restrict__ bet,
    const float* __restrict__ dec, const float* __restrict__ lwc,
    float* __restrict__ states, float* __restrict__ o) {
  const int bh = blockIdx.x;
  const int b = bh >> 4, h = bh & 15;
  const int tid = threadIdx.x;
  const int w = tid >> 6, lane = tid & 63;

  __shared__ float tok[452];        // [0,64)=q [64,256)=k [256,448)=v [448,451)=beta [451]=dec
  __shared__ float kSp[2][4][64];   // double-buffered per-wave partial sums

  const size_t stStride = (size_t)kH * 4096;
  float* st = states + ((size_t)b * kLVL * kH + h) * 4096;

  float s[16];

  for (int l = 0; l < kLU; l++) {
#pragma unroll
    for (int kk = 0; kk < 16; kk++)
      st[l * stStride + (size_t)(w * 16 + kk) * 64 + lane] = 0.f;
  }

  for (int c = 0; c < kNc; c++) {
    const float* lwp = lwc + ((size_t)(b * kNc + c) * kH + h) * 16;
#pragma unroll
    for (int kk = 0; kk < 16; kk++) s[kk] = 0.f;
    for (int l = 0; l < kLU; l++) {
      const float lwv = lwp[l];
#pragma unroll
      for (int kk = 0; kk < 16; kk++)
        s[kk] = fmaf(lwv, st[l * stStride + (size_t)(w * 16 + kk) * 64 + lane], s[kk]);
    }

    for (int tt = 0; tt < kC; tt++) {
      const size_t m = (size_t)b * kT + (size_t)c * kC + tt;
      __syncthreads();
      for (int i = tid; i < 452; i += 256) {
        float val;
        if (i < 64)        val = q[m * 1024 + h * 64 + i];
        else if (i < 256)  val = k[m * 3072 + h * 192 + (i - 64)];
        else if (i < 448)  val = v[m * 3072 + h * 192 + (i - 256)];
        else if (i < 451)  val = bet[m * 48 + h * 3 + (i - 448)];
        else               val = dec[m * 16 + h];
        tok[i] = val;
      }
      __syncthreads();

      const float eg = tok[451];
#pragma unroll
      for (int kk = 0; kk < 16; kk++) s[kk] *= eg;

#pragma unroll
      for (int j = 0; j < kNH; j++) {
        float p = 0.f;
#pragma unroll
        for (int kk = 0; kk < 16; kk++)
          p = fmaf(tok[64 + (w * 16 + kk) * 3 + j], s[kk], p);
        kSp[j & 1][w][lane] = p;
        __syncthreads();
        const float kS = kSp[j & 1][0][lane] + kSp[j & 1][1][lane] +
                         kSp[j & 1][2][lane] + kSp[j & 1][3][lane];
        const float coef = tok[448 + j] * (tok[256 + lane * 3 + j] - kS);
#pragma unroll
        for (int kk = 0; kk < 16; kk++)
          s[kk] = fmaf(tok[64 + (w * 16 + kk) * 3 + j], coef, s[kk]);
      }

      float p = 0.f;
#pragma unroll
      for (int kk = 0; kk < 16; kk++) p = fmaf(tok[w * 16 + kk], s[kk], p);
      kSp[1][w][lane] = p;
      __syncthreads();
      if (w == 0) {
        const float ov = kSp[1][0][lane] + kSp[1][1][lane] +
                         kSp[1][2][lane] + kSp[1][3][lane];
        o[m * 1024 + h * 64 + lane] = ov;
      }
    }

    const int lev = __builtin_ctz(c + 1);
    for (int l = 0; l < lev; l++) {
#pragma unroll
      for (int kk = 0; kk < 16; kk++) {
        const size_t idx = l * stStride + (size_t)(w * 16 + kk) * 64 + lane;
        s[kk] += st[idx];
        st[idx] = 0.f;
      }
    }
#pragma unroll
    for (int kk = 0; kk < 16; kk++)
      st[lev * stStride + (size_t)(w * 16 + kk) * 64 + lane] = s[kk];
  }
}

// ---------------------------------------------------------------------------
// GroupNorm stats per (b,h) over (HEAD_V, T)
// ---------------------------------------------------------------------------
__global__ __launch_bounds__(256) void gn_stats(const float* __restrict__ o,
                                                float* __restrict__ stats) {
  const int bh = blockIdx.x;
  const int b = bh >> 4, h = bh & 15;
  double sum = 0.0, sumsq = 0.0;
  for (int idx = threadIdx.x; idx < kT * 64; idx += 256) {
    const int t = idx >> 6, vv = idx & 63;
    const float val = o[((size_t)b * kT + t) * 1024 + h * 64 + vv];
    sum += val;
    sumsq += (double)val * val;
  }
  __shared__ double sred[256], qred[256];
  sred[threadIdx.x] = sum;
  qred[threadIdx.x] = sumsq;
  __syncthreads();
  for (int stp = 128; stp > 0; stp >>= 1) {
    if (threadIdx.x < stp) {
      sred[threadIdx.x] += sred[threadIdx.x + stp];
      qred[threadIdx.x] += qred[threadIdx.x + stp];
    }
    __syncthreads();
  }
  if (threadIdx.x == 0) {
    const double n = (double)kT * 64.0;
    const double mu = sred[0] / n;
    const double var = qred[0] / n - mu * mu;
    stats[bh * 2]     = (float)mu;
    stats[bh * 2 + 1] = (float)(1.0 / sqrt(var + 1e-5));
  }
}

// ---------------------------------------------------------------------------
// z = ((o - mu)*rstd*gamma + beta) * sigmoid(og), written as bf16 for out-proj
// ---------------------------------------------------------------------------
__global__ void gate_kernel(const float* __restrict__ o, const float* __restrict__ og,
                            const float* __restrict__ gamma, const float* __restrict__ gbeta,
                            const float* __restrict__ stats, __hip_bfloat16* __restrict__ z) {
  const size_t idx = (size_t)blockIdx.x * 256 + threadIdx.x;
  if (idx >= (size_t)kM * 1024) return;
  const int cidx = (int)(idx & 1023);
  const int h = cidx >> 6;
  const size_t m = idx >> 10;
  const int b = (int)(m >> 11);
  const float mu = stats[(b * 16 + h) * 2];
  const float rstd = stats[(b * 16 + h) * 2 + 1];
  const float val = (o[idx] - mu) * rstd * gamma[cidx] + gbeta[cidx];
  const float gt = og[idx];
  z[idx] = __float2bfloat16(val * (1.f / (1.f + expf(-gt))));
}

// ---------------------------------------------------------------------------
extern "C" void kernel_launch(void* const* d_in, const int* in_sizes, int n_in,
                              void* d_out, int out_size, void* d_ws, size_t ws_size,
                              hipStream_t stream) {
  const float* x     = (const float*)d_in[0];
  // d_in[1]=cos, d_in[2]=sin: unused by the reference forward
  const float* Wq    = (const float*)d_in[3];
  const float* Wk    = (const float*)d_in[4];
  const float* Wv    = (const float*)d_in[5];
  const float* Wb    = (const float*)d_in[6];
  const float* Wa    = (const float*)d_in[7];
  const float* Wg    = (const float*)d_in[8];
  const float* Wo    = (const float*)d_in[9];
  const float* Wl    = (const float*)d_in[10];
  const float* Lp    = (const float*)d_in[11];
  const float* gamma = (const float*)d_in[12];
  const float* gbeta = (const float*)d_in[13];
  float* out = (float*)d_out;

  float* ws = (float*)d_ws;
  size_t off = 0;
  auto alloc = [&](size_t n) { float* p = ws + off; off += n; return p; };
  float* qb    = alloc((size_t)kM * 1024);
  float* kb    = alloc((size_t)kM * 3072);
  float* vb    = alloc((size_t)kM * 3072);
  float* betb  = alloc((size_t)kM * 48);
  float* decb  = alloc((size_t)kM * 16);
  float* lwb   = alloc((size_t)kM * 256);
  float* lwcb  = alloc((size_t)kB * kNc * kH * kLVL);
  float* stb   = alloc((size_t)kB * kLVL * kH * 4096);
  float* ob    = alloc((size_t)kM * 1024);
  float* statb = alloc(64);

  __hip_bfloat16* bfp = (__hip_bfloat16*)(ws + off);
  size_t boff = 0;
  auto balloc = [&](size_t n) { __hip_bfloat16* p = bfp + boff; boff += n; return p; };
  __hip_bfloat16* xb   = balloc((size_t)kM * 1024);
  __hip_bfloat16* Wqb  = balloc((size_t)1024 * 1024);
  __hip_bfloat16* Wkb  = balloc((size_t)3072 * 1024);
  __hip_bfloat16* Wvb  = balloc((size_t)3072 * 1024);
  __hip_bfloat16* Wgb  = balloc((size_t)1024 * 1024);
  __hip_bfloat16* Wlb  = balloc((size_t)256 * 1024);
  __hip_bfloat16* Wob  = balloc((size_t)1024 * 1024);
  __hip_bfloat16* Wbdb = balloc((size_t)128 * 1024);
  (void)ws_size;  // ~176 MB used (round-1 proved >= 181 MB available)

  // buffers dead after the recurrence, reused:
  float* ogb = kb;
  __hip_bfloat16* zbf = (__hip_bfloat16*)vb;

  const dim3 blk(256);

  // casts
  cast_bf16<<<dim3(4096), blk, 0, stream>>>(x,  xb,  kM * 1024);
  cast_bf16<<<dim3(1024), blk, 0, stream>>>(Wq, Wqb, 1024 * 1024);
  cast_bf16<<<dim3(3072), blk, 0, stream>>>(Wk, Wkb, 3072 * 1024);
  cast_bf16<<<dim3(3072), blk, 0, stream>>>(Wv, Wvb, 3072 * 1024);
  cast_bf16<<<dim3(1024), blk, 0, stream>>>(Wg, Wgb, 1024 * 1024);
  cast_bf16<<<dim3(256),  blk, 0, stream>>>(Wl, Wlb, 256 * 1024);
  cast_bf16<<<dim3(1024), blk, 0, stream>>>(Wo, Wob, 1024 * 1024);
  cast_bd<<<dim3(512), blk, 0, stream>>>(Wb, Wa, Wbdb);

  // projections (bf16 MFMA)
  gemm_bf16<0><<<dim3(8, 32),  blk, 0, stream>>>(xb, Wqb,  qb,   nullptr, 1024, nullptr);
  gemm_bf16<1><<<dim3(24, 32), blk, 0, stream>>>(xb, Wkb,  kb,   nullptr, 3072, nullptr);
  gemm_bf16<1><<<dim3(24, 32), blk, 0, stream>>>(xb, Wvb,  vb,   nullptr, 3072, nullptr);
  gemm_bf16<3><<<dim3(1, 32),  blk, 0, stream>>>(xb, Wbdb, betb, decb,    128,  nullptr);
  gemm_bf16<4><<<dim3(2, 32),  blk, 0, stream>>>(xb, Wlb,  lwb,  nullptr, 256,  Lp);

  lwc_mean<<<dim3(64), blk, 0, stream>>>(lwb, lwcb);

  // sequential recurrence (one block per (b,h))
  recurrence<<<dim3(kB * kH), blk, 0, stream>>>(qb, kb, vb, betb, decb, lwcb, stb, ob);

  // og projection after recurrence (reuses kb space)
  gemm_bf16<0><<<dim3(8, 32), blk, 0, stream>>>(xb, Wgb, ogb, nullptr, 1024, nullptr);

  // group norm + gate
  gn_stats<<<dim3(kB * kH), blk, 0, stream>>>(ob, statb);
  gate_kernel<<<dim3((kM * 1024 + 255) / 256), blk, 0, stream>>>(ob, ogb, gamma, gbeta, statb, zbf);

  // final projection
  gemm_bf16<0><<<dim3(8, 32), blk, 0, stream>>>(zbf, Wob, out, nullptr, 1024, nullptr);
}

// Round 3
// 4030.797 us; speedup vs baseline: 1.5748x; 1.0013x over previous
//
#include <hip/hip_runtime.h>
#include <hip/hip_bf16.h>
#include <math.h>

// Problem constants
constexpr int kB   = 2;
constexpr int kT   = 2048;
constexpr int kH   = 16;    // heads
constexpr int kNH  = 3;     // delta-product sub-steps per token
constexpr int kC   = 64;    // chunk size
constexpr int kNc  = 32;    // T / C
constexpr int kLVL = 16;    // levels allocated
constexpr int kLU  = 6;     // levels reachable (max ctz(i+1), i<32 -> 5)
constexpr int kM   = kB * kT;   // 4096 rows
constexpr int kK   = 1024;      // K of every GEMM here

using bf16x8 = __attribute__((ext_vector_type(8))) short;  // 8 bf16 (4 VGPRs)
using f32x4  = __attribute__((ext_vector_type(4))) float;

__device__ __forceinline__ void glds16(const void* g, void* l) {
  __builtin_amdgcn_global_load_lds(
      (const __attribute__((address_space(1))) unsigned int*)g,
      (__attribute__((address_space(3))) unsigned int*)l, 16, 0, 0);
}

// ---------------------------------------------------------------------------
// bf16 MFMA NT-GEMM: C[m,n] = act( sum_k A[m,k] * W[n,k] ), K = 1024.
// A (M,1024) bf16 row-major, W (N,1024) bf16 row-major (i.e. B^T layout).
// 128x128 tile, BK=32, 4 waves in 2x2, each wave 64x64 via 4x4 16x16x32 frags.
// Staging: global_load_lds width=16, linear LDS dest; the XOR chunk swizzle
// (chunk ^= (row>>1)&3) is applied to the GLOBAL source address and to the
// ds_read_b128 fragment reads (both-sides swizzle, m173/m201 pattern), which
// spreads the 16 rows of a fragment read across 8 bank slots (~2-way, free).
// MODE: 0 none, 1 silu, 3 split sigmoid (cols<48 -> Cmat[48], cols 48..63 ->
// C2[16], rest dropped), 4 softplus(Lp[n]*x)
// ---------------------------------------------------------------------------
template <int MODE>
__global__ __launch_bounds__(256) void gemm_bf16(
    const __hip_bfloat16* __restrict__ A, const __hip_bfloat16* __restrict__ W,
    float* __restrict__ Cmat, float* __restrict__ C2, int N,
    const float* __restrict__ Lp) {
  __shared__ __hip_bfloat16 As[128 * 32];
  __shared__ __hip_bfloat16 Bs[128 * 32];
  const int tid = threadIdx.x;
  const int w = tid >> 6, lane = tid & 63;
  const int bm = blockIdx.y * 128, bn = blockIdx.x * 128;

  // staging: thread -> (row sr / sr+64, physical 16B chunk sp); the data the
  // read expects at physical chunk p of row r is logical chunk p ^ ((r>>1)&3).
  // Note ((sr+64)>>1)&3 == (sr>>1)&3, so one g0 serves both halves.
  const int sr = tid >> 2, sp = tid & 3;
  const int g0 = sp ^ ((sr >> 1) & 3);
  const __hip_bfloat16* a0 = A + (size_t)(bm + sr) * kK + g0 * 8;
  const __hip_bfloat16* a1 = A + (size_t)(bm + sr + 64) * kK + g0 * 8;
  const __hip_bfloat16* b0 = W + (size_t)(bn + sr) * kK + g0 * 8;
  const __hip_bfloat16* b1 = W + (size_t)(bn + sr + 64) * kK + g0 * 8;
  char* AsB = (char*)As + w * 1024;  // wave-uniform LDS dest (+ lane*16 in HW)
  char* BsB = (char*)Bs + w * 1024;

  // fragment read byte offsets. A-frag (16x16x32): lane holds row (lane&15),
  // k-chunk (lane>>4)*8; B-frag: col (lane&15), same k-chunk.
  const int wr = w >> 1, wc = w & 1;
  const int fr = lane & 15, fc = lane >> 4;
  int aOff[4], bOff[4];
#pragma unroll
  for (int f = 0; f < 4; f++) {
    const int ra = wr * 64 + f * 16 + fr;
    aOff[f] = ra * 64 + ((fc ^ ((ra >> 1) & 3)) * 16);
    const int rb = wc * 64 + f * 16 + fr;
    bOff[f] = rb * 64 + ((fc ^ ((rb >> 1) & 3)) * 16);
  }

  f32x4 acc[4][4];
#pragma unroll
  for (int i = 0; i < 4; i++)
#pragma unroll
    for (int j = 0; j < 4; j++) acc[i][j] = (f32x4){0.f, 0.f, 0.f, 0.f};

  for (int k0 = 0; k0 < kK; k0 += 32) {
    __syncthreads();  // previous iteration's ds_reads done before overwrite
    glds16(a0 + k0, AsB);
    glds16(a1 + k0, AsB + 4096);
    glds16(b0 + k0, BsB);
    glds16(b1 + k0, BsB + 4096);
    __syncthreads();  // drains vmcnt(0): staged data visible

    bf16x8 af[4], bfr[4];
#pragma unroll
    for (int f = 0; f < 4; f++) af[f] = *(const bf16x8*)((const char*)As + aOff[f]);
#pragma unroll
    for (int f = 0; f < 4; f++) bfr[f] = *(const bf16x8*)((const char*)Bs + bOff[f]);
#pragma unroll
    for (int i = 0; i < 4; i++)
#pragma unroll
      for (int j = 0; j < 4; j++)
        acc[i][j] = __builtin_amdgcn_mfma_f32_16x16x32_bf16(af[i], bfr[j], acc[i][j], 0, 0, 0);
  }

  // C/D layout: col = lane&15, row = (lane>>4)*4 + e  [m89 verified]
  const int r0 = bm + wr * 64, c0 = bn + wc * 64;
#pragma unroll
  for (int i = 0; i < 4; i++)
#pragma unroll
    for (int j = 0; j < 4; j++)
#pragma unroll
      for (int e = 0; e < 4; e++) {
        const int rr = r0 + i * 16 + fc * 4 + e;
        const int cc = c0 + j * 16 + fr;
        float vx = acc[i][j][e];
        if constexpr (MODE == 1) {            // silu
          vx = vx / (1.f + expf(-vx));
        }
        if constexpr (MODE == 4) {            // softplus(Lp*x)
          const float y = Lp[cc] * vx;
          vx = fmaxf(y, 0.f) + log1pf(expf(-fabsf(y)));
        }
        if constexpr (MODE == 3) {            // beta (48) + dec (16), sigmoid
          const float s = 1.f / (1.f + expf(-vx));
          if (cc < 48)       Cmat[(size_t)rr * 48 + cc] = s;
          else if (cc < 64)  C2[(size_t)rr * 16 + (cc - 48)] = s;
        } else {
          Cmat[(size_t)rr * N + cc] = vx;
        }
      }
}

// ---------------------------------------------------------------------------
// f32 -> bf16 cast (n multiple of 4)
// ---------------------------------------------------------------------------
__global__ void cast_bf16(const float* __restrict__ in, __hip_bfloat16* __restrict__ out, int n) {
  const int i = (blockIdx.x * 256 + threadIdx.x) * 4;
  if (i >= n) return;
  const float4 v = *(const float4*)(in + i);
  __hip_bfloat16 tmp[4] = {__float2bfloat16(v.x), __float2bfloat16(v.y),
                           __float2bfloat16(v.z), __float2bfloat16(v.w)};
  *(ushort4*)(out + i) = *(ushort4*)tmp;
}

// Combined beta/dec weight tile: rows 0..47 = Wb, 48..63 = Wa, 64..127 = 0
__global__ void cast_bd(const float* __restrict__ Wb, const float* __restrict__ Wa,
                        __hip_bfloat16* __restrict__ out) {
  const int idx = blockIdx.x * 256 + threadIdx.x;  // 128*1024
  if (idx >= 128 * 1024) return;
  const int r = idx >> 10, k = idx & 1023;
  const float val = (r < 48) ? Wb[r * 1024 + k] : ((r < 64) ? Wa[(r - 48) * 1024 + k] : 0.f);
  out[idx] = __float2bfloat16(val);
}

// ---------------------------------------------------------------------------
// lwc = mean over the 64 tokens of each chunk of lw (B,T,H,16) -> (B,Nc,H,16)
// ---------------------------------------------------------------------------
__global__ void lwc_mean(const float* __restrict__ lw, float* __restrict__ lwc) {
  const int idx = blockIdx.x * 256 + threadIdx.x;  // ((b*32+c)*16+h)*16+l
  if (idx >= kB * kNc * kH * kLVL) return;
  const int l = idx & 15;
  const int h = (idx >> 4) & 15;
  const int c = (idx >> 8) & 31;
  const int b = idx >> 13;
  size_t base = ((size_t)b * kT + (size_t)c * kC) * 256 + h * 16 + l;
  float s = 0.f;
  for (int tt = 0; tt < kC; tt++) s += lw[base + (size_t)tt * 256];
  lwc[idx] = s * (1.f / 64.f);
}

// ---------------------------------------------------------------------------
// Sequential gated delta-product recurrence (unchanged from round 1, verified).
// One block per (b,h); 4 waves; wave w owns k-rows [16w,16w+16), lane = v-col.
// ---------------------------------------------------------------------------
__global__ __launch_bounds__(256) void recurrence(
    const float* __restrict__ q, const float* __restrict__ k,
    const float* __restrict__ v, const float* __restrict__ bet,
    const float* __restrict__ dec, const float* __restrict__ lwc,
    float* __restrict__ states, float* __restrict__ o) {
  const int bh = blockIdx.x;
  const int b = bh >> 4, h = bh & 15;
  const int tid = threadIdx.x;
  const int w = tid >> 6, lane = tid & 63;

  __shared__ float tok[452];        // [0,64)=q [64,256)=k [256,448)=v [448,451)=beta [451]=dec
  __shared__ float kSp[2][4][64];   // double-buffered per-wave partial sums

  const size_t stStride = (size_t)kH * 4096;
  float* st = states + ((size_t)b * kLVL * kH + h) * 4096;

  float s[16];

  for (int l = 0; l < kLU; l++) {
#pragma unroll
    for (int kk = 0; kk < 16; kk++)
      st[l * stStride + (size_t)(w * 16 + kk) * 64 + lane] = 0.f;
  }

  for (int c = 0; c < kNc; c++) {
    const float* lwp = lwc + ((size_t)(b * kNc + c) * kH + h) * 16;
#pragma unroll
    for (int kk = 0; kk < 16; kk++) s[kk] = 0.f;
    for (int l = 0; l < kLU; l++) {
      const float lwv = lwp[l];
#pragma unroll
      for (int kk = 0; kk < 16; kk++)
        s[kk] = fmaf(lwv, st[l * stStride + (size_t)(w * 16 + kk) * 64 + lane], s[kk]);
    }

    for (int tt = 0; tt < kC; tt++) {
      const size_t m = (size_t)b * kT + (size_t)c * kC + tt;
      __syncthreads();
      for (int i = tid; i < 452; i += 256) {
        float val;
        if (i < 64)        val = q[m * 1024 + h * 64 + i];
        else if (i < 256)  val = k[m * 3072 + h * 192 + (i - 64)];
        else if (i < 448)  val = v[m * 3072 + h * 192 + (i - 256)];
        else if (i < 451)  val = bet[m * 48 + h * 3 + (i - 448)];
        else               val = dec[m * 16 + h];
        tok[i] = val;
      }
      __syncthreads();

      const float eg = tok[451];
#pragma unroll
      for (int kk = 0; kk < 16; kk++) s[kk] *= eg;

#pragma unroll
      for (int j = 0; j < kNH; j++) {
        float p = 0.f;
#pragma unroll
        for (int kk = 0; kk < 16; kk++)
          p = fmaf(tok[64 + (w * 16 + kk) * 3 + j], s[kk], p);
        kSp[j & 1][w][lane] = p;
        __syncthreads();
        const float kS = kSp[j & 1][0][lane] + kSp[j & 1][1][lane] +
                         kSp[j & 1][2][lane] + kSp[j & 1][3][lane];
        const float coef = tok[448 + j] * (tok[256 + lane * 3 + j] - kS);
#pragma unroll
        for (int kk = 0; kk < 16; kk++)
          s[kk] = fmaf(tok[64 + (w * 16 + kk) * 3 + j], coef, s[kk]);
      }

      float p = 0.f;
#pragma unroll
      for (int kk = 0; kk < 16; kk++) p = fmaf(tok[w * 16 + kk], s[kk], p);
      kSp[1][w][lane] = p;
      __syncthreads();
      if (w == 0) {
        const float ov = kSp[1][0][lane] + kSp[1][1][lane] +
                         kSp[1][2][lane] + kSp[1][3][lane];
        o[m * 1024 + h * 64 + lane] = ov;
      }
    }

    const int lev = __builtin_ctz(c + 1);
    for (int l = 0; l < lev; l++) {
#pragma unroll
      for (int kk = 0; kk < 16; kk++) {
        const size_t idx = l * stStride + (size_t)(w * 16 + kk) * 64 + lane;
        s[kk] += st[idx];
        st[idx] = 0.f;
      }
    }
#pragma unroll
    for (int kk = 0; kk < 16; kk++)
      st[lev * stStride + (size_t)(w * 16 + kk) * 64 + lane] = s[kk];
  }
}

// ---------------------------------------------------------------------------
// GroupNorm stats per (b,h) over (HEAD_V, T)
// ---------------------------------------------------------------------------
__global__ __launch_bounds__(256) void gn_stats(const float* __restrict__ o,
                                                float* __restrict__ stats) {
  const int bh = blockIdx.x;
  const int b = bh >> 4, h = bh & 15;
  double sum = 0.0, sumsq = 0.0;
  for (int idx = threadIdx.x; idx < kT * 64; idx += 256) {
    const int t = idx >> 6, vv = idx & 63;
    const float val = o[((size_t)b * kT + t) * 1024 + h * 64 + vv];
    sum += val;
    sumsq += (double)val * val;
  }
  __shared__ double sred[256], qred[256];
  sred[threadIdx.x] = sum;
  qred[threadIdx.x] = sumsq;
  __syncthreads();
  for (int stp = 128; stp > 0; stp >>= 1) {
    if (threadIdx.x < stp) {
      sred[threadIdx.x] += sred[threadIdx.x + stp];
      qred[threadIdx.x] += qred[threadIdx.x + stp];
    }
    __syncthreads();
  }
  if (threadIdx.x == 0) {
    const double n = (double)kT * 64.0;
    const double mu = sred[0] / n;
    const double var = qred[0] / n - mu * mu;
    stats[bh * 2]     = (float)mu;
    stats[bh * 2 + 1] = (float)(1.0 / sqrt(var + 1e-5));
  }
}

// ---------------------------------------------------------------------------
// z = ((o - mu)*rstd*gamma + beta) * sigmoid(og), written as bf16 for out-proj
// ---------------------------------------------------------------------------
__global__ void gate_kernel(const float* __restrict__ o, const float* __restrict__ og,
                            const float* __restrict__ gamma, const float* __restrict__ gbeta,
                            const float* __restrict__ stats, __hip_bfloat16* __restrict__ z) {
  const size_t idx = (size_t)blockIdx.x * 256 + threadIdx.x;
  if (idx >= (size_t)kM * 1024) return;
  const int cidx = (int)(idx & 1023);
  const int h = cidx >> 6;
  const size_t m = idx >> 10;
  const int b = (int)(m >> 11);
  const float mu = stats[(b * 16 + h) * 2];
  const float rstd = stats[(b * 16 + h) * 2 + 1];
  const float val = (o[idx] - mu) * rstd * gamma[cidx] + gbeta[cidx];
  const float gt = og[idx];
  z[idx] = __float2bfloat16(val * (1.f / (1.f + expf(-gt))));
}

// ---------------------------------------------------------------------------
extern "C" void kernel_launch(void* const* d_in, const int* in_sizes, int n_in,
                              void* d_out, int out_size, void* d_ws, size_t ws_size,
                              hipStream_t stream) {
  const float* x     = (const float*)d_in[0];
  // d_in[1]=cos, d_in[2]=sin: unused by the reference forward
  const float* Wq    = (const float*)d_in[3];
  const float* Wk    = (const float*)d_in[4];
  const float* Wv    = (const float*)d_in[5];
  const float* Wb    = (const float*)d_in[6];
  const float* Wa    = (const float*)d_in[7];
  const float* Wg    = (const float*)d_in[8];
  const float* Wo    = (const float*)d_in[9];
  const float* Wl    = (const float*)d_in[10];
  const float* Lp    = (const float*)d_in[11];
  const float* gamma = (const float*)d_in[12];
  const float* gbeta = (const float*)d_in[13];
  float* out = (float*)d_out;

  float* ws = (float*)d_ws;
  size_t off = 0;
  auto alloc = [&](size_t n) { float* p = ws + off; off += n; return p; };
  float* qb    = alloc((size_t)kM * 1024);
  float* kb    = alloc((size_t)kM * 3072);
  float* vb    = alloc((size_t)kM * 3072);
  float* betb  = alloc((size_t)kM * 48);
  float* decb  = alloc((size_t)kM * 16);
  float* lwb   = alloc((size_t)kM * 256);
  float* lwcb  = alloc((size_t)kB * kNc * kH * kLVL);
  float* stb   = alloc((size_t)kB * kLVL * kH * 4096);
  float* ob    = alloc((size_t)kM * 1024);
  float* statb = alloc(64);

  __hip_bfloat16* bfp = (__hip_bfloat16*)(ws + off);
  size_t boff = 0;
  auto balloc = [&](size_t n) { __hip_bfloat16* p = bfp + boff; boff += n; return p; };
  __hip_bfloat16* xb   = balloc((size_t)kM * 1024);
  __hip_bfloat16* Wqb  = balloc((size_t)1024 * 1024);
  __hip_bfloat16* Wkb  = balloc((size_t)3072 * 1024);
  __hip_bfloat16* Wvb  = balloc((size_t)3072 * 1024);
  __hip_bfloat16* Wgb  = balloc((size_t)1024 * 1024);
  __hip_bfloat16* Wlb  = balloc((size_t)256 * 1024);
  __hip_bfloat16* Wob  = balloc((size_t)1024 * 1024);
  __hip_bfloat16* Wbdb = balloc((size_t)128 * 1024);
  (void)ws_size;  // ~176 MB used (round-1 proved >= 181 MB available)

  // buffers dead after the recurrence, reused:
  float* ogb = kb;
  __hip_bfloat16* zbf = (__hip_bfloat16*)vb;

  const dim3 blk(256);

  // casts
  cast_bf16<<<dim3(4096), blk, 0, stream>>>(x,  xb,  kM * 1024);
  cast_bf16<<<dim3(1024), blk, 0, stream>>>(Wq, Wqb, 1024 * 1024);
  cast_bf16<<<dim3(3072), blk, 0, stream>>>(Wk, Wkb, 3072 * 1024);
  cast_bf16<<<dim3(3072), blk, 0, stream>>>(Wv, Wvb, 3072 * 1024);
  cast_bf16<<<dim3(1024), blk, 0, stream>>>(Wg, Wgb, 1024 * 1024);
  cast_bf16<<<dim3(256),  blk, 0, stream>>>(Wl, Wlb, 256 * 1024);
  cast_bf16<<<dim3(1024), blk, 0, stream>>>(Wo, Wob, 1024 * 1024);
  cast_bd<<<dim3(512), blk, 0, stream>>>(Wb, Wa, Wbdb);

  // projections (bf16 MFMA)
  gemm_bf16<0><<<dim3(8, 32),  blk, 0, stream>>>(xb, Wqb,  qb,   nullptr, 1024, nullptr);
  gemm_bf16<1><<<dim3(24, 32), blk, 0, stream>>>(xb, Wkb,  kb,   nullptr, 3072, nullptr);
  gemm_bf16<1><<<dim3(24, 32), blk, 0, stream>>>(xb, Wvb,  vb,   nullptr, 3072, nullptr);
  gemm_bf16<3><<<dim3(1, 32),  blk, 0, stream>>>(xb, Wbdb, betb, decb,    128,  nullptr);
  gemm_bf16<4><<<dim3(2, 32),  blk, 0, stream>>>(xb, Wlb,  lwb,  nullptr, 256,  Lp);

  lwc_mean<<<dim3(64), blk, 0, stream>>>(lwb, lwcb);

  // sequential recurrence (one block per (b,h))
  recurrence<<<dim3(kB * kH), blk, 0, stream>>>(qb, kb, vb, betb, decb, lwcb, stb, ob);

  // og projection after recurrence (reuses kb space)
  gemm_bf16<0><<<dim3(8, 32), blk, 0, stream>>>(xb, Wgb, ogb, nullptr, 1024, nullptr);

  // group norm + gate
  gn_stats<<<dim3(kB * kH), blk, 0, stream>>>(ob, statb);
  gate_kernel<<<dim3((kM * 1024 + 255) / 256), blk, 0, stream>>>(ob, ogb, gamma, gbeta, statb, zbf);

  // final projection
  gemm_bf16<0><<<dim3(8, 32), blk, 0, stream>>>(zbf, Wob, out, nullptr, 1024, nullptr);
}

// Round 4
// 3642.467 us; speedup vs baseline: 1.7427x; 1.1066x over previous
//
#include <hip/hip_runtime.h>
#include <hip/hip_bf16.h>
#include <math.h>

// Problem constants
constexpr int kB   = 2;
constexpr int kT   = 2048;
constexpr int kH   = 16;
constexpr int kC   = 64;    // chunk size
constexpr int kNc  = 32;    // T / C
constexpr int kM   = kB * kT;   // 4096
constexpr int kK   = 1024;

using bf16x8 = __attribute__((ext_vector_type(8))) short;
using f32x4  = __attribute__((ext_vector_type(4))) float;

__device__ __forceinline__ void glds16(const void* g, void* l) {
  __builtin_amdgcn_global_load_lds(
      (const __attribute__((address_space(1))) unsigned int*)g,
      (__attribute__((address_space(3))) unsigned int*)l, 16, 0, 0);
}

// ---------------------------------------------------------------------------
// bf16 MFMA NT-GEMM (verified rounds 2-3). MODE: 0 plain f32, 3 beta/dec
// sigmoid packed, 4 softplus(Lp*x), 5 silu + (b,h,chunk,i,d) pack for k/v.
// ---------------------------------------------------------------------------
template <int MODE>
__global__ __launch_bounds__(256) void gemm_bf16(
    const __hip_bfloat16* __restrict__ A, const __hip_bfloat16* __restrict__ W,
    float* __restrict__ Cmat, float* __restrict__ C2, int N,
    const float* __restrict__ Lp) {
  __shared__ __hip_bfloat16 As[128 * 32];
  __shared__ __hip_bfloat16 Bs[128 * 32];
  const int tid = threadIdx.x;
  const int w = tid >> 6, lane = tid & 63;
  const int bm = blockIdx.y * 128, bn = blockIdx.x * 128;

  const int sr = tid >> 2, sp = tid & 3;
  const int g0 = sp ^ ((sr >> 1) & 3);
  const __hip_bfloat16* a0 = A + (size_t)(bm + sr) * kK + g0 * 8;
  const __hip_bfloat16* a1 = A + (size_t)(bm + sr + 64) * kK + g0 * 8;
  const __hip_bfloat16* b0 = W + (size_t)(bn + sr) * kK + g0 * 8;
  const __hip_bfloat16* b1 = W + (size_t)(bn + sr + 64) * kK + g0 * 8;
  char* AsB = (char*)As + w * 1024;
  char* BsB = (char*)Bs + w * 1024;

  const int wr = w >> 1, wc = w & 1;
  const int fr = lane & 15, fc = lane >> 4;
  int aOff[4], bOff[4];
#pragma unroll
  for (int f = 0; f < 4; f++) {
    const int ra = wr * 64 + f * 16 + fr;
    aOff[f] = ra * 64 + ((fc ^ ((ra >> 1) & 3)) * 16);
    const int rb = wc * 64 + f * 16 + fr;
    bOff[f] = rb * 64 + ((fc ^ ((rb >> 1) & 3)) * 16);
  }

  f32x4 acc[4][4];
#pragma unroll
  for (int i = 0; i < 4; i++)
#pragma unroll
    for (int j = 0; j < 4; j++) acc[i][j] = (f32x4){0.f, 0.f, 0.f, 0.f};

  for (int k0 = 0; k0 < kK; k0 += 32) {
    __syncthreads();
    glds16(a0 + k0, AsB);
    glds16(a1 + k0, AsB + 4096);
    glds16(b0 + k0, BsB);
    glds16(b1 + k0, BsB + 4096);
    __syncthreads();

    bf16x8 af[4], bfr[4];
#pragma unroll
    for (int f = 0; f < 4; f++) af[f] = *(const bf16x8*)((const char*)As + aOff[f]);
#pragma unroll
    for (int f = 0; f < 4; f++) bfr[f] = *(const bf16x8*)((const char*)Bs + bOff[f]);
#pragma unroll
    for (int i = 0; i < 4; i++)
#pragma unroll
      for (int j = 0; j < 4; j++)
        acc[i][j] = __builtin_amdgcn_mfma_f32_16x16x32_bf16(af[i], bfr[j], acc[i][j], 0, 0, 0);
  }

  const int r0 = bm + wr * 64, c0 = bn + wc * 64;
#pragma unroll
  for (int i = 0; i < 4; i++)
#pragma unroll
    for (int j = 0; j < 4; j++)
#pragma unroll
      for (int e = 0; e < 4; e++) {
        const int rr = r0 + i * 16 + fc * 4 + e;
        const int cc = c0 + j * 16 + fr;
        float vx = acc[i][j][e];
        if constexpr (MODE == 4) {            // softplus(Lp*x) -> plain layout
          const float y = Lp[cc] * vx;
          vx = fmaxf(y, 0.f) + log1pf(expf(-fabsf(y)));
          Cmat[(size_t)rr * N + cc] = vx;
        } else if constexpr (MODE == 3) {     // beta(48)/dec(16) sigmoid, packed
          const float s = 1.f / (1.f + expf(-vx));
          const int b = rr >> 11, tok = rr & 2047, chn = tok >> 6, tt = tok & 63;
          if (cc < 48) {
            const int hh = cc / 3, j3 = cc - hh * 3;
            Cmat[(size_t)((b * 16 + hh) * 32 + chn) * 192 + tt * 3 + j3] = s;
          } else if (cc < 64) {
            const int hh = cc - 48;
            C2[(size_t)((b * 16 + hh) * 32 + chn) * 64 + tt] = s;
          }
        } else if constexpr (MODE == 5) {     // silu + kv pack
          vx = vx / (1.f + expf(-vx));
          const int b = rr >> 11, tok = rr & 2047, chn = tok >> 6, tt = tok & 63;
          const int hh = cc / 192, rem = cc - hh * 192;
          const int d = rem / 3, j3 = rem - d * 3;
          Cmat[((size_t)((b * 16 + hh) * 32 + chn) * 192 + tt * 3 + j3) * 64 + d] = vx;
        } else {
          Cmat[(size_t)rr * N + cc] = vx;
        }
      }
}

// ---------------------------------------------------------------------------
__global__ void cast_bf16(const float* __restrict__ in, __hip_bfloat16* __restrict__ out, int n) {
  const int i = (blockIdx.x * 256 + threadIdx.x) * 4;
  if (i >= n) return;
  const float4 v = *(const float4*)(in + i);
  __hip_bfloat16 tmp[4] = {__float2bfloat16(v.x), __float2bfloat16(v.y),
                           __float2bfloat16(v.z), __float2bfloat16(v.w)};
  *(ushort4*)(out + i) = *(ushort4*)tmp;
}

__global__ void cast_bd(const float* __restrict__ Wb, const float* __restrict__ Wa,
                        __hip_bfloat16* __restrict__ out) {
  const int idx = blockIdx.x * 256 + threadIdx.x;
  if (idx >= 128 * 1024) return;
  const int r = idx >> 10, k = idx & 1023;
  const float val = (r < 48) ? Wb[r * 1024 + k] : ((r < 64) ? Wa[(r - 48) * 1024 + k] : 0.f);
  out[idx] = __float2bfloat16(val);
}

__global__ void lwc_mean(const float* __restrict__ lw, float* __restrict__ lwc) {
  const int idx = blockIdx.x * 256 + threadIdx.x;
  if (idx >= kB * kNc * kH * 16) return;
  const int l = idx & 15, h = (idx >> 4) & 15, c = (idx >> 8) & 31, b = idx >> 13;
  size_t base = ((size_t)b * kT + (size_t)c * kC) * 256 + h * 16 + l;
  float s = 0.f;
  for (int tt = 0; tt < kC; tt++) s += lw[base + (size_t)tt * 256];
  lwc[idx] = s * (1.f / 64.f);
}

// ---------------------------------------------------------------------------
// chunk_prep<PASS>: per (b,h,chunk) block. Solves (I+Lambda) X = RHS via
// blocked forward substitution (Lambda never materialized beyond 64x64 tiles),
// then forms the affine chunk operators.
// PASS 0: RHS = K^ (rows c_tau(i)*k_i) -> outA = Tc = cC*I - W^T X (stride 4096)
//                                         outB = Qe = diag(c)Q - Phi X
// PASS 1: RHS = V                      -> outA = Bc = W^T X  (into KP slice)
//                                         outB = Vo = Phi X (into VP slice)
// ---------------------------------------------------------------------------
template <int PASS>
__global__ __launch_bounds__(256) void chunk_prep(
    const float* __restrict__ KP, const float* __restrict__ VP,
    const float* __restrict__ qbuf, const float* __restrict__ betp,
    const float* __restrict__ decp, float* __restrict__ outA,
    float* __restrict__ outB) {
  const int ch = blockIdx.x;          // bh*32 + c
  const int c  = ch & 31;
  const int bh = ch >> 5;
  const int b  = bh >> 4, h = bh & 15;
  const int tid = threadIdx.x;

  __shared__ float Kt[64][193];       // [d][i], padded (bank-spread)
  __shared__ float X[192][64];
  __shared__ float tile[64 * 64];
  __shared__ float cpre[64], decs[64];
  __shared__ float cti[192], rci[192], bet_s[192], wfac[192];

  const float* KPs = KP + (size_t)ch * 12288;
  const float* VPs = VP + (size_t)ch * 12288;

  for (int idx = tid; idx < 12288; idx += 256)
    Kt[idx & 63][idx >> 6] = KPs[idx];
  if (tid < 192) bet_s[tid] = betp[(size_t)ch * 192 + tid];
  if (tid < 64)  decs[tid] = decp[(size_t)ch * 64 + tid];
  __syncthreads();
  if (tid == 0) {
    float p = 1.f;
    for (int t = 0; t < 64; t++) { p *= decs[t]; cpre[t] = p; }
  }
  __syncthreads();
  if (tid < 192) {
    const float cv = cpre[tid / 3];
    cti[tid] = cv;
    const float r = 1.f / cv;
    rci[tid] = r;
    wfac[tid] = bet_s[tid] * cpre[63] * r;
  }
  __syncthreads();
  for (int idx = tid; idx < 12288; idx += 256) {
    const int i = idx >> 6, d = idx & 63;
    X[i][d] = (PASS == 0) ? cti[i] * Kt[d][i] : VPs[idx];
  }
  __syncthreads();

  const int c2 = tid & 63;
  const int wg = tid >> 6;

  // blocked forward substitution: 3 blocks of 64
  for (int sb = 0; sb < 3; sb++) {
    const int s = sb * 64;
    for (int jb = 0; jb <= sb; jb++) {
      const int j0 = jb * 64;
      // Lambda tile [ii][jj] = bet[gj] * (k_gi . k_gj) * cti[gi]/cti[gj]
#pragma unroll 4
      for (int n = 0; n < 16; n++) {
        const int ii = wg * 16 + n;
        const int gi = s + ii, gj = j0 + c2;
        float dsum = 0.f;
#pragma unroll 8
        for (int dd = 0; dd < 64; dd++)
          dsum = fmaf(Kt[dd][gi], Kt[dd][gj], dsum);
        tile[ii * 64 + c2] = bet_s[gj] * dsum * (cti[gi] * rci[gj]);
      }
      __syncthreads();
      if (jb < sb) {
#pragma unroll 4
        for (int n = 0; n < 16; n++) {
          const int ii = wg * 16 + n;
          float acc = X[s + ii][c2];
#pragma unroll 8
          for (int jj = 0; jj < 64; jj++)
            acc = fmaf(-tile[ii * 64 + jj], X[j0 + jj][c2], acc);
          X[s + ii][c2] = acc;
        }
        __syncthreads();
      } else {
        // local forward substitution; thread owns column c2 (strict lower)
        if (tid < 64) {
          for (int ii = 1; ii < 64; ii++) {
            float acc = X[s + ii][tid];
            for (int jj = 0; jj < ii; jj++)
              acc = fmaf(-tile[ii * 64 + jj], X[s + jj][tid], acc);
            X[s + ii][tid] = acc;
          }
        }
        __syncthreads();
      }
    }
  }

  // products
  float accA[16], accB[16];
#pragma unroll
  for (int n = 0; n < 16; n++) { accA[n] = 0.f; accB[n] = 0.f; }
  const float* qbase = qbuf + ((size_t)(b * 2048 + c * 64)) * 1024 + h * 64;

  for (int ib = 0; ib < 3; ib++) {
    {  // stage Phi block: tile[t*64 + i2]
      const int i2 = c2;
      const int i = ib * 64 + i2;
      const int tau = i / 3;
      const float fi = bet_s[i] * rci[i];
#pragma unroll 4
      for (int n = 0; n < 16; n++) {
        const int t = wg * 16 + n;
        float val = 0.f;
        if (tau <= t) {
          float dsum = 0.f;
#pragma unroll 8
          for (int dd = 0; dd < 64; dd++)
            dsum = fmaf(qbase[(size_t)t * 1024 + dd], Kt[dd][i], dsum);
          val = fi * cpre[t] * dsum;
        }
        tile[t * 64 + i2] = val;
      }
    }
    __syncthreads();
#pragma unroll 4
    for (int n = 0; n < 16; n++) {
      const int row = wg * 16 + n;
      float a = accA[n], bb = accB[n];
#pragma unroll 8
      for (int i2 = 0; i2 < 64; i2++) {
        const int i = ib * 64 + i2;
        const float xv = X[i][c2];
        a  = fmaf(wfac[i] * Kt[row][i], xv, a);
        bb = fmaf(tile[row * 64 + i2], xv, bb);
      }
      accA[n] = a; accB[n] = bb;
    }
    __syncthreads();
  }

#pragma unroll
  for (int n = 0; n < 16; n++) {
    const int row = wg * 16 + n;
    if (PASS == 0) {
      outA[(size_t)ch * 4096 + row * 64 + c2] =
          ((row == c2) ? cpre[63] : 0.f) - accA[n];
      outB[(size_t)ch * 4096 + row * 64 + c2] =
          cpre[row] * qbase[(size_t)row * 1024 + c2] - accB[n];
    } else {
      outA[(size_t)ch * 12288 + row * 64 + c2] = accA[n];  // Bc -> KP slice
      outB[(size_t)ch * 12288 + row * 64 + c2] = accB[n];  // Vo -> VP slice
    }
  }
}

// ---------------------------------------------------------------------------
// chunk_scan: 64 blocks = (b,h) x v-half. Level states in LDS. Per chunk:
// S0 = sum_l lw[l] st[l]; O = Qe S0 + Vo (-> VP slice +4096); Sf = Tc S0 + Bc;
// hierarchical merge at lev = ctz(c+1).
// ---------------------------------------------------------------------------
__global__ __launch_bounds__(256) void chunk_scan(
    const float* __restrict__ Tc, const float* __restrict__ Qe,
    const float* __restrict__ KPb, float* __restrict__ VPb,
    const float* __restrict__ lwcb) {
  const int blk = blockIdx.x;
  const int bh = blk >> 1, vh = blk & 1;
  const int b = bh >> 4, h = bh & 15;
  const int vbase = vh * 32;
  const int tid = threadIdx.x;
  const int v = tid & 31;
  const int tg = tid >> 5;   // 0..7

  __shared__ float stL[6][64][32];
  __shared__ float S0s[64][32];
  __shared__ float QT[64][64];
  __shared__ float BV[64][32];

  for (int idx = tid; idx < 6 * 2048; idx += 256) ((float*)stL)[idx] = 0.f;
  __syncthreads();

  float sf[8];
  for (int c = 0; c < 32; c++) {
    const size_t ch = (size_t)bh * 32 + c;
    const float* lwp = lwcb + ((size_t)(b * kNc + c) * kH + h) * 16;
    float lw[6];
#pragma unroll
    for (int l = 0; l < 6; l++) lw[l] = lwp[l];

#pragma unroll
    for (int n = 0; n < 8; n++) {
      const int k = n * 8 + tg;
      float s = 0.f;
#pragma unroll
      for (int l = 0; l < 6; l++) s = fmaf(lw[l], stL[l][k][v], s);
      S0s[k][v] = s;
    }
    for (int idx = tid; idx < 4096; idx += 256) QT[idx >> 6][idx & 63] = Qe[ch * 4096 + idx];
    for (int idx = tid; idx < 2048; idx += 256)
      BV[idx >> 5][idx & 31] = VPb[ch * 12288 + (idx >> 5) * 64 + vbase + (idx & 31)];
    __syncthreads();

#pragma unroll 2
    for (int n = 0; n < 8; n++) {
      const int t = n * 8 + tg;
      float o = BV[t][v];
#pragma unroll 8
      for (int k = 0; k < 64; k++) o = fmaf(QT[t][k], S0s[k][v], o);
      VPb[ch * 12288 + 4096 + t * 64 + vbase + v] = o;
    }
    __syncthreads();

    for (int idx = tid; idx < 4096; idx += 256) QT[idx >> 6][idx & 63] = Tc[ch * 4096 + idx];
    for (int idx = tid; idx < 2048; idx += 256)
      BV[idx >> 5][idx & 31] = KPb[ch * 12288 + (idx >> 5) * 64 + vbase + (idx & 31)];
    __syncthreads();

#pragma unroll 2
    for (int n = 0; n < 8; n++) {
      const int r = n * 8 + tg;
      float s = BV[r][v];
#pragma unroll 8
      for (int k = 0; k < 64; k++) s = fmaf(QT[r][k], S0s[k][v], s);
      sf[n] = s;
    }
    const int lev = __builtin_ctz(c + 1);
#pragma unroll
    for (int n = 0; n < 8; n++) {
      const int r = n * 8 + tg;
      float s = sf[n];
      for (int l = 0; l < lev; l++) { s += stL[l][r][v]; stL[l][r][v] = 0.f; }
      stL[lev][r][v] = s;
    }
    __syncthreads();
  }
}

// ---------------------------------------------------------------------------
__global__ __launch_bounds__(256) void gn_stats(const float* __restrict__ VPb,
                                                float* __restrict__ stats) {
  const int bh = blockIdx.x;
  double sum = 0.0, sumsq = 0.0;
  for (int idx = threadIdx.x; idx < kNc * 4096; idx += 256) {
    const int c = idx >> 12, r = idx & 4095;
    const float val = VPb[((size_t)bh * 32 + c) * 12288 + 4096 + r];
    sum += val;
    sumsq += (double)val * val;
  }
  __shared__ double sred[256], qred[256];
  sred[threadIdx.x] = sum;
  qred[threadIdx.x] = sumsq;
  __syncthreads();
  for (int stp = 128; stp > 0; stp >>= 1) {
    if (threadIdx.x < stp) {
      sred[threadIdx.x] += sred[threadIdx.x + stp];
      qred[threadIdx.x] += qred[threadIdx.x + stp];
    }
    __syncthreads();
  }
  if (threadIdx.x == 0) {
    const double n = (double)kT * 64.0;
    const double mu = sred[0] / n;
    const double var = qred[0] / n - mu * mu;
    stats[bh * 2] = (float)mu;
    stats[bh * 2 + 1] = (float)(1.0 / sqrt(var + 1e-5));
  }
}

__global__ void gate_kernel(const float* __restrict__ VPb, const float* __restrict__ og,
                            const float* __restrict__ gamma, const float* __restrict__ gbeta,
                            const float* __restrict__ stats, __hip_bfloat16* __restrict__ z) {
  const size_t idx = (size_t)blockIdx.x * 256 + threadIdx.x;
  if (idx >= (size_t)kM * 1024) return;
  const int cidx = (int)(idx & 1023);
  const int h = cidx >> 6, v = cidx & 63;
  const size_t m = idx >> 10;
  const int b = (int)(m >> 11);
  const int tok = (int)(m & 2047), c = tok >> 6, tt = tok & 63;
  const float o = VPb[((size_t)((b * 16 + h) * 32 + c)) * 12288 + 4096 + tt * 64 + v];
  const float mu = stats[(b * 16 + h) * 2];
  const float rstd = stats[(b * 16 + h) * 2 + 1];
  const float val = (o - mu) * rstd * gamma[cidx] + gbeta[cidx];
  const float gt = og[idx];
  z[idx] = __float2bfloat16(val * (1.f / (1.f + expf(-gt))));
}

// ---------------------------------------------------------------------------
extern "C" void kernel_launch(void* const* d_in, const int* in_sizes, int n_in,
                              void* d_out, int out_size, void* d_ws, size_t ws_size,
                              hipStream_t stream) {
  const float* x     = (const float*)d_in[0];
  const float* Wq    = (const float*)d_in[3];
  const float* Wk    = (const float*)d_in[4];
  const float* Wv    = (const float*)d_in[5];
  const float* Wb    = (const float*)d_in[6];
  const float* Wa    = (const float*)d_in[7];
  const float* Wg    = (const float*)d_in[8];
  const float* Wo    = (const float*)d_in[9];
  const float* Wl    = (const float*)d_in[10];
  const float* Lp    = (const float*)d_in[11];
  const float* gamma = (const float*)d_in[12];
  const float* gbeta = (const float*)d_in[13];
  float* out = (float*)d_out;
  (void)ws_size;

  // arena (exact byte offsets; total = 181,469,440 == round-1 proven usage)
  char* base = (char*)d_ws;
  __hip_bfloat16* xb   = (__hip_bfloat16*)(base + 0);            // 8,388,608
  __hip_bfloat16* Wgb  = (__hip_bfloat16*)(base + 8388608);      // 2,097,152
  __hip_bfloat16* Wob  = (__hip_bfloat16*)(base + 10485760);     // 2,097,152
  char* Wscr           = base + 12582912;                        // 16,777,216
  __hip_bfloat16* Wqb  = (__hip_bfloat16*)(Wscr + 0);
  __hip_bfloat16* Wkb  = (__hip_bfloat16*)(Wscr + 2097152);
  __hip_bfloat16* Wvb  = (__hip_bfloat16*)(Wscr + 8388608);
  __hip_bfloat16* Wlb  = (__hip_bfloat16*)(Wscr + 14680064);
  __hip_bfloat16* Wbdb = (__hip_bfloat16*)(Wscr + 15204352);
  __hip_bfloat16* zbf  = (__hip_bfloat16*)Wscr;                  // after preps
  float* qb    = (float*)(base + 29360128);                      // 16,777,216
  float* ogb   = qb;                                             // after preps
  float* KP    = (float*)(base + 46137344);                      // 50,331,648
  float* VP    = (float*)(base + 96468992);                      // 50,331,648
  float* betp  = (float*)(base + 146800640);                     // 786,432
  float* decp  = (float*)(base + 147587072);                     // 262,144
  float* lwcb  = (float*)(base + 147849216);                     // 65,536
  float* statb = (float*)(base + 147914752);                     // 256
  float* Tc    = (float*)(base + 147915008);                     // 16,777,216
  float* lwb   = Tc;                                             // before prep1
  float* Qe    = (float*)(base + 164692224);                     // 16,777,216

  const dim3 blk(256);

  // casts
  cast_bf16<<<dim3(4096), blk, 0, stream>>>(x,  xb,  kM * 1024);
  cast_bf16<<<dim3(1024), blk, 0, stream>>>(Wq, Wqb, 1024 * 1024);
  cast_bf16<<<dim3(3072), blk, 0, stream>>>(Wk, Wkb, 3072 * 1024);
  cast_bf16<<<dim3(3072), blk, 0, stream>>>(Wv, Wvb, 3072 * 1024);
  cast_bf16<<<dim3(1024), blk, 0, stream>>>(Wg, Wgb, 1024 * 1024);
  cast_bf16<<<dim3(256),  blk, 0, stream>>>(Wl, Wlb, 256 * 1024);
  cast_bf16<<<dim3(1024), blk, 0, stream>>>(Wo, Wob, 1024 * 1024);
  cast_bd<<<dim3(512), blk, 0, stream>>>(Wb, Wa, Wbdb);

  // projections
  gemm_bf16<0><<<dim3(8, 32),  blk, 0, stream>>>(xb, Wqb,  qb,   nullptr, 1024, nullptr);
  gemm_bf16<5><<<dim3(24, 32), blk, 0, stream>>>(xb, Wkb,  KP,   nullptr, 3072, nullptr);
  gemm_bf16<5><<<dim3(24, 32), blk, 0, stream>>>(xb, Wvb,  VP,   nullptr, 3072, nullptr);
  gemm_bf16<3><<<dim3(1, 32),  blk, 0, stream>>>(xb, Wbdb, betp, decp,    128,  nullptr);
  gemm_bf16<4><<<dim3(2, 32),  blk, 0, stream>>>(xb, Wlb,  lwb,  nullptr, 256,  Lp);

  lwc_mean<<<dim3(64), blk, 0, stream>>>(lwb, lwcb);

  // chunk operators (parallel over 1024 chunk-heads)
  chunk_prep<0><<<dim3(1024), blk, 0, stream>>>(KP, VP, qb, betp, decp, Tc, Qe);
  chunk_prep<1><<<dim3(1024), blk, 0, stream>>>(KP, VP, qb, betp, decp, KP, VP);

  // og projection (qb now dead -> ogb aliases it)
  gemm_bf16<0><<<dim3(8, 32), blk, 0, stream>>>(xb, Wgb, ogb, nullptr, 1024, nullptr);

  // sequential chunk scan (64 blocks: (b,h) x v-half)
  chunk_scan<<<dim3(64), blk, 0, stream>>>(Tc, Qe, KP, VP, lwcb);

  // group norm + gate
  gn_stats<<<dim3(kB * kH), blk, 0, stream>>>(VP, statb);
  gate_kernel<<<dim3((kM * 1024 + 255) / 256), blk, 0, stream>>>(VP, ogb, gamma, gbeta, statb, zbf);

  // final projection
  gemm_bf16<0><<<dim3(8, 32), blk, 0, stream>>>(zbf, Wob, out, nullptr, 1024, nullptr);
}

// Round 5
// 1636.527 us; speedup vs baseline: 3.8788x; 2.2257x over previous
//
#include <hip/hip_runtime.h>
#include <hip/hip_bf16.h>
#include <math.h>

// Problem constants
constexpr int kB   = 2;
constexpr int kT   = 2048;
constexpr int kH   = 16;
constexpr int kC   = 64;    // chunk size
constexpr int kNc  = 32;    // T / C
constexpr int kM   = kB * kT;   // 4096
constexpr int kK   = 1024;

using bf16x8 = __attribute__((ext_vector_type(8))) short;
using f32x4  = __attribute__((ext_vector_type(4))) float;

__device__ __forceinline__ void glds16(const void* g, void* l) {
  __builtin_amdgcn_global_load_lds(
      (const __attribute__((address_space(1))) unsigned int*)g,
      (__attribute__((address_space(3))) unsigned int*)l, 16, 0, 0);
}

// ---------------------------------------------------------------------------
// bf16 MFMA NT-GEMM (verified structure). MODE:
//  0: f32 plain [rr*N+cc]
//  3: beta(48)/dec(16) sigmoid -> betp [ch][192] f32, decp [ch][64] f32
//  4: softplus(Lp*x) f32 plain (lw)
//  5: silu -> bf16 pack [ch][i=tt*3+j3][d]
//  6: bf16 q pack [ch][t][d]
//  7: bf16 plain [rr*1024+cc] (og)
// ---------------------------------------------------------------------------
template <int MODE>
__global__ __launch_bounds__(256) void gemm_bf16(
    const __hip_bfloat16* __restrict__ A, const __hip_bfloat16* __restrict__ W,
    void* __restrict__ outA, void* __restrict__ outB, int N,
    const float* __restrict__ Lp) {
  __shared__ __hip_bfloat16 As[128 * 32];
  __shared__ __hip_bfloat16 Bs[128 * 32];
  const int tid = threadIdx.x;
  const int w = tid >> 6, lane = tid & 63;
  const int bm = blockIdx.y * 128, bn = blockIdx.x * 128;

  const int sr = tid >> 2, sp = tid & 3;
  const int g0 = sp ^ ((sr >> 1) & 3);
  const __hip_bfloat16* a0 = A + (size_t)(bm + sr) * kK + g0 * 8;
  const __hip_bfloat16* a1 = A + (size_t)(bm + sr + 64) * kK + g0 * 8;
  const __hip_bfloat16* b0 = W + (size_t)(bn + sr) * kK + g0 * 8;
  const __hip_bfloat16* b1 = W + (size_t)(bn + sr + 64) * kK + g0 * 8;
  char* AsB = (char*)As + w * 1024;
  char* BsB = (char*)Bs + w * 1024;

  const int wr = w >> 1, wc = w & 1;
  const int fr = lane & 15, fc = lane >> 4;
  int aOff[4], bOff[4];
#pragma unroll
  for (int f = 0; f < 4; f++) {
    const int ra = wr * 64 + f * 16 + fr;
    aOff[f] = ra * 64 + ((fc ^ ((ra >> 1) & 3)) * 16);
    const int rb = wc * 64 + f * 16 + fr;
    bOff[f] = rb * 64 + ((fc ^ ((rb >> 1) & 3)) * 16);
  }

  f32x4 acc[4][4];
#pragma unroll
  for (int i = 0; i < 4; i++)
#pragma unroll
    for (int j = 0; j < 4; j++) acc[i][j] = (f32x4){0.f, 0.f, 0.f, 0.f};

  for (int k0 = 0; k0 < kK; k0 += 32) {
    __syncthreads();
    glds16(a0 + k0, AsB);
    glds16(a1 + k0, AsB + 4096);
    glds16(b0 + k0, BsB);
    glds16(b1 + k0, BsB + 4096);
    __syncthreads();

    bf16x8 af[4], bfr[4];
#pragma unroll
    for (int f = 0; f < 4; f++) af[f] = *(const bf16x8*)((const char*)As + aOff[f]);
#pragma unroll
    for (int f = 0; f < 4; f++) bfr[f] = *(const bf16x8*)((const char*)Bs + bOff[f]);
#pragma unroll
    for (int i = 0; i < 4; i++)
#pragma unroll
      for (int j = 0; j < 4; j++)
        acc[i][j] = __builtin_amdgcn_mfma_f32_16x16x32_bf16(af[i], bfr[j], acc[i][j], 0, 0, 0);
  }

  const int r0 = bm + wr * 64, c0 = bn + wc * 64;
#pragma unroll
  for (int i = 0; i < 4; i++)
#pragma unroll
    for (int j = 0; j < 4; j++)
#pragma unroll
      for (int e = 0; e < 4; e++) {
        const int rr = r0 + i * 16 + fc * 4 + e;
        const int cc = c0 + j * 16 + fr;
        float vx = acc[i][j][e];
        if constexpr (MODE == 0) {
          ((float*)outA)[(size_t)rr * N + cc] = vx;
        } else if constexpr (MODE == 4) {
          const float y = Lp[cc] * vx;
          vx = fmaxf(y, 0.f) + log1pf(expf(-fabsf(y)));
          ((float*)outA)[(size_t)rr * N + cc] = vx;
        } else if constexpr (MODE == 3) {
          const float s = 1.f / (1.f + expf(-vx));
          const int b = rr >> 11, tok = rr & 2047, chn = tok >> 6, tt = tok & 63;
          if (cc < 48) {
            const int hh = cc / 3, j3 = cc - hh * 3;
            ((float*)outA)[(size_t)((b * 16 + hh) * 32 + chn) * 192 + tt * 3 + j3] = s;
          } else if (cc < 64) {
            const int hh = cc - 48;
            ((float*)outB)[(size_t)((b * 16 + hh) * 32 + chn) * 64 + tt] = s;
          }
        } else if constexpr (MODE == 5) {
          vx = vx / (1.f + expf(-vx));
          const int b = rr >> 11, tok = rr & 2047, chn = tok >> 6, tt = tok & 63;
          const int hh = cc / 192, rem = cc - hh * 192;
          const int d = rem / 3, j3 = rem - d * 3;
          ((__hip_bfloat16*)outA)[(size_t)((b * 16 + hh) * 32 + chn) * 12288 +
                                  (tt * 3 + j3) * 64 + d] = __float2bfloat16(vx);
        } else if constexpr (MODE == 6) {
          const int b = rr >> 11, tok = rr & 2047, chn = tok >> 6, tt = tok & 63;
          const int hh = cc >> 6, d = cc & 63;
          ((__hip_bfloat16*)outA)[(size_t)((b * 16 + hh) * 32 + chn) * 4096 +
                                  tt * 64 + d] = __float2bfloat16(vx);
        } else if constexpr (MODE == 7) {
          ((__hip_bfloat16*)outA)[(size_t)rr * 1024 + cc] = __float2bfloat16(vx);
        }
      }
}

// ---------------------------------------------------------------------------
__global__ void cast_bf16(const float* __restrict__ in, __hip_bfloat16* __restrict__ out, int n) {
  const int i = (blockIdx.x * 256 + threadIdx.x) * 4;
  if (i >= n) return;
  const float4 v = *(const float4*)(in + i);
  __hip_bfloat16 tmp[4] = {__float2bfloat16(v.x), __float2bfloat16(v.y),
                           __float2bfloat16(v.z), __float2bfloat16(v.w)};
  *(ushort4*)(out + i) = *(ushort4*)tmp;
}

__global__ void cast_bd(const float* __restrict__ Wb, const float* __restrict__ Wa,
                        __hip_bfloat16* __restrict__ out) {
  const int idx = blockIdx.x * 256 + threadIdx.x;
  if (idx >= 128 * 1024) return;
  const int r = idx >> 10, k = idx & 1023;
  const float val = (r < 48) ? Wb[r * 1024 + k] : ((r < 64) ? Wa[(r - 48) * 1024 + k] : 0.f);
  out[idx] = __float2bfloat16(val);
}

__global__ void lwc_mean(const float* __restrict__ lw, float* __restrict__ lwc) {
  const int idx = blockIdx.x * 256 + threadIdx.x;
  if (idx >= kB * kNc * kH * 16) return;
  const int l = idx & 15, h = (idx >> 4) & 15, c = (idx >> 8) & 31, b = idx >> 13;
  size_t base = ((size_t)b * kT + (size_t)c * kC) * 256 + h * 16 + l;
  float s = 0.f;
  for (int tt = 0; tt < kC; tt++) s += lw[base + (size_t)tt * 256];
  lwc[idx] = s * (1.f / 64.f);
}

// ---------------------------------------------------------------------------
// gram_phi: per-chunk-head. S = [K(192); Q(64)] (256x64 bf16). Out = S*K^T.
// Rows <192 -> G tiles (bf16, packed lower 6 tiles); rows >=192 -> PhiM
// (masked QK^T, no beta) into Astk rows 64..127. Also writes KT (K^T) into
// Astk rows 0..63 (transposed from LDS).
// ---------------------------------------------------------------------------
__global__ __launch_bounds__(256, 1) void gram_phi(
    const __hip_bfloat16* __restrict__ KP16, const __hip_bfloat16* __restrict__ qpack,
    __hip_bfloat16* __restrict__ G16, __hip_bfloat16* __restrict__ Astk) {
  const int ch = blockIdx.x;
  const int tid = threadIdx.x;
  const int w = tid >> 6, lane = tid & 63;
  __shared__ __hip_bfloat16 Sa[256 * 64];  // row-swizzled

  for (int cidx = tid; cidx < 2048; cidx += 256) {
    const int r = cidx >> 3, cko = cidx & 7;
    const __hip_bfloat16* src =
        (r < 192) ? (KP16 + (size_t)ch * 12288 + r * 64 + cko * 8)
                  : (qpack + (size_t)ch * 4096 + (r - 192) * 64 + cko * 8);
    bf16x8 vv = *(const bf16x8*)src;
    *(bf16x8*)((char*)Sa + r * 128 + ((cko ^ ((r >> 1) & 3)) * 16)) = vv;
  }
  __syncthreads();

  const int fr = lane & 15, fc = lane >> 4;
  f32x4 acc[4][12];
#pragma unroll
  for (int i = 0; i < 4; i++)
#pragma unroll
    for (int j = 0; j < 12; j++) acc[i][j] = (f32x4){0.f, 0.f, 0.f, 0.f};

#pragma unroll
  for (int ks = 0; ks < 2; ks++) {
    bf16x8 af[4];
#pragma unroll
    for (int i = 0; i < 4; i++) {
      const int ra = w * 64 + i * 16 + fr;
      af[i] = *(const bf16x8*)((char*)Sa + ra * 128 + (((ks * 4 + fc) ^ ((ra >> 1) & 3)) * 16));
    }
#pragma unroll
    for (int j = 0; j < 12; j++) {
      const int rb = j * 16 + fr;
      bf16x8 bfv = *(const bf16x8*)((char*)Sa + rb * 128 + (((ks * 4 + fc) ^ ((rb >> 1) & 3)) * 16));
#pragma unroll
      for (int i = 0; i < 4; i++)
        acc[i][j] = __builtin_amdgcn_mfma_f32_16x16x32_bf16(af[i], bfv, acc[i][j], 0, 0, 0);
    }
  }

#pragma unroll
  for (int i = 0; i < 4; i++)
#pragma unroll
    for (int j = 0; j < 12; j++)
#pragma unroll
      for (int e = 0; e < 4; e++) {
        const int gr = w * 64 + i * 16 + fc * 4 + e;
        const int gc = j * 16 + fr;
        const float val = acc[i][j][e];
        if (gr < 192) {
          const int sbb = gr >> 6, jbb = gc >> 6;
          if (jbb <= sbb)
            G16[(size_t)ch * 24576 + (size_t)(sbb * (sbb + 1) / 2 + jbb) * 4096 +
                (gr & 63) * 64 + (gc & 63)] = __float2bfloat16(val);
        } else {
          const int t = gr - 192;
          const float mval = ((gc / 3) <= t) ? val : 0.f;
          Astk[(size_t)ch * 24576 + (size_t)(64 + t) * 192 + gc] = __float2bfloat16(mval);
        }
      }

  // KT rows: Astk[ch][d][i] = K[i][d] (from swizzled LDS)
  for (int s = tid; s < 1536; s += 256) {
    const int d = s / 24, i0 = (s % 24) * 8;
    __hip_bfloat16 tmp[8];
#pragma unroll
    for (int e = 0; e < 8; e++) {
      const int i = i0 + e;
      tmp[e] = *(const __hip_bfloat16*)((char*)Sa + i * 128 +
                                        (((d >> 3) ^ ((i >> 1) & 3)) * 16) + (d & 7) * 2);
    }
    *(bf16x8*)(Astk + (size_t)ch * 24576 + (size_t)d * 192 + i0) = *(bf16x8*)tmp;
  }
}

// ---------------------------------------------------------------------------
// chunk_solve: grid (1024, 2). Solves (I + Ltil) Xt = Rt, Ltil[i][j] =
// beta_j*G[i][j] (strict lower). pass0: Rt = K; pass1: Rt = V / c_i.
// Writes Bt[col][i] = beta_i * Xt[i][col] (bf16) IN-PLACE over its RHS strip.
// ---------------------------------------------------------------------------
__global__ __launch_bounds__(256, 2) void chunk_solve(
    const __hip_bfloat16* __restrict__ G16,
    __hip_bfloat16* __restrict__ KP16, __hip_bfloat16* __restrict__ VP16,
    const float* __restrict__ betp, const float* __restrict__ decp) {
  const int ch = blockIdx.x;
  const int pass = blockIdx.y;
  const int tid = threadIdx.x;
  __shared__ float X[192][64];
  __shared__ float tile[64 * 64];
  __shared__ float bet[192], cpre[64], rc[64];

  __hip_bfloat16* rhs = (pass ? VP16 : KP16) + (size_t)ch * 12288;

  if (tid < 192) bet[tid] = betp[(size_t)ch * 192 + tid];
  if (tid < 64) cpre[tid] = decp[(size_t)ch * 64 + tid];
  __syncthreads();
  if (tid == 0) {
    float p = 1.f;
    for (int t = 0; t < 64; t++) { p *= cpre[t]; cpre[t] = p; }
  }
  __syncthreads();
  if (tid < 64) rc[tid] = 1.f / cpre[tid];
  __syncthreads();

  // stage X (RHS)
  for (int v = tid; v < 1536; v += 256) {
    const int i = v >> 3, d0 = (v & 7) * 8;
    bf16x8 vv = *(const bf16x8*)(rhs + i * 64 + d0);
    const float sc = pass ? rc[i / 3] : 1.f;
#pragma unroll
    for (int e = 0; e < 8; e++)
      X[i][d0 + e] = __bfloat162float(*(((const __hip_bfloat16*)&vv) + e)) * sc;
  }
  __syncthreads();

  const int c2 = tid & 63, wg = tid >> 6;
  for (int sb = 0; sb < 3; sb++) {
    const int s = sb * 64;
    for (int jb = 0; jb < sb; jb++) {
      const __hip_bfloat16* gt = G16 + (size_t)ch * 24576 +
                                 (size_t)(sb * (sb + 1) / 2 + jb) * 4096;
      for (int idx = tid; idx < 4096; idx += 256)
        tile[idx] = __bfloat162float(gt[idx]) * bet[jb * 64 + (idx & 63)];
      __syncthreads();
#pragma unroll 4
      for (int n = 0; n < 16; n++) {
        const int ii = wg * 16 + n;
        float acc = X[s + ii][c2];
#pragma unroll 8
        for (int jj = 0; jj < 64; jj++)
          acc = fmaf(-tile[ii * 64 + jj], X[jb * 64 + jj][c2], acc);
        X[s + ii][c2] = acc;
      }
      __syncthreads();
    }
    const __hip_bfloat16* gt = G16 + (size_t)ch * 24576 +
                               (size_t)(sb * (sb + 1) / 2 + sb) * 4096;
    for (int idx = tid; idx < 4096; idx += 256)
      tile[idx] = __bfloat162float(gt[idx]) * bet[s + (idx & 63)];
    __syncthreads();
    if (tid < 64) {
      for (int ii = 1; ii < 64; ii++) {
        float acc = X[s + ii][tid];
        for (int jj = 0; jj < ii; jj++)
          acc = fmaf(-tile[ii * 64 + jj], X[s + jj][tid], acc);
        X[s + ii][tid] = acc;
      }
    }
    __syncthreads();
  }

  // write Bt over the rhs strip
  for (int v = tid; v < 1536; v += 256) {
    const int col = v / 24, i0 = (v % 24) * 8;
    __hip_bfloat16 tmp[8];
#pragma unroll
    for (int e = 0; e < 8; e++)
      tmp[e] = __float2bfloat16(bet[i0 + e] * X[i0 + e][col]);
    *(bf16x8*)(rhs + col * 192 + i0) = *(bf16x8*)tmp;
  }
}

// ---------------------------------------------------------------------------
// products: per ch. Out(128x128) = Astk(128x192) x Bt(128x192)^T-NT.
// A rows: 0-63 KT, 64-127 PhiM. B rows: 0-63 Bt_K (KP strip), 64-127 Bt_V (VP).
// Epilogue: Tc = cC(I - KT*BtK), Bc = cC*KT*BtV (f32 -> KP strip),
// Qe = c_t(q - PhiM*BtK), Vo = c_t*PhiM*BtV (f32 -> VP strip).
// ---------------------------------------------------------------------------
__global__ __launch_bounds__(256) void products(
    const __hip_bfloat16* __restrict__ Astk,
    const __hip_bfloat16* __restrict__ KP16, const __hip_bfloat16* __restrict__ VP16,
    const __hip_bfloat16* __restrict__ qpack, const float* __restrict__ decp,
    float* __restrict__ Tc, float* __restrict__ Qe,
    float* __restrict__ BcW, float* __restrict__ VoW) {
  const int ch = blockIdx.x;
  const int tid = threadIdx.x;
  const int w = tid >> 6, lane = tid & 63;
  __shared__ __hip_bfloat16 As[128 * 32];
  __shared__ __hip_bfloat16 Bs[128 * 32];
  __shared__ float cpre[64];

  if (tid < 64) cpre[tid] = decp[(size_t)ch * 64 + tid];
  __syncthreads();
  if (tid == 0) {
    float p = 1.f;
    for (int t = 0; t < 64; t++) { p *= cpre[t]; cpre[t] = p; }
  }

  const int sr = tid >> 2, sp = tid & 3;
  const int g0 = sp ^ ((sr >> 1) & 3);
  const __hip_bfloat16* a0 = Astk + (size_t)ch * 24576 + sr * 192 + g0 * 8;
  const __hip_bfloat16* a1 = a0 + 64 * 192;
  const __hip_bfloat16* b0 = KP16 + (size_t)ch * 12288 + sr * 192 + g0 * 8;
  const __hip_bfloat16* b1 = VP16 + (size_t)ch * 12288 + sr * 192 + g0 * 8;
  char* AsB = (char*)As + w * 1024;
  char* BsB = (char*)Bs + w * 1024;

  const int wr = w >> 1, wc = w & 1;
  const int fr = lane & 15, fc = lane >> 4;
  int aOff[4], bOff[4];
#pragma unroll
  for (int f = 0; f < 4; f++) {
    const int ra = wr * 64 + f * 16 + fr;
    aOff[f] = ra * 64 + ((fc ^ ((ra >> 1) & 3)) * 16);
    const int rb = wc * 64 + f * 16 + fr;
    bOff[f] = rb * 64 + ((fc ^ ((rb >> 1) & 3)) * 16);
  }

  f32x4 acc[4][4];
#pragma unroll
  for (int i = 0; i < 4; i++)
#pragma unroll
    for (int j = 0; j < 4; j++) acc[i][j] = (f32x4){0.f, 0.f, 0.f, 0.f};

  for (int k0 = 0; k0 < 192; k0 += 32) {
    __syncthreads();
    glds16(a0 + k0, AsB);
    glds16(a1 + k0, AsB + 4096);
    glds16(b0 + k0, BsB);
    glds16(b1 + k0, BsB + 4096);
    __syncthreads();

    bf16x8 af[4], bfr[4];
#pragma unroll
    for (int f = 0; f < 4; f++) af[f] = *(const bf16x8*)((const char*)As + aOff[f]);
#pragma unroll
    for (int f = 0; f < 4; f++) bfr[f] = *(const bf16x8*)((const char*)Bs + bOff[f]);
#pragma unroll
    for (int i = 0; i < 4; i++)
#pragma unroll
      for (int j = 0; j < 4; j++)
        acc[i][j] = __builtin_amdgcn_mfma_f32_16x16x32_bf16(af[i], bfr[j], acc[i][j], 0, 0, 0);
  }
  __syncthreads();

  const float cC = cpre[63];
#pragma unroll
  for (int i = 0; i < 4; i++)
#pragma unroll
    for (int j = 0; j < 4; j++)
#pragma unroll
      for (int e = 0; e < 4; e++) {
        const int rr = wr * 64 + i * 16 + fc * 4 + e;
        const int cc = wc * 64 + j * 16 + fr;
        const float val = acc[i][j][e];
        if (rr < 64) {
          if (cc < 64)
            Tc[(size_t)ch * 4096 + rr * 64 + cc] = cC * (((rr == cc) ? 1.f : 0.f) - val);
          else
            BcW[(size_t)ch * 6144 + rr * 64 + (cc - 64)] = cC * val;
        } else {
          const int t = rr - 64;
          const float ct = cpre[t];
          if (cc < 64) {
            const float qv = __bfloat162float(qpack[(size_t)ch * 4096 + t * 64 + cc]);
            Qe[(size_t)ch * 4096 + t * 64 + cc] = ct * (qv - val);
          } else {
            VoW[(size_t)ch * 6144 + t * 64 + (cc - 64)] = ct * val;
          }
        }
      }
}

// ---------------------------------------------------------------------------
// chunk_scan: 64 blocks = (b,h) x v-half. Level states in LDS.
// ---------------------------------------------------------------------------
__global__ __launch_bounds__(256) void chunk_scan(
    const float* __restrict__ Tc, const float* __restrict__ Qe,
    const float* __restrict__ BcS, const float* __restrict__ VoS,
    const float* __restrict__ lwcb, float* __restrict__ Obuf) {
  const int blk = blockIdx.x;
  const int bh = blk >> 1, vh = blk & 1;
  const int b = bh >> 4, h = bh & 15;
  const int vbase = vh * 32;
  const int tid = threadIdx.x;
  const int v = tid & 31;
  const int tg = tid >> 5;

  __shared__ float stL[6][64][32];
  __shared__ float S0s[64][32];
  __shared__ float QT[64][64];
  __shared__ float BV[64][32];

  for (int idx = tid; idx < 6 * 2048; idx += 256) ((float*)stL)[idx] = 0.f;
  __syncthreads();

  float sf[8];
  for (int c = 0; c < 32; c++) {
    const size_t ch = (size_t)bh * 32 + c;
    const float* lwp = lwcb + ((size_t)(b * kNc + c) * kH + h) * 16;
    float lw[6];
#pragma unroll
    for (int l = 0; l < 6; l++) lw[l] = lwp[l];

#pragma unroll
    for (int n = 0; n < 8; n++) {
      const int k = n * 8 + tg;
      float s = 0.f;
#pragma unroll
      for (int l = 0; l < 6; l++) s = fmaf(lw[l], stL[l][k][v], s);
      S0s[k][v] = s;
    }
    for (int idx = tid; idx < 4096; idx += 256) QT[idx >> 6][idx & 63] = Qe[ch * 4096 + idx];
    for (int idx = tid; idx < 2048; idx += 256)
      BV[idx >> 5][idx & 31] = VoS[ch * 6144 + (idx >> 5) * 64 + vbase + (idx & 31)];
    __syncthreads();

#pragma unroll 2
    for (int n = 0; n < 8; n++) {
      const int t = n * 8 + tg;
      float o = BV[t][v];
#pragma unroll 8
      for (int k = 0; k < 64; k++) o = fmaf(QT[t][k], S0s[k][v], o);
      Obuf[ch * 4096 + t * 64 + vbase + v] = o;
    }
    __syncthreads();

    for (int idx = tid; idx < 4096; idx += 256) QT[idx >> 6][idx & 63] = Tc[ch * 4096 + idx];
    for (int idx = tid; idx < 2048; idx += 256)
      BV[idx >> 5][idx & 31] = BcS[ch * 6144 + (idx >> 5) * 64 + vbase + (idx & 31)];
    __syncthreads();

#pragma unroll 2
    for (int n = 0; n < 8; n++) {
      const int r = n * 8 + tg;
      float s = BV[r][v];
#pragma unroll 8
      for (int k = 0; k < 64; k++) s = fmaf(QT[r][k], S0s[k][v], s);
      sf[n] = s;
    }
    const int lev = __builtin_ctz(c + 1);
#pragma unroll
    for (int n = 0; n < 8; n++) {
      const int r = n * 8 + tg;
      float s = sf[n];
      for (int l = 0; l < lev; l++) { s += stL[l][r][v]; stL[l][r][v] = 0.f; }
      stL[lev][r][v] = s;
    }
    __syncthreads();
  }
}

// ---------------------------------------------------------------------------
__global__ __launch_bounds__(256) void gn_stats(const float* __restrict__ Obuf,
                                                float* __restrict__ stats) {
  const int bh = blockIdx.x;
  double sum = 0.0, sumsq = 0.0;
  for (int idx = threadIdx.x; idx < kNc * 4096; idx += 256) {
    const float val = Obuf[(size_t)bh * 131072 + idx];
    sum += val;
    sumsq += (double)val * val;
  }
  __shared__ double sred[256], qred[256];
  sred[threadIdx.x] = sum;
  qred[threadIdx.x] = sumsq;
  __syncthreads();
  for (int stp = 128; stp > 0; stp >>= 1) {
    if (threadIdx.x < stp) {
      sred[threadIdx.x] += sred[threadIdx.x + stp];
      qred[threadIdx.x] += qred[threadIdx.x + stp];
    }
    __syncthreads();
  }
  if (threadIdx.x == 0) {
    const double n = (double)kT * 64.0;
    const double mu = sred[0] / n;
    const double var = qred[0] / n - mu * mu;
    stats[bh * 2] = (float)mu;
    stats[bh * 2 + 1] = (float)(1.0 / sqrt(var + 1e-5));
  }
}

__global__ void gate_kernel(const float* __restrict__ Obuf,
                            const __hip_bfloat16* __restrict__ og,
                            const float* __restrict__ gamma, const float* __restrict__ gbeta,
                            const float* __restrict__ stats, __hip_bfloat16* __restrict__ z) {
  const size_t idx = (size_t)blockIdx.x * 256 + threadIdx.x;
  if (idx >= (size_t)kM * 1024) return;
  const int cidx = (int)(idx & 1023);
  const int h = cidx >> 6, v = cidx & 63;
  const size_t m = idx >> 10;
  const int b = (int)(m >> 11);
  const int tok = (int)(m & 2047), c = tok >> 6, tt = tok & 63;
  const float o = Obuf[(size_t)((b * 16 + h) * 32 + c) * 4096 + tt * 64 + v];
  const float mu = stats[(b * 16 + h) * 2];
  const float rstd = stats[(b * 16 + h) * 2 + 1];
  const float val = (o - mu) * rstd * gamma[cidx] + gbeta[cidx];
  const float gt = __bfloat162float(og[idx]);
  z[idx] = __float2bfloat16(val * (1.f / (1.f + expf(-gt))));
}

// ---------------------------------------------------------------------------
extern "C" void kernel_launch(void* const* d_in, const int* in_sizes, int n_in,
                              void* d_out, int out_size, void* d_ws, size_t ws_size,
                              hipStream_t stream) {
  const float* x     = (const float*)d_in[0];
  const float* Wq    = (const float*)d_in[3];
  const float* Wk    = (const float*)d_in[4];
  const float* Wv    = (const float*)d_in[5];
  const float* Wb    = (const float*)d_in[6];
  const float* Wa    = (const float*)d_in[7];
  const float* Wg    = (const float*)d_in[8];
  const float* Wo    = (const float*)d_in[9];
  const float* Wl    = (const float*)d_in[10];
  const float* Lp    = (const float*)d_in[11];
  const float* gamma = (const float*)d_in[12];
  const float* gbeta = (const float*)d_in[13];
  float* out = (float*)d_out;
  (void)ws_size;  // peak usage 170,984,448 B < 181,469,440 proven in round 1

  char* base = (char*)d_ws;
  // P1: qpack -> zbf
  __hip_bfloat16* qpack = (__hip_bfloat16*)(base + 0);                 // 8,388,608
  __hip_bfloat16* zbf   = qpack;                                       // after products
  // P2/P3: kv packs -> Bt (in-place) -> Bc/Vo f32 (in-place)
  __hip_bfloat16* KP16 = (__hip_bfloat16*)(base + 8388608);            // 25,165,824
  __hip_bfloat16* VP16 = (__hip_bfloat16*)(base + 33554432);           // 25,165,824
  // P4 region (50,331,648): early = xb + weights; then G16; then Tc/Qe/Obuf
  char* P4 = base + 58720256;
  __hip_bfloat16* xb   = (__hip_bfloat16*)(P4 + 0);                    // 8,388,608
  __hip_bfloat16* Wqb  = (__hip_bfloat16*)(P4 + 8388608);              // 2,097,152
  __hip_bfloat16* Wkb  = (__hip_bfloat16*)(P4 + 10485760);             // 6,291,456
  __hip_bfloat16* Wvb  = (__hip_bfloat16*)(P4 + 16777216);             // 6,291,456
  __hip_bfloat16* Wgb  = (__hip_bfloat16*)(P4 + 23068672);             // 2,097,152
  __hip_bfloat16* Wlb  = (__hip_bfloat16*)(P4 + 25165824);             // 524,288
  __hip_bfloat16* Wbdb = (__hip_bfloat16*)(P4 + 25690112);             // 262,144
  __hip_bfloat16* G16  = (__hip_bfloat16*)P4;                          // full 50,331,648
  float* Tc   = (float*)(P4 + 0);                                      // 16,777,216
  float* Qe   = (float*)(P4 + 16777216);                               // 16,777,216
  float* Obuf = (float*)(P4 + 33554432);                               // 16,777,216
  // P5 region (50,331,648): early = lwb; then Astk
  char* P5 = base + 109051904;
  float* lwb = (float*)(P5 + 0);                                       // 4,194,304
  __hip_bfloat16* Astk = (__hip_bfloat16*)P5;                          // 50,331,648
  // P6: persistent small
  char* P6 = base + 159383552;
  float* betp  = (float*)(P6 + 0);                                     // 786,432
  float* decp  = (float*)(P6 + 786432);                                // 262,144
  float* lwcb  = (float*)(P6 + 1048576);                               // 65,536
  float* statb = (float*)(P6 + 1114112);                               // 1,024
  __hip_bfloat16* Wob = (__hip_bfloat16*)(P6 + 1115136);               // 2,097,152
  __hip_bfloat16* ogb = (__hip_bfloat16*)(P6 + 3212288);               // 8,388,608

  const dim3 blk(256);

  // casts
  cast_bf16<<<dim3(4096), blk, 0, stream>>>(x,  xb,  kM * 1024);
  cast_bf16<<<dim3(1024), blk, 0, stream>>>(Wq, Wqb, 1024 * 1024);
  cast_bf16<<<dim3(3072), blk, 0, stream>>>(Wk, Wkb, 3072 * 1024);
  cast_bf16<<<dim3(3072), blk, 0, stream>>>(Wv, Wvb, 3072 * 1024);
  cast_bf16<<<dim3(1024), blk, 0, stream>>>(Wg, Wgb, 1024 * 1024);
  cast_bf16<<<dim3(256),  blk, 0, stream>>>(Wl, Wlb, 256 * 1024);
  cast_bf16<<<dim3(1024), blk, 0, stream>>>(Wo, Wob, 1024 * 1024);
  cast_bd<<<dim3(512), blk, 0, stream>>>(Wb, Wa, Wbdb);

  // projections
  gemm_bf16<6><<<dim3(8, 32),  blk, 0, stream>>>(xb, Wqb,  qpack, nullptr, 1024, nullptr);
  gemm_bf16<5><<<dim3(24, 32), blk, 0, stream>>>(xb, Wkb,  KP16,  nullptr, 3072, nullptr);
  gemm_bf16<5><<<dim3(24, 32), blk, 0, stream>>>(xb, Wvb,  VP16,  nullptr, 3072, nullptr);
  gemm_bf16<3><<<dim3(1, 32),  blk, 0, stream>>>(xb, Wbdb, betp,  decp,    128,  nullptr);
  gemm_bf16<4><<<dim3(2, 32),  blk, 0, stream>>>(xb, Wlb,  lwb,   nullptr, 256,  Lp);
  gemm_bf16<7><<<dim3(8, 32),  blk, 0, stream>>>(xb, Wgb,  ogb,   nullptr, 1024, nullptr);

  lwc_mean<<<dim3(64), blk, 0, stream>>>(lwb, lwcb);

  // chunk operators
  gram_phi<<<dim3(1024), blk, 0, stream>>>(KP16, qpack, G16, Astk);
  chunk_solve<<<dim3(1024, 2), blk, 0, stream>>>(G16, KP16, VP16, betp, decp);
  products<<<dim3(1024), blk, 0, stream>>>(Astk, KP16, VP16, qpack, decp,
                                           Tc, Qe, (float*)KP16, (float*)VP16);

  // sequential chunk scan
  chunk_scan<<<dim3(64), blk, 0, stream>>>(Tc, Qe, (const float*)KP16, (const float*)VP16,
                                           lwcb, Obuf);

  // group norm + gate
  gn_stats<<<dim3(kB * kH), blk, 0, stream>>>(Obuf, statb);
  gate_kernel<<<dim3((kM * 1024 + 255) / 256), blk, 0, stream>>>(Obuf, ogb, gamma, gbeta,
                                                                 statb, zbf);

  // final projection
  gemm_bf16<0><<<dim3(8, 32), blk, 0, stream>>>(zbf, Wob, out, nullptr, 1024, nullptr);
}

// Round 6
// 1581.780 us; speedup vs baseline: 4.0131x; 1.0346x over previous
//
#include <hip/hip_runtime.h>
#include <hip/hip_bf16.h>
#include <math.h>

// Problem constants
constexpr int kB   = 2;
constexpr int kT   = 2048;
constexpr int kH   = 16;
constexpr int kC   = 64;    // chunk size
constexpr int kNc  = 32;    // T / C
constexpr int kM   = kB * kT;   // 4096
constexpr int kK   = 1024;

using bf16x8 = __attribute__((ext_vector_type(8))) short;
using f32x4  = __attribute__((ext_vector_type(4))) float;

__device__ __forceinline__ void glds16(const void* g, void* l) {
  __builtin_amdgcn_global_load_lds(
      (const __attribute__((address_space(1))) unsigned int*)g,
      (__attribute__((address_space(3))) unsigned int*)l, 16, 0, 0);
}

// ---------------------------------------------------------------------------
// bf16 MFMA NT-GEMM (verified structure). MODE:
//  0: f32 plain [rr*N+cc]
//  3: beta(48)/dec(16) sigmoid -> betp [ch][192] f32, decp [ch][64] f32
//  4: softplus(Lp*x) f32 plain (lw)
//  5: silu -> bf16 pack [ch][i=tt*3+j3][d]
//  6: bf16 q pack [ch][t][d]
//  7: bf16 plain [rr*1024+cc] (og)
// ---------------------------------------------------------------------------
template <int MODE>
__global__ __launch_bounds__(256) void gemm_bf16(
    const __hip_bfloat16* __restrict__ A, const __hip_bfloat16* __restrict__ W,
    void* __restrict__ outA, void* __restrict__ outB, int N,
    const float* __restrict__ Lp) {
  __shared__ __hip_bfloat16 As[128 * 32];
  __shared__ __hip_bfloat16 Bs[128 * 32];
  const int tid = threadIdx.x;
  const int w = tid >> 6, lane = tid & 63;
  const int bm = blockIdx.y * 128, bn = blockIdx.x * 128;

  const int sr = tid >> 2, sp = tid & 3;
  const int g0 = sp ^ ((sr >> 1) & 3);
  const __hip_bfloat16* a0 = A + (size_t)(bm + sr) * kK + g0 * 8;
  const __hip_bfloat16* a1 = A + (size_t)(bm + sr + 64) * kK + g0 * 8;
  const __hip_bfloat16* b0 = W + (size_t)(bn + sr) * kK + g0 * 8;
  const __hip_bfloat16* b1 = W + (size_t)(bn + sr + 64) * kK + g0 * 8;
  char* AsB = (char*)As + w * 1024;
  char* BsB = (char*)Bs + w * 1024;

  const int wr = w >> 1, wc = w & 1;
  const int fr = lane & 15, fc = lane >> 4;
  int aOff[4], bOff[4];
#pragma unroll
  for (int f = 0; f < 4; f++) {
    const int ra = wr * 64 + f * 16 + fr;
    aOff[f] = ra * 64 + ((fc ^ ((ra >> 1) & 3)) * 16);
    const int rb = wc * 64 + f * 16 + fr;
    bOff[f] = rb * 64 + ((fc ^ ((rb >> 1) & 3)) * 16);
  }

  f32x4 acc[4][4];
#pragma unroll
  for (int i = 0; i < 4; i++)
#pragma unroll
    for (int j = 0; j < 4; j++) acc[i][j] = (f32x4){0.f, 0.f, 0.f, 0.f};

  for (int k0 = 0; k0 < kK; k0 += 32) {
    __syncthreads();
    glds16(a0 + k0, AsB);
    glds16(a1 + k0, AsB + 4096);
    glds16(b0 + k0, BsB);
    glds16(b1 + k0, BsB + 4096);
    __syncthreads();

    bf16x8 af[4], bfr[4];
#pragma unroll
    for (int f = 0; f < 4; f++) af[f] = *(const bf16x8*)((const char*)As + aOff[f]);
#pragma unroll
    for (int f = 0; f < 4; f++) bfr[f] = *(const bf16x8*)((const char*)Bs + bOff[f]);
#pragma unroll
    for (int i = 0; i < 4; i++)
#pragma unroll
      for (int j = 0; j < 4; j++)
        acc[i][j] = __builtin_amdgcn_mfma_f32_16x16x32_bf16(af[i], bfr[j], acc[i][j], 0, 0, 0);
  }

  const int r0 = bm + wr * 64, c0 = bn + wc * 64;
#pragma unroll
  for (int i = 0; i < 4; i++)
#pragma unroll
    for (int j = 0; j < 4; j++)
#pragma unroll
      for (int e = 0; e < 4; e++) {
        const int rr = r0 + i * 16 + fc * 4 + e;
        const int cc = c0 + j * 16 + fr;
        float vx = acc[i][j][e];
        if constexpr (MODE == 0) {
          ((float*)outA)[(size_t)rr * N + cc] = vx;
        } else if constexpr (MODE == 4) {
          const float y = Lp[cc] * vx;
          vx = fmaxf(y, 0.f) + log1pf(expf(-fabsf(y)));
          ((float*)outA)[(size_t)rr * N + cc] = vx;
        } else if constexpr (MODE == 3) {
          const float s = 1.f / (1.f + expf(-vx));
          const int b = rr >> 11, tok = rr & 2047, chn = tok >> 6, tt = tok & 63;
          if (cc < 48) {
            const int hh = cc / 3, j3 = cc - hh * 3;
            ((float*)outA)[(size_t)((b * 16 + hh) * 32 + chn) * 192 + tt * 3 + j3] = s;
          } else if (cc < 64) {
            const int hh = cc - 48;
            ((float*)outB)[(size_t)((b * 16 + hh) * 32 + chn) * 64 + tt] = s;
          }
        } else if constexpr (MODE == 5) {
          vx = vx / (1.f + expf(-vx));
          const int b = rr >> 11, tok = rr & 2047, chn = tok >> 6, tt = tok & 63;
          const int hh = cc / 192, rem = cc - hh * 192;
          const int d = rem / 3, j3 = rem - d * 3;
          ((__hip_bfloat16*)outA)[(size_t)((b * 16 + hh) * 32 + chn) * 12288 +
                                  (tt * 3 + j3) * 64 + d] = __float2bfloat16(vx);
        } else if constexpr (MODE == 6) {
          const int b = rr >> 11, tok = rr & 2047, chn = tok >> 6, tt = tok & 63;
          const int hh = cc >> 6, d = cc & 63;
          ((__hip_bfloat16*)outA)[(size_t)((b * 16 + hh) * 32 + chn) * 4096 +
                                  tt * 64 + d] = __float2bfloat16(vx);
        } else if constexpr (MODE == 7) {
          ((__hip_bfloat16*)outA)[(size_t)rr * 1024 + cc] = __float2bfloat16(vx);
        }
      }
}

// ---------------------------------------------------------------------------
__global__ void cast_bf16(const float* __restrict__ in, __hip_bfloat16* __restrict__ out, int n) {
  const int i = (blockIdx.x * 256 + threadIdx.x) * 4;
  if (i >= n) return;
  const float4 v = *(const float4*)(in + i);
  __hip_bfloat16 tmp[4] = {__float2bfloat16(v.x), __float2bfloat16(v.y),
                           __float2bfloat16(v.z), __float2bfloat16(v.w)};
  *(ushort4*)(out + i) = *(ushort4*)tmp;
}

__global__ void cast_bd(const float* __restrict__ Wb, const float* __restrict__ Wa,
                        __hip_bfloat16* __restrict__ out) {
  const int idx = blockIdx.x * 256 + threadIdx.x;
  if (idx >= 128 * 1024) return;
  const int r = idx >> 10, k = idx & 1023;
  const float val = (r < 48) ? Wb[r * 1024 + k] : ((r < 64) ? Wa[(r - 48) * 1024 + k] : 0.f);
  out[idx] = __float2bfloat16(val);
}

__global__ void lwc_mean(const float* __restrict__ lw, float* __restrict__ lwc) {
  const int idx = blockIdx.x * 256 + threadIdx.x;
  if (idx >= kB * kNc * kH * 16) return;
  const int l = idx & 15, h = (idx >> 4) & 15, c = (idx >> 8) & 31, b = idx >> 13;
  size_t base = ((size_t)b * kT + (size_t)c * kC) * 256 + h * 16 + l;
  float s = 0.f;
  for (int tt = 0; tt < kC; tt++) s += lw[base + (size_t)tt * 256];
  lwc[idx] = s * (1.f / 64.f);
}

// ---------------------------------------------------------------------------
// gram_phi: per-chunk-head. S = [K(192); Q(64)] (256x64 bf16). Out = S*K^T.
// Rows <192 -> G tiles (bf16, packed lower 6 tiles); rows >=192 -> PhiM
// (masked QK^T, no beta) into Astk rows 64..127. Also writes KT (K^T) into
// Astk rows 0..63 (transposed from LDS).
// ---------------------------------------------------------------------------
__global__ __launch_bounds__(256, 1) void gram_phi(
    const __hip_bfloat16* __restrict__ KP16, const __hip_bfloat16* __restrict__ qpack,
    __hip_bfloat16* __restrict__ G16, __hip_bfloat16* __restrict__ Astk) {
  const int ch = blockIdx.x;
  const int tid = threadIdx.x;
  const int w = tid >> 6, lane = tid & 63;
  __shared__ __hip_bfloat16 Sa[256 * 64];  // row-swizzled

  for (int cidx = tid; cidx < 2048; cidx += 256) {
    const int r = cidx >> 3, cko = cidx & 7;
    const __hip_bfloat16* src =
        (r < 192) ? (KP16 + (size_t)ch * 12288 + r * 64 + cko * 8)
                  : (qpack + (size_t)ch * 4096 + (r - 192) * 64 + cko * 8);
    bf16x8 vv = *(const bf16x8*)src;
    *(bf16x8*)((char*)Sa + r * 128 + ((cko ^ ((r >> 1) & 3)) * 16)) = vv;
  }
  __syncthreads();

  const int fr = lane & 15, fc = lane >> 4;
  f32x4 acc[4][12];
#pragma unroll
  for (int i = 0; i < 4; i++)
#pragma unroll
    for (int j = 0; j < 12; j++) acc[i][j] = (f32x4){0.f, 0.f, 0.f, 0.f};

#pragma unroll
  for (int ks = 0; ks < 2; ks++) {
    bf16x8 af[4];
#pragma unroll
    for (int i = 0; i < 4; i++) {
      const int ra = w * 64 + i * 16 + fr;
      af[i] = *(const bf16x8*)((char*)Sa + ra * 128 + (((ks * 4 + fc) ^ ((ra >> 1) & 3)) * 16));
    }
#pragma unroll
    for (int j = 0; j < 12; j++) {
      const int rb = j * 16 + fr;
      bf16x8 bfv = *(const bf16x8*)((char*)Sa + rb * 128 + (((ks * 4 + fc) ^ ((rb >> 1) & 3)) * 16));
#pragma unroll
      for (int i = 0; i < 4; i++)
        acc[i][j] = __builtin_amdgcn_mfma_f32_16x16x32_bf16(af[i], bfv, acc[i][j], 0, 0, 0);
    }
  }

#pragma unroll
  for (int i = 0; i < 4; i++)
#pragma unroll
    for (int j = 0; j < 12; j++)
#pragma unroll
      for (int e = 0; e < 4; e++) {
        const int gr = w * 64 + i * 16 + fc * 4 + e;
        const int gc = j * 16 + fr;
        const float val = acc[i][j][e];
        if (gr < 192) {
          const int sbb = gr >> 6, jbb = gc >> 6;
          if (jbb <= sbb)
            G16[(size_t)ch * 24576 + (size_t)(sbb * (sbb + 1) / 2 + jbb) * 4096 +
                (gr & 63) * 64 + (gc & 63)] = __float2bfloat16(val);
        } else {
          const int t = gr - 192;
          const float mval = ((gc / 3) <= t) ? val : 0.f;
          Astk[(size_t)ch * 24576 + (size_t)(64 + t) * 192 + gc] = __float2bfloat16(mval);
        }
      }

  // KT rows: Astk[ch][d][i] = K[i][d] (from swizzled LDS)
  for (int s = tid; s < 1536; s += 256) {
    const int d = s / 24, i0 = (s % 24) * 8;
    __hip_bfloat16 tmp[8];
#pragma unroll
    for (int e = 0; e < 8; e++) {
      const int i = i0 + e;
      tmp[e] = *(const __hip_bfloat16*)((char*)Sa + i * 128 +
                                        (((d >> 3) ^ ((i >> 1) & 3)) * 16) + (d & 7) * 2);
    }
    *(bf16x8*)(Astk + (size_t)ch * 24576 + (size_t)d * 192 + i0) = *(bf16x8*)tmp;
  }
}

// ---------------------------------------------------------------------------
// chunk_solve (merged passes): one block per ch solves (I + Ltil) Xt = [K | V/c]
// with Ltil[i][j] = beta_j*G[i][j] (strict lower), RHS width 128.
// Diagonal 64-blocks are solved with 16-sub-blocking: serial 16-row solves
// (<=15-deep chains, 128 lanes active) + parallel rank-16 trailing updates
// (all 256 threads). X row stride padded to 133 floats (bank decorrelation).
// Writes Bt[col][i] = beta_i * Xt[i][col] (bf16) in-place over the RHS strips.
// ---------------------------------------------------------------------------
__global__ __launch_bounds__(256) void chunk_solve(
    const __hip_bfloat16* __restrict__ G16,
    __hip_bfloat16* __restrict__ KP16, __hip_bfloat16* __restrict__ VP16,
    const float* __restrict__ betp, const float* __restrict__ decp) {
  const int ch = blockIdx.x;
  const int tid = threadIdx.x;
  constexpr int XS = 133;  // padded row stride (odd -> banks decorrelate)
  __shared__ float X[192 * XS];        // 102,144 B
  __shared__ float tile[64 * 65];      //  16,640 B
  __shared__ float bet[192], cpre[64], rc[64];

  if (tid < 192) bet[tid] = betp[(size_t)ch * 192 + tid];
  if (tid < 64) cpre[tid] = decp[(size_t)ch * 64 + tid];
  __syncthreads();
  if (tid == 0) {
    float p = 1.f;
    for (int t = 0; t < 64; t++) { p *= cpre[t]; cpre[t] = p; }
  }
  __syncthreads();
  if (tid < 64) rc[tid] = 1.f / cpre[tid];
  __syncthreads();

  // stage RHS: X[i][0..63] = K[i][:]; X[i][64..127] = V[i][:] / c_{tau(i)}
  for (int v = tid; v < 3072; v += 256) {
    const bool isV = v >= 1536;
    const int vv = isV ? (v - 1536) : v;
    const int i = vv >> 3, d0 = (vv & 7) * 8;
    const __hip_bfloat16* src = (isV ? VP16 : KP16) + (size_t)ch * 12288 + i * 64 + d0;
    bf16x8 vb8 = *(const bf16x8*)src;
    const float sc = isV ? rc[i / 3] : 1.f;
    const int cb = isV ? 64 : 0;
#pragma unroll
    for (int e = 0; e < 8; e++)
      X[i * XS + cb + d0 + e] =
          __bfloat162float(*(((const __hip_bfloat16*)&vb8) + e)) * sc;
  }
  __syncthreads();

  const int col2 = tid & 127;   // RHS column
  const int rg = tid >> 7;      // row group (0/1)

  for (int sb = 0; sb < 3; sb++) {
    const int s = sb * 64;
    // off-diagonal rank-64 updates (parallel, all 256 threads)
    for (int jb = 0; jb < sb; jb++) {
      const __hip_bfloat16* gt = G16 + (size_t)ch * 24576 +
                                 (size_t)(sb * (sb + 1) / 2 + jb) * 4096;
      for (int idx = tid; idx < 4096; idx += 256)
        tile[(idx >> 6) * 65 + (idx & 63)] =
            __bfloat162float(gt[idx]) * bet[jb * 64 + (idx & 63)];
      __syncthreads();
      for (int r = rg; r < 64; r += 2) {
        float acc = X[(s + r) * XS + col2];
#pragma unroll 8
        for (int jj = 0; jj < 64; jj++)
          acc = fmaf(-tile[r * 65 + jj], X[(jb * 64 + jj) * XS + col2], acc);
        X[(s + r) * XS + col2] = acc;
      }
      __syncthreads();
    }
    // stage diagonal Ltil block
    {
      const __hip_bfloat16* gt = G16 + (size_t)ch * 24576 +
                                 (size_t)(sb * (sb + 1) / 2 + sb) * 4096;
      for (int idx = tid; idx < 4096; idx += 256)
        tile[(idx >> 6) * 65 + (idx & 63)] =
            __bfloat162float(gt[idx]) * bet[s + (idx & 63)];
    }
    __syncthreads();
    // 16-sub-blocked diagonal solve
    for (int db = 0; db < 4; db++) {
      const int l0 = db * 16;
      if (tid < 128) {
        for (int ii = 1; ii < 16; ii++) {
          float acc = X[(s + l0 + ii) * XS + tid];
          for (int jj = 0; jj < ii; jj++)
            acc = fmaf(-tile[(l0 + ii) * 65 + l0 + jj], X[(s + l0 + jj) * XS + tid], acc);
          X[(s + l0 + ii) * XS + tid] = acc;
        }
      }
      __syncthreads();
      const int rem = 48 - l0;  // rows below this sub-block within the 64-block
      if (rem > 0) {
        for (int r = rg; r < rem; r += 2) {
          const int lrow = l0 + 16 + r;
          float acc = X[(s + lrow) * XS + col2];
#pragma unroll
          for (int jj = 0; jj < 16; jj++)
            acc = fmaf(-tile[lrow * 65 + l0 + jj], X[(s + l0 + jj) * XS + col2], acc);
          X[(s + lrow) * XS + col2] = acc;
        }
      }
      __syncthreads();
    }
  }

  // write Bt over the rhs strips: Bt[col][i] = beta_i * X[i][col]
  for (int v = tid; v < 3072; v += 256) {
    const int col = v / 24, i0 = (v % 24) * 8;
    __hip_bfloat16 tmp[8];
#pragma unroll
    for (int e = 0; e < 8; e++)
      tmp[e] = __float2bfloat16(bet[i0 + e] * X[(i0 + e) * XS + col]);
    __hip_bfloat16* dst = (col < 64 ? (KP16 + (size_t)ch * 12288 + col * 192)
                                    : (VP16 + (size_t)ch * 12288 + (col - 64) * 192)) + i0;
    *(bf16x8*)dst = *(bf16x8*)tmp;
  }
}

// ---------------------------------------------------------------------------
// products: per ch. Out(128x128) = Astk(128x192) x Bt(128x192)^T-NT.
// A rows: 0-63 KT, 64-127 PhiM. B rows: 0-63 Bt_K (KP strip), 64-127 Bt_V (VP).
// Epilogue: Tc = cC(I - KT*BtK), Bc = cC*KT*BtV (f32 -> KP strip),
// Qe = c_t(q - PhiM*BtK), Vo = c_t*PhiM*BtV (f32 -> VP strip).
// ---------------------------------------------------------------------------
__global__ __launch_bounds__(256) void products(
    const __hip_bfloat16* __restrict__ Astk,
    const __hip_bfloat16* __restrict__ KP16, const __hip_bfloat16* __restrict__ VP16,
    const __hip_bfloat16* __restrict__ qpack, const float* __restrict__ decp,
    float* __restrict__ Tc, float* __restrict__ Qe,
    float* __restrict__ BcW, float* __restrict__ VoW) {
  const int ch = blockIdx.x;
  const int tid = threadIdx.x;
  const int w = tid >> 6, lane = tid & 63;
  __shared__ __hip_bfloat16 As[128 * 32];
  __shared__ __hip_bfloat16 Bs[128 * 32];
  __shared__ float cpre[64];

  if (tid < 64) cpre[tid] = decp[(size_t)ch * 64 + tid];
  __syncthreads();
  if (tid == 0) {
    float p = 1.f;
    for (int t = 0; t < 64; t++) { p *= cpre[t]; cpre[t] = p; }
  }

  const int sr = tid >> 2, sp = tid & 3;
  const int g0 = sp ^ ((sr >> 1) & 3);
  const __hip_bfloat16* a0 = Astk + (size_t)ch * 24576 + sr * 192 + g0 * 8;
  const __hip_bfloat16* a1 = a0 + 64 * 192;
  const __hip_bfloat16* b0 = KP16 + (size_t)ch * 12288 + sr * 192 + g0 * 8;
  const __hip_bfloat16* b1 = VP16 + (size_t)ch * 12288 + sr * 192 + g0 * 8;
  char* AsB = (char*)As + w * 1024;
  char* BsB = (char*)Bs + w * 1024;

  const int wr = w >> 1, wc = w & 1;
  const int fr = lane & 15, fc = lane >> 4;
  int aOff[4], bOff[4];
#pragma unroll
  for (int f = 0; f < 4; f++) {
    const int ra = wr * 64 + f * 16 + fr;
    aOff[f] = ra * 64 + ((fc ^ ((ra >> 1) & 3)) * 16);
    const int rb = wc * 64 + f * 16 + fr;
    bOff[f] = rb * 64 + ((fc ^ ((rb >> 1) & 3)) * 16);
  }

  f32x4 acc[4][4];
#pragma unroll
  for (int i = 0; i < 4; i++)
#pragma unroll
    for (int j = 0; j < 4; j++) acc[i][j] = (f32x4){0.f, 0.f, 0.f, 0.f};

  for (int k0 = 0; k0 < 192; k0 += 32) {
    __syncthreads();
    glds16(a0 + k0, AsB);
    glds16(a1 + k0, AsB + 4096);
    glds16(b0 + k0, BsB);
    glds16(b1 + k0, BsB + 4096);
    __syncthreads();

    bf16x8 af[4], bfr[4];
#pragma unroll
    for (int f = 0; f < 4; f++) af[f] = *(const bf16x8*)((const char*)As + aOff[f]);
#pragma unroll
    for (int f = 0; f < 4; f++) bfr[f] = *(const bf16x8*)((const char*)Bs + bOff[f]);
#pragma unroll
    for (int i = 0; i < 4; i++)
#pragma unroll
      for (int j = 0; j < 4; j++)
        acc[i][j] = __builtin_amdgcn_mfma_f32_16x16x32_bf16(af[i], bfr[j], acc[i][j], 0, 0, 0);
  }
  __syncthreads();

  const float cC = cpre[63];
#pragma unroll
  for (int i = 0; i < 4; i++)
#pragma unroll
    for (int j = 0; j < 4; j++)
#pragma unroll
      for (int e = 0; e < 4; e++) {
        const int rr = wr * 64 + i * 16 + fc * 4 + e;
        const int cc = wc * 64 + j * 16 + fr;
        const float val = acc[i][j][e];
        if (rr < 64) {
          if (cc < 64)
            Tc[(size_t)ch * 4096 + rr * 64 + cc] = cC * (((rr == cc) ? 1.f : 0.f) - val);
          else
            BcW[(size_t)ch * 6144 + rr * 64 + (cc - 64)] = cC * val;
        } else {
          const int t = rr - 64;
          const float ct = cpre[t];
          if (cc < 64) {
            const float qv = __bfloat162float(qpack[(size_t)ch * 4096 + t * 64 + cc]);
            Qe[(size_t)ch * 4096 + t * 64 + cc] = ct * (qv - val);
          } else {
            VoW[(size_t)ch * 6144 + t * 64 + (cc - 64)] = ct * val;
          }
        }
      }
}

// ---------------------------------------------------------------------------
// chunk_scan: 64 blocks = (b,h) x v-half. Level states in LDS.
// ---------------------------------------------------------------------------
__global__ __launch_bounds__(256) void chunk_scan(
    const float* __restrict__ Tc, const float* __restrict__ Qe,
    const float* __restrict__ BcS, const float* __restrict__ VoS,
    const float* __restrict__ lwcb, float* __restrict__ Obuf) {
  const int blk = blockIdx.x;
  const int bh = blk >> 1, vh = blk & 1;
  const int b = bh >> 4, h = bh & 15;
  const int vbase = vh * 32;
  const int tid = threadIdx.x;
  const int v = tid & 31;
  const int tg = tid >> 5;

  __shared__ float stL[6][64][32];
  __shared__ float S0s[64][32];
  __shared__ float QT[64][64];
  __shared__ float BV[64][32];

  for (int idx = tid; idx < 6 * 2048; idx += 256) ((float*)stL)[idx] = 0.f;
  __syncthreads();

  float sf[8];
  for (int c = 0; c < 32; c++) {
    const size_t ch = (size_t)bh * 32 + c;
    const float* lwp = lwcb + ((size_t)(b * kNc + c) * kH + h) * 16;
    float lw[6];
#pragma unroll
    for (int l = 0; l < 6; l++) lw[l] = lwp[l];

#pragma unroll
    for (int n = 0; n < 8; n++) {
      const int k = n * 8 + tg;
      float s = 0.f;
#pragma unroll
      for (int l = 0; l < 6; l++) s = fmaf(lw[l], stL[l][k][v], s);
      S0s[k][v] = s;
    }
    for (int idx = tid; idx < 4096; idx += 256) QT[idx >> 6][idx & 63] = Qe[ch * 4096 + idx];
    for (int idx = tid; idx < 2048; idx += 256)
      BV[idx >> 5][idx & 31] = VoS[ch * 6144 + (idx >> 5) * 64 + vbase + (idx & 31)];
    __syncthreads();

#pragma unroll 2
    for (int n = 0; n < 8; n++) {
      const int t = n * 8 + tg;
      float o = BV[t][v];
#pragma unroll 8
      for (int k = 0; k < 64; k++) o = fmaf(QT[t][k], S0s[k][v], o);
      Obuf[ch * 4096 + t * 64 + vbase + v] = o;
    }
    __syncthreads();

    for (int idx = tid; idx < 4096; idx += 256) QT[idx >> 6][idx & 63] = Tc[ch * 4096 + idx];
    for (int idx = tid; idx < 2048; idx += 256)
      BV[idx >> 5][idx & 31] = BcS[ch * 6144 + (idx >> 5) * 64 + vbase + (idx & 31)];
    __syncthreads();

#pragma unroll 2
    for (int n = 0; n < 8; n++) {
      const int r = n * 8 + tg;
      float s = BV[r][v];
#pragma unroll 8
      for (int k = 0; k < 64; k++) s = fmaf(QT[r][k], S0s[k][v], s);
      sf[n] = s;
    }
    const int lev = __builtin_ctz(c + 1);
#pragma unroll
    for (int n = 0; n < 8; n++) {
      const int r = n * 8 + tg;
      float s = sf[n];
      for (int l = 0; l < lev; l++) { s += stL[l][r][v]; stL[l][r][v] = 0.f; }
      stL[lev][r][v] = s;
    }
    __syncthreads();
  }
}

// ---------------------------------------------------------------------------
__global__ __launch_bounds__(256) void gn_stats(const float* __restrict__ Obuf,
                                                float* __restrict__ stats) {
  const int bh = blockIdx.x;
  double sum = 0.0, sumsq = 0.0;
  for (int idx = threadIdx.x; idx < kNc * 4096; idx += 256) {
    const float val = Obuf[(size_t)bh * 131072 + idx];
    sum += val;
    sumsq += (double)val * val;
  }
  __shared__ double sred[256], qred[256];
  sred[threadIdx.x] = sum;
  qred[threadIdx.x] = sumsq;
  __syncthreads();
  for (int stp = 128; stp > 0; stp >>= 1) {
    if (threadIdx.x < stp) {
      sred[threadIdx.x] += sred[threadIdx.x + stp];
      qred[threadIdx.x] += qred[threadIdx.x + stp];
    }
    __syncthreads();
  }
  if (threadIdx.x == 0) {
    const double n = (double)kT * 64.0;
    const double mu = sred[0] / n;
    const double var = qred[0] / n - mu * mu;
    stats[bh * 2] = (float)mu;
    stats[bh * 2 + 1] = (float)(1.0 / sqrt(var + 1e-5));
  }
}

__global__ void gate_kernel(const float* __restrict__ Obuf,
                            const __hip_bfloat16* __restrict__ og,
                            const float* __restrict__ gamma, const float* __restrict__ gbeta,
                            const float* __restrict__ stats, __hip_bfloat16* __restrict__ z) {
  const size_t idx = (size_t)blockIdx.x * 256 + threadIdx.x;
  if (idx >= (size_t)kM * 1024) return;
  const int cidx = (int)(idx & 1023);
  const int h = cidx >> 6, v = cidx & 63;
  const size_t m = idx >> 10;
  const int b = (int)(m >> 11);
  const int tok = (int)(m & 2047), c = tok >> 6, tt = tok & 63;
  const float o = Obuf[(size_t)((b * 16 + h) * 32 + c) * 4096 + tt * 64 + v];
  const float mu = stats[(b * 16 + h) * 2];
  const float rstd = stats[(b * 16 + h) * 2 + 1];
  const float val = (o - mu) * rstd * gamma[cidx] + gbeta[cidx];
  const float gt = __bfloat162float(og[idx]);
  z[idx] = __float2bfloat16(val * (1.f / (1.f + expf(-gt))));
}

// ---------------------------------------------------------------------------
extern "C" void kernel_launch(void* const* d_in, const int* in_sizes, int n_in,
                              void* d_out, int out_size, void* d_ws, size_t ws_size,
                              hipStream_t stream) {
  const float* x     = (const float*)d_in[0];
  const float* Wq    = (const float*)d_in[3];
  const float* Wk    = (const float*)d_in[4];
  const float* Wv    = (const float*)d_in[5];
  const float* Wb    = (const float*)d_in[6];
  const float* Wa    = (const float*)d_in[7];
  const float* Wg    = (const float*)d_in[8];
  const float* Wo    = (const float*)d_in[9];
  const float* Wl    = (const float*)d_in[10];
  const float* Lp    = (const float*)d_in[11];
  const float* gamma = (const float*)d_in[12];
  const float* gbeta = (const float*)d_in[13];
  float* out = (float*)d_out;
  (void)ws_size;  // peak usage 170,984,448 B < 181,469,440 proven in round 1

  char* base = (char*)d_ws;
  // P1: qpack -> zbf
  __hip_bfloat16* qpack = (__hip_bfloat16*)(base + 0);                 // 8,388,608
  __hip_bfloat16* zbf   = qpack;                                       // after products
  // P2/P3: kv packs -> Bt (in-place) -> Bc/Vo f32 (in-place)
  __hip_bfloat16* KP16 = (__hip_bfloat16*)(base + 8388608);            // 25,165,824
  __hip_bfloat16* VP16 = (__hip_bfloat16*)(base + 33554432);           // 25,165,824
  // P4 region (50,331,648): early = xb + weights; then G16; then Tc/Qe/Obuf
  char* P4 = base + 58720256;
  __hip_bfloat16* xb   = (__hip_bfloat16*)(P4 + 0);                    // 8,388,608
  __hip_bfloat16* Wqb  = (__hip_bfloat16*)(P4 + 8388608);              // 2,097,152
  __hip_bfloat16* Wkb  = (__hip_bfloat16*)(P4 + 10485760);             // 6,291,456
  __hip_bfloat16* Wvb  = (__hip_bfloat16*)(P4 + 16777216);             // 6,291,456
  __hip_bfloat16* Wgb  = (__hip_bfloat16*)(P4 + 23068672);             // 2,097,152
  __hip_bfloat16* Wlb  = (__hip_bfloat16*)(P4 + 25165824);             // 524,288
  __hip_bfloat16* Wbdb = (__hip_bfloat16*)(P4 + 25690112);             // 262,144
  __hip_bfloat16* G16  = (__hip_bfloat16*)P4;                          // full 50,331,648
  float* Tc   = (float*)(P4 + 0);                                      // 16,777,216
  float* Qe   = (float*)(P4 + 16777216);                               // 16,777,216
  float* Obuf = (float*)(P4 + 33554432);                               // 16,777,216
  // P5 region (50,331,648): early = lwb; then Astk
  char* P5 = base + 109051904;
  float* lwb = (float*)(P5 + 0);                                       // 4,194,304
  __hip_bfloat16* Astk = (__hip_bfloat16*)P5;                          // 50,331,648
  // P6: persistent small
  char* P6 = base + 159383552;
  float* betp  = (float*)(P6 + 0);                                     // 786,432
  float* decp  = (float*)(P6 + 786432);                                // 262,144
  float* lwcb  = (float*)(P6 + 1048576);                               // 65,536
  float* statb = (float*)(P6 + 1114112);                               // 1,024
  __hip_bfloat16* Wob = (__hip_bfloat16*)(P6 + 1115136);               // 2,097,152
  __hip_bfloat16* ogb = (__hip_bfloat16*)(P6 + 3212288);               // 8,388,608

  const dim3 blk(256);

  // casts
  cast_bf16<<<dim3(4096), blk, 0, stream>>>(x,  xb,  kM * 1024);
  cast_bf16<<<dim3(1024), blk, 0, stream>>>(Wq, Wqb, 1024 * 1024);
  cast_bf16<<<dim3(3072), blk, 0, stream>>>(Wk, Wkb, 3072 * 1024);
  cast_bf16<<<dim3(3072), blk, 0, stream>>>(Wv, Wvb, 3072 * 1024);
  cast_bf16<<<dim3(1024), blk, 0, stream>>>(Wg, Wgb, 1024 * 1024);
  cast_bf16<<<dim3(256),  blk, 0, stream>>>(Wl, Wlb, 256 * 1024);
  cast_bf16<<<dim3(1024), blk, 0, stream>>>(Wo, Wob, 1024 * 1024);
  cast_bd<<<dim3(512), blk, 0, stream>>>(Wb, Wa, Wbdb);

  // projections
  gemm_bf16<6><<<dim3(8, 32),  blk, 0, stream>>>(xb, Wqb,  qpack, nullptr, 1024, nullptr);
  gemm_bf16<5><<<dim3(24, 32), blk, 0, stream>>>(xb, Wkb,  KP16,  nullptr, 3072, nullptr);
  gemm_bf16<5><<<dim3(24, 32), blk, 0, stream>>>(xb, Wvb,  VP16,  nullptr, 3072, nullptr);
  gemm_bf16<3><<<dim3(1, 32),  blk, 0, stream>>>(xb, Wbdb, betp,  decp,    128,  nullptr);
  gemm_bf16<4><<<dim3(2, 32),  blk, 0, stream>>>(xb, Wlb,  lwb,   nullptr, 256,  Lp);
  gemm_bf16<7><<<dim3(8, 32),  blk, 0, stream>>>(xb, Wgb,  ogb,   nullptr, 1024, nullptr);

  lwc_mean<<<dim3(64), blk, 0, stream>>>(lwb, lwcb);

  // chunk operators
  gram_phi<<<dim3(1024), blk, 0, stream>>>(KP16, qpack, G16, Astk);
  chunk_solve<<<dim3(1024), blk, 0, stream>>>(G16, KP16, VP16, betp, decp);
  products<<<dim3(1024), blk, 0, stream>>>(Astk, KP16, VP16, qpack, decp,
                                           Tc, Qe, (float*)KP16, (float*)VP16);

  // sequential chunk scan
  chunk_scan<<<dim3(64), blk, 0, stream>>>(Tc, Qe, (const float*)KP16, (const float*)VP16,
                                           lwcb, Obuf);

  // group norm + gate
  gn_stats<<<dim3(kB * kH), blk, 0, stream>>>(Obuf, statb);
  gate_kernel<<<dim3((kM * 1024 + 255) / 256), blk, 0, stream>>>(Obuf, ogb, gamma, gbeta,
                                                                 statb, zbf);

  // final projection
  gemm_bf16<0><<<dim3(8, 32), blk, 0, stream>>>(zbf, Wob, out, nullptr, 1024, nullptr);
}

// Round 7
// 1279.928 us; speedup vs baseline: 4.9595x; 1.2358x over previous
//
#include <hip/hip_runtime.h>
#include <hip/hip_bf16.h>
#include <math.h>

// Problem constants
constexpr int kB   = 2;
constexpr int kT   = 2048;
constexpr int kH   = 16;
constexpr int kC   = 64;    // chunk size
constexpr int kNc  = 32;    // T / C
constexpr int kM   = kB * kT;   // 4096
constexpr int kK   = 1024;

using bf16x8 = __attribute__((ext_vector_type(8))) short;
using f32x4  = __attribute__((ext_vector_type(4))) float;

__device__ __forceinline__ void glds16(const void* g, void* l) {
  __builtin_amdgcn_global_load_lds(
      (const __attribute__((address_space(1))) unsigned int*)g,
      (__attribute__((address_space(3))) unsigned int*)l, 16, 0, 0);
}

// ---------------------------------------------------------------------------
// bf16 MFMA NT-GEMM (verified structure). MODE:
//  0: f32 plain [rr*N+cc]
//  3: beta(48)/dec(16) sigmoid -> betp [ch][192] f32, decp [ch][64] f32
//  4: softplus(Lp*x) f32 plain (lw)
//  5: silu -> bf16 pack [ch][i=tt*3+j3][d]
//  6: bf16 q pack [ch][t][d]
//  7: bf16 plain [rr*1024+cc] (og)
// ---------------------------------------------------------------------------
template <int MODE>
__global__ __launch_bounds__(256) void gemm_bf16(
    const __hip_bfloat16* __restrict__ A, const __hip_bfloat16* __restrict__ W,
    void* __restrict__ outA, void* __restrict__ outB, int N,
    const float* __restrict__ Lp) {
  __shared__ __hip_bfloat16 As[128 * 32];
  __shared__ __hip_bfloat16 Bs[128 * 32];
  const int tid = threadIdx.x;
  const int w = tid >> 6, lane = tid & 63;
  const int bm = blockIdx.y * 128, bn = blockIdx.x * 128;

  const int sr = tid >> 2, sp = tid & 3;
  const int g0 = sp ^ ((sr >> 1) & 3);
  const __hip_bfloat16* a0 = A + (size_t)(bm + sr) * kK + g0 * 8;
  const __hip_bfloat16* a1 = A + (size_t)(bm + sr + 64) * kK + g0 * 8;
  const __hip_bfloat16* b0 = W + (size_t)(bn + sr) * kK + g0 * 8;
  const __hip_bfloat16* b1 = W + (size_t)(bn + sr + 64) * kK + g0 * 8;
  char* AsB = (char*)As + w * 1024;
  char* BsB = (char*)Bs + w * 1024;

  const int wr = w >> 1, wc = w & 1;
  const int fr = lane & 15, fc = lane >> 4;
  int aOff[4], bOff[4];
#pragma unroll
  for (int f = 0; f < 4; f++) {
    const int ra = wr * 64 + f * 16 + fr;
    aOff[f] = ra * 64 + ((fc ^ ((ra >> 1) & 3)) * 16);
    const int rb = wc * 64 + f * 16 + fr;
    bOff[f] = rb * 64 + ((fc ^ ((rb >> 1) & 3)) * 16);
  }

  f32x4 acc[4][4];
#pragma unroll
  for (int i = 0; i < 4; i++)
#pragma unroll
    for (int j = 0; j < 4; j++) acc[i][j] = (f32x4){0.f, 0.f, 0.f, 0.f};

  for (int k0 = 0; k0 < kK; k0 += 32) {
    __syncthreads();
    glds16(a0 + k0, AsB);
    glds16(a1 + k0, AsB + 4096);
    glds16(b0 + k0, BsB);
    glds16(b1 + k0, BsB + 4096);
    __syncthreads();

    bf16x8 af[4], bfr[4];
#pragma unroll
    for (int f = 0; f < 4; f++) af[f] = *(const bf16x8*)((const char*)As + aOff[f]);
#pragma unroll
    for (int f = 0; f < 4; f++) bfr[f] = *(const bf16x8*)((const char*)Bs + bOff[f]);
#pragma unroll
    for (int i = 0; i < 4; i++)
#pragma unroll
      for (int j = 0; j < 4; j++)
        acc[i][j] = __builtin_amdgcn_mfma_f32_16x16x32_bf16(af[i], bfr[j], acc[i][j], 0, 0, 0);
  }

  const int r0 = bm + wr * 64, c0 = bn + wc * 64;
#pragma unroll
  for (int i = 0; i < 4; i++)
#pragma unroll
    for (int j = 0; j < 4; j++)
#pragma unroll
      for (int e = 0; e < 4; e++) {
        const int rr = r0 + i * 16 + fc * 4 + e;
        const int cc = c0 + j * 16 + fr;
        float vx = acc[i][j][e];
        if constexpr (MODE == 0) {
          ((float*)outA)[(size_t)rr * N + cc] = vx;
        } else if constexpr (MODE == 4) {
          const float y = Lp[cc] * vx;
          vx = fmaxf(y, 0.f) + log1pf(expf(-fabsf(y)));
          ((float*)outA)[(size_t)rr * N + cc] = vx;
        } else if constexpr (MODE == 3) {
          const float s = 1.f / (1.f + expf(-vx));
          const int b = rr >> 11, tok = rr & 2047, chn = tok >> 6, tt = tok & 63;
          if (cc < 48) {
            const int hh = cc / 3, j3 = cc - hh * 3;
            ((float*)outA)[(size_t)((b * 16 + hh) * 32 + chn) * 192 + tt * 3 + j3] = s;
          } else if (cc < 64) {
            const int hh = cc - 48;
            ((float*)outB)[(size_t)((b * 16 + hh) * 32 + chn) * 64 + tt] = s;
          }
        } else if constexpr (MODE == 5) {
          vx = vx / (1.f + expf(-vx));
          const int b = rr >> 11, tok = rr & 2047, chn = tok >> 6, tt = tok & 63;
          const int hh = cc / 192, rem = cc - hh * 192;
          const int d = rem / 3, j3 = rem - d * 3;
          ((__hip_bfloat16*)outA)[(size_t)((b * 16 + hh) * 32 + chn) * 12288 +
                                  (tt * 3 + j3) * 64 + d] = __float2bfloat16(vx);
        } else if constexpr (MODE == 6) {
          const int b = rr >> 11, tok = rr & 2047, chn = tok >> 6, tt = tok & 63;
          const int hh = cc >> 6, d = cc & 63;
          ((__hip_bfloat16*)outA)[(size_t)((b * 16 + hh) * 32 + chn) * 4096 +
                                  tt * 64 + d] = __float2bfloat16(vx);
        } else if constexpr (MODE == 7) {
          ((__hip_bfloat16*)outA)[(size_t)rr * 1024 + cc] = __float2bfloat16(vx);
        }
      }
}

// ---------------------------------------------------------------------------
__global__ void cast_bf16(const float* __restrict__ in, __hip_bfloat16* __restrict__ out, int n) {
  const int i = (blockIdx.x * 256 + threadIdx.x) * 4;
  if (i >= n) return;
  const float4 v = *(const float4*)(in + i);
  __hip_bfloat16 tmp[4] = {__float2bfloat16(v.x), __float2bfloat16(v.y),
                           __float2bfloat16(v.z), __float2bfloat16(v.w)};
  *(ushort4*)(out + i) = *(ushort4*)tmp;
}

__global__ void cast_bd(const float* __restrict__ Wb, const float* __restrict__ Wa,
                        __hip_bfloat16* __restrict__ out) {
  const int idx = blockIdx.x * 256 + threadIdx.x;
  if (idx >= 128 * 1024) return;
  const int r = idx >> 10, k = idx & 1023;
  const float val = (r < 48) ? Wb[r * 1024 + k] : ((r < 64) ? Wa[(r - 48) * 1024 + k] : 0.f);
  out[idx] = __float2bfloat16(val);
}

__global__ void lwc_mean(const float* __restrict__ lw, float* __restrict__ lwc) {
  const int idx = blockIdx.x * 256 + threadIdx.x;
  if (idx >= kB * kNc * kH * 16) return;
  const int l = idx & 15, h = (idx >> 4) & 15, c = (idx >> 8) & 31, b = idx >> 13;
  size_t base = ((size_t)b * kT + (size_t)c * kC) * 256 + h * 16 + l;
  float s = 0.f;
  for (int tt = 0; tt < kC; tt++) s += lw[base + (size_t)tt * 256];
  lwc[idx] = s * (1.f / 64.f);
}

// ---------------------------------------------------------------------------
// gram_phi: per-chunk-head. S = [K(192); Q(64)] (256x64 bf16). Out = S*K^T.
// Rows <192 -> G tiles (bf16, packed lower 6 tiles); rows >=192 -> PhiM
// (masked QK^T, no beta) into Astk rows 64..127. Also writes KT (K^T) into
// Astk rows 0..63 (transposed from LDS).
// ---------------------------------------------------------------------------
__global__ __launch_bounds__(256, 1) void gram_phi(
    const __hip_bfloat16* __restrict__ KP16, const __hip_bfloat16* __restrict__ qpack,
    __hip_bfloat16* __restrict__ G16, __hip_bfloat16* __restrict__ Astk) {
  const int ch = blockIdx.x;
  const int tid = threadIdx.x;
  const int w = tid >> 6, lane = tid & 63;
  __shared__ __hip_bfloat16 Sa[256 * 64];  // row-swizzled

  for (int cidx = tid; cidx < 2048; cidx += 256) {
    const int r = cidx >> 3, cko = cidx & 7;
    const __hip_bfloat16* src =
        (r < 192) ? (KP16 + (size_t)ch * 12288 + r * 64 + cko * 8)
                  : (qpack + (size_t)ch * 4096 + (r - 192) * 64 + cko * 8);
    bf16x8 vv = *(const bf16x8*)src;
    *(bf16x8*)((char*)Sa + r * 128 + ((cko ^ ((r >> 1) & 3)) * 16)) = vv;
  }
  __syncthreads();

  const int fr = lane & 15, fc = lane >> 4;
  f32x4 acc[4][12];
#pragma unroll
  for (int i = 0; i < 4; i++)
#pragma unroll
    for (int j = 0; j < 12; j++) acc[i][j] = (f32x4){0.f, 0.f, 0.f, 0.f};

#pragma unroll
  for (int ks = 0; ks < 2; ks++) {
    bf16x8 af[4];
#pragma unroll
    for (int i = 0; i < 4; i++) {
      const int ra = w * 64 + i * 16 + fr;
      af[i] = *(const bf16x8*)((char*)Sa + ra * 128 + (((ks * 4 + fc) ^ ((ra >> 1) & 3)) * 16));
    }
#pragma unroll
    for (int j = 0; j < 12; j++) {
      const int rb = j * 16 + fr;
      bf16x8 bfv = *(const bf16x8*)((char*)Sa + rb * 128 + (((ks * 4 + fc) ^ ((rb >> 1) & 3)) * 16));
#pragma unroll
      for (int i = 0; i < 4; i++)
        acc[i][j] = __builtin_amdgcn_mfma_f32_16x16x32_bf16(af[i], bfv, acc[i][j], 0, 0, 0);
    }
  }

#pragma unroll
  for (int i = 0; i < 4; i++)
#pragma unroll
    for (int j = 0; j < 12; j++)
#pragma unroll
      for (int e = 0; e < 4; e++) {
        const int gr = w * 64 + i * 16 + fc * 4 + e;
        const int gc = j * 16 + fr;
        const float val = acc[i][j][e];
        if (gr < 192) {
          const int sbb = gr >> 6, jbb = gc >> 6;
          if (jbb <= sbb)
            G16[(size_t)ch * 24576 + (size_t)(sbb * (sbb + 1) / 2 + jbb) * 4096 +
                (gr & 63) * 64 + (gc & 63)] = __float2bfloat16(val);
        } else {
          const int t = gr - 192;
          const float mval = ((gc / 3) <= t) ? val : 0.f;
          Astk[(size_t)ch * 24576 + (size_t)(64 + t) * 192 + gc] = __float2bfloat16(mval);
        }
      }

  // KT rows: Astk[ch][d][i] = K[i][d] (from swizzled LDS)
  for (int s = tid; s < 1536; s += 256) {
    const int d = s / 24, i0 = (s % 24) * 8;
    __hip_bfloat16 tmp[8];
#pragma unroll
    for (int e = 0; e < 8; e++) {
      const int i = i0 + e;
      tmp[e] = *(const __hip_bfloat16*)((char*)Sa + i * 128 +
                                        (((d >> 3) ^ ((i >> 1) & 3)) * 16) + (d & 7) * 2);
    }
    *(bf16x8*)(Astk + (size_t)ch * 24576 + (size_t)d * 192 + i0) = *(bf16x8*)tmp;
  }
}

// ---------------------------------------------------------------------------
// chunk_solve (merged passes): one block per ch solves (I + Ltil) Xt = [K | V/c]
// with Ltil[i][j] = beta_j*G[i][j] (strict lower), RHS width 128.
// ---------------------------------------------------------------------------
__global__ __launch_bounds__(256) void chunk_solve(
    const __hip_bfloat16* __restrict__ G16,
    __hip_bfloat16* __restrict__ KP16, __hip_bfloat16* __restrict__ VP16,
    const float* __restrict__ betp, const float* __restrict__ decp) {
  const int ch = blockIdx.x;
  const int tid = threadIdx.x;
  constexpr int XS = 133;  // padded row stride (odd -> banks decorrelate)
  __shared__ float X[192 * XS];        // 102,144 B
  __shared__ float tile[64 * 65];      //  16,640 B
  __shared__ float bet[192], cpre[64], rc[64];

  if (tid < 192) bet[tid] = betp[(size_t)ch * 192 + tid];
  if (tid < 64) cpre[tid] = decp[(size_t)ch * 64 + tid];
  __syncthreads();
  if (tid == 0) {
    float p = 1.f;
    for (int t = 0; t < 64; t++) { p *= cpre[t]; cpre[t] = p; }
  }
  __syncthreads();
  if (tid < 64) rc[tid] = 1.f / cpre[tid];
  __syncthreads();

  // stage RHS: X[i][0..63] = K[i][:]; X[i][64..127] = V[i][:] / c_{tau(i)}
  for (int v = tid; v < 3072; v += 256) {
    const bool isV = v >= 1536;
    const int vv = isV ? (v - 1536) : v;
    const int i = vv >> 3, d0 = (vv & 7) * 8;
    const __hip_bfloat16* src = (isV ? VP16 : KP16) + (size_t)ch * 12288 + i * 64 + d0;
    bf16x8 vb8 = *(const bf16x8*)src;
    const float sc = isV ? rc[i / 3] : 1.f;
    const int cb = isV ? 64 : 0;
#pragma unroll
    for (int e = 0; e < 8; e++)
      X[i * XS + cb + d0 + e] =
          __bfloat162float(*(((const __hip_bfloat16*)&vb8) + e)) * sc;
  }
  __syncthreads();

  const int col2 = tid & 127;   // RHS column
  const int rg = tid >> 7;      // row group (0/1)

  for (int sb = 0; sb < 3; sb++) {
    const int s = sb * 64;
    // off-diagonal rank-64 updates (parallel, all 256 threads)
    for (int jb = 0; jb < sb; jb++) {
      const __hip_bfloat16* gt = G16 + (size_t)ch * 24576 +
                                 (size_t)(sb * (sb + 1) / 2 + jb) * 4096;
      for (int idx = tid; idx < 4096; idx += 256)
        tile[(idx >> 6) * 65 + (idx & 63)] =
            __bfloat162float(gt[idx]) * bet[jb * 64 + (idx & 63)];
      __syncthreads();
      for (int r = rg; r < 64; r += 2) {
        float acc = X[(s + r) * XS + col2];
#pragma unroll 8
        for (int jj = 0; jj < 64; jj++)
          acc = fmaf(-tile[r * 65 + jj], X[(jb * 64 + jj) * XS + col2], acc);
        X[(s + r) * XS + col2] = acc;
      }
      __syncthreads();
    }
    // stage diagonal Ltil block
    {
      const __hip_bfloat16* gt = G16 + (size_t)ch * 24576 +
                                 (size_t)(sb * (sb + 1) / 2 + sb) * 4096;
      for (int idx = tid; idx < 4096; idx += 256)
        tile[(idx >> 6) * 65 + (idx & 63)] =
            __bfloat162float(gt[idx]) * bet[s + (idx & 63)];
    }
    __syncthreads();
    // 16-sub-blocked diagonal solve
    for (int db = 0; db < 4; db++) {
      const int l0 = db * 16;
      if (tid < 128) {
        for (int ii = 1; ii < 16; ii++) {
          float acc = X[(s + l0 + ii) * XS + tid];
          for (int jj = 0; jj < ii; jj++)
            acc = fmaf(-tile[(l0 + ii) * 65 + l0 + jj], X[(s + l0 + jj) * XS + tid], acc);
          X[(s + l0 + ii) * XS + tid] = acc;
        }
      }
      __syncthreads();
      const int rem = 48 - l0;  // rows below this sub-block within the 64-block
      if (rem > 0) {
        for (int r = rg; r < rem; r += 2) {
          const int lrow = l0 + 16 + r;
          float acc = X[(s + lrow) * XS + col2];
#pragma unroll
          for (int jj = 0; jj < 16; jj++)
            acc = fmaf(-tile[lrow * 65 + l0 + jj], X[(s + l0 + jj) * XS + col2], acc);
          X[(s + lrow) * XS + col2] = acc;
        }
      }
      __syncthreads();
    }
  }

  // write Bt over the rhs strips: Bt[col][i] = beta_i * X[i][col]
  for (int v = tid; v < 3072; v += 256) {
    const int col = v / 24, i0 = (v % 24) * 8;
    __hip_bfloat16 tmp[8];
#pragma unroll
    for (int e = 0; e < 8; e++)
      tmp[e] = __float2bfloat16(bet[i0 + e] * X[(i0 + e) * XS + col]);
    __hip_bfloat16* dst = (col < 64 ? (KP16 + (size_t)ch * 12288 + col * 192)
                                    : (VP16 + (size_t)ch * 12288 + (col - 64) * 192)) + i0;
    *(bf16x8*)dst = *(bf16x8*)tmp;
  }
}

// ---------------------------------------------------------------------------
// products: per ch. Out(128x128) = Astk(128x192) x Bt(128x192)^T-NT.
// ---------------------------------------------------------------------------
__global__ __launch_bounds__(256) void products(
    const __hip_bfloat16* __restrict__ Astk,
    const __hip_bfloat16* __restrict__ KP16, const __hip_bfloat16* __restrict__ VP16,
    const __hip_bfloat16* __restrict__ qpack, const float* __restrict__ decp,
    float* __restrict__ Tc, float* __restrict__ Qe,
    float* __restrict__ BcW, float* __restrict__ VoW) {
  const int ch = blockIdx.x;
  const int tid = threadIdx.x;
  const int w = tid >> 6, lane = tid & 63;
  __shared__ __hip_bfloat16 As[128 * 32];
  __shared__ __hip_bfloat16 Bs[128 * 32];
  __shared__ float cpre[64];

  if (tid < 64) cpre[tid] = decp[(size_t)ch * 64 + tid];
  __syncthreads();
  if (tid == 0) {
    float p = 1.f;
    for (int t = 0; t < 64; t++) { p *= cpre[t]; cpre[t] = p; }
  }

  const int sr = tid >> 2, sp = tid & 3;
  const int g0 = sp ^ ((sr >> 1) & 3);
  const __hip_bfloat16* a0 = Astk + (size_t)ch * 24576 + sr * 192 + g0 * 8;
  const __hip_bfloat16* a1 = a0 + 64 * 192;
  const __hip_bfloat16* b0 = KP16 + (size_t)ch * 12288 + sr * 192 + g0 * 8;
  const __hip_bfloat16* b1 = VP16 + (size_t)ch * 12288 + sr * 192 + g0 * 8;
  char* AsB = (char*)As + w * 1024;
  char* BsB = (char*)Bs + w * 1024;

  const int wr = w >> 1, wc = w & 1;
  const int fr = lane & 15, fc = lane >> 4;
  int aOff[4], bOff[4];
#pragma unroll
  for (int f = 0; f < 4; f++) {
    const int ra = wr * 64 + f * 16 + fr;
    aOff[f] = ra * 64 + ((fc ^ ((ra >> 1) & 3)) * 16);
    const int rb = wc * 64 + f * 16 + fr;
    bOff[f] = rb * 64 + ((fc ^ ((rb >> 1) & 3)) * 16);
  }

  f32x4 acc[4][4];
#pragma unroll
  for (int i = 0; i < 4; i++)
#pragma unroll
    for (int j = 0; j < 4; j++) acc[i][j] = (f32x4){0.f, 0.f, 0.f, 0.f};

  for (int k0 = 0; k0 < 192; k0 += 32) {
    __syncthreads();
    glds16(a0 + k0, AsB);
    glds16(a1 + k0, AsB + 4096);
    glds16(b0 + k0, BsB);
    glds16(b1 + k0, BsB + 4096);
    __syncthreads();

    bf16x8 af[4], bfr[4];
#pragma unroll
    for (int f = 0; f < 4; f++) af[f] = *(const bf16x8*)((const char*)As + aOff[f]);
#pragma unroll
    for (int f = 0; f < 4; f++) bfr[f] = *(const bf16x8*)((const char*)Bs + bOff[f]);
#pragma unroll
    for (int i = 0; i < 4; i++)
#pragma unroll
      for (int j = 0; j < 4; j++)
        acc[i][j] = __builtin_amdgcn_mfma_f32_16x16x32_bf16(af[i], bfr[j], acc[i][j], 0, 0, 0);
  }
  __syncthreads();

  const float cC = cpre[63];
#pragma unroll
  for (int i = 0; i < 4; i++)
#pragma unroll
    for (int j = 0; j < 4; j++)
#pragma unroll
      for (int e = 0; e < 4; e++) {
        const int rr = wr * 64 + i * 16 + fc * 4 + e;
        const int cc = wc * 64 + j * 16 + fr;
        const float val = acc[i][j][e];
        if (rr < 64) {
          if (cc < 64)
            Tc[(size_t)ch * 4096 + rr * 64 + cc] = cC * (((rr == cc) ? 1.f : 0.f) - val);
          else
            BcW[(size_t)ch * 6144 + rr * 64 + (cc - 64)] = cC * val;
        } else {
          const int t = rr - 64;
          const float ct = cpre[t];
          if (cc < 64) {
            const float qv = __bfloat162float(qpack[(size_t)ch * 4096 + t * 64 + cc]);
            Qe[(size_t)ch * 4096 + t * 64 + cc] = ct * (qv - val);
          } else {
            VoW[(size_t)ch * 6144 + t * 64 + (cc - 64)] = ct * val;
          }
        }
      }
}

// ---------------------------------------------------------------------------
// state_scan: 64 blocks = (b,h) x v-half. ONLY the sequential state pass:
// S0 = sum_l lw[l]*stL[l] (stored to S0g); Sf = Tc*S0 + Bc; level merge.
// Tc/Bc for chunk c+1 are register-prefetched while chunk c computes.
// ---------------------------------------------------------------------------
__global__ __launch_bounds__(256) void state_scan(
    const float* __restrict__ Tc, const float* __restrict__ BcS,
    const float* __restrict__ lwcb, float* __restrict__ S0g) {
  const int blk = blockIdx.x;
  const int bh = blk >> 1, vh = blk & 1;
  const int b = bh >> 4, h = bh & 15;
  const int vbase = vh * 32;
  const int tid = threadIdx.x;
  const int v = tid & 31;
  const int tg = tid >> 5;  // 0..7

  __shared__ float stL[6][64][32];   // 48 KB
  __shared__ float S0s[64][32];      //  8 KB
  __shared__ float Tt[64][64];       // 16 KB
  __shared__ float Bt_[64][32];      //  8 KB

  for (int idx = tid; idx < 6 * 2048; idx += 256) ((float*)stL)[idx] = 0.f;

  // prefetch chunk 0 into registers
  float tReg[16], bReg[8];
  {
    const size_t ch0 = (size_t)bh * 32;
#pragma unroll
    for (int i = 0; i < 16; i++) tReg[i] = Tc[ch0 * 4096 + tid + i * 256];
#pragma unroll
    for (int i = 0; i < 8; i++) {
      const int idx = tid + i * 256;
      bReg[i] = BcS[ch0 * 6144 + (idx >> 5) * 64 + vbase + (idx & 31)];
    }
  }
  __syncthreads();  // stL zero-init visible

  for (int c = 0; c < 32; c++) {
    const size_t ch = (size_t)bh * 32 + c;
    // commit prefetched tiles to LDS (prev readers done at loop-end barrier)
#pragma unroll
    for (int i = 0; i < 16; i++) ((float*)Tt)[tid + i * 256] = tReg[i];
#pragma unroll
    for (int i = 0; i < 8; i++) ((float*)Bt_)[tid + i * 256] = bReg[i];

    // S0 = sum_l lw[l] * stL[l]; store to global for o_gemm
    const float* lwp = lwcb + ((size_t)(b * kNc + c) * kH + h) * 16;
    float lw[6];
#pragma unroll
    for (int l = 0; l < 6; l++) lw[l] = lwp[l];
#pragma unroll
    for (int n = 0; n < 8; n++) {
      const int k = n * 8 + tg;
      float s = 0.f;
#pragma unroll
      for (int l = 0; l < 6; l++) s = fmaf(lw[l], stL[l][k][v], s);
      S0s[k][v] = s;
      S0g[ch * 4096 + k * 64 + vbase + v] = s;
    }
    __syncthreads();

    // issue prefetch for c+1 (hidden under the matmul below)
    const size_t chn = (size_t)bh * 32 + (c < 31 ? c + 1 : 31);
#pragma unroll
    for (int i = 0; i < 16; i++) tReg[i] = Tc[chn * 4096 + tid + i * 256];
#pragma unroll
    for (int i = 0; i < 8; i++) {
      const int idx = tid + i * 256;
      bReg[i] = BcS[chn * 6144 + (idx >> 5) * 64 + vbase + (idx & 31)];
    }

    // Sf = Tt * S0 + Bc; hierarchical merge at lev = ctz(c+1)
    const int lev = __builtin_ctz(c + 1);
#pragma unroll
    for (int n = 0; n < 8; n++) {
      const int r = n * 8 + tg;
      float s = Bt_[r][v];
#pragma unroll 8
      for (int k = 0; k < 64; k++) s = fmaf(Tt[r][k], S0s[k][v], s);
      for (int l = 0; l < lev; l++) { s += stL[l][r][v]; stL[l][r][v] = 0.f; }
      stL[lev][r][v] = s;
    }
    __syncthreads();
  }
}

// ---------------------------------------------------------------------------
// o_gemm: 1024 parallel blocks (one per ch). O = Qe * S0 + Vo  (f32, same fma
// order as the old fused scan -> bit-identical output).
// ---------------------------------------------------------------------------
__global__ __launch_bounds__(256) void o_gemm(
    const float* __restrict__ Qe, const float* __restrict__ S0g,
    const float* __restrict__ VoS, float* __restrict__ Obuf) {
  const int ch = blockIdx.x;
  const int tid = threadIdx.x;
  const int v = tid & 63;
  const int tg = tid >> 6;  // 0..3
  __shared__ float Qs[64][64];
  __shared__ float Ss[64][64];
  for (int idx = tid; idx < 4096; idx += 256) {
    ((float*)Qs)[idx] = Qe[(size_t)ch * 4096 + idx];
    ((float*)Ss)[idx] = S0g[(size_t)ch * 4096 + idx];
  }
  __syncthreads();
#pragma unroll
  for (int n = 0; n < 16; n++) {
    const int t = n * 4 + tg;
    float o = VoS[(size_t)ch * 6144 + t * 64 + v];
#pragma unroll 8
    for (int k = 0; k < 64; k++) o = fmaf(Qs[t][k], Ss[k][v], o);
    Obuf[(size_t)ch * 4096 + t * 64 + v] = o;
  }
}

// ---------------------------------------------------------------------------
__global__ __launch_bounds__(256) void gn_stats(const float* __restrict__ Obuf,
                                                float* __restrict__ stats) {
  const int bh = blockIdx.x;
  double sum = 0.0, sumsq = 0.0;
  for (int idx = threadIdx.x; idx < kNc * 4096; idx += 256) {
    const float val = Obuf[(size_t)bh * 131072 + idx];
    sum += val;
    sumsq += (double)val * val;
  }
  __shared__ double sred[256], qred[256];
  sred[threadIdx.x] = sum;
  qred[threadIdx.x] = sumsq;
  __syncthreads();
  for (int stp = 128; stp > 0; stp >>= 1) {
    if (threadIdx.x < stp) {
      sred[threadIdx.x] += sred[threadIdx.x + stp];
      qred[threadIdx.x] += qred[threadIdx.x + stp];
    }
    __syncthreads();
  }
  if (threadIdx.x == 0) {
    const double n = (double)kT * 64.0;
    const double mu = sred[0] / n;
    const double var = qred[0] / n - mu * mu;
    stats[bh * 2] = (float)mu;
    stats[bh * 2 + 1] = (float)(1.0 / sqrt(var + 1e-5));
  }
}

__global__ void gate_kernel(const float* __restrict__ Obuf,
                            const __hip_bfloat16* __restrict__ og,
                            const float* __restrict__ gamma, const float* __restrict__ gbeta,
                            const float* __restrict__ stats, __hip_bfloat16* __restrict__ z) {
  const size_t idx = (size_t)blockIdx.x * 256 + threadIdx.x;
  if (idx >= (size_t)kM * 1024) return;
  const int cidx = (int)(idx & 1023);
  const int h = cidx >> 6, v = cidx & 63;
  const size_t m = idx >> 10;
  const int b = (int)(m >> 11);
  const int tok = (int)(m & 2047), c = tok >> 6, tt = tok & 63;
  const float o = Obuf[(size_t)((b * 16 + h) * 32 + c) * 4096 + tt * 64 + v];
  const float mu = stats[(b * 16 + h) * 2];
  const float rstd = stats[(b * 16 + h) * 2 + 1];
  const float val = (o - mu) * rstd * gamma[cidx] + gbeta[cidx];
  const float gt = __bfloat162float(og[idx]);
  z[idx] = __float2bfloat16(val * (1.f / (1.f + expf(-gt))));
}

// ---------------------------------------------------------------------------
extern "C" void kernel_launch(void* const* d_in, const int* in_sizes, int n_in,
                              void* d_out, int out_size, void* d_ws, size_t ws_size,
                              hipStream_t stream) {
  const float* x     = (const float*)d_in[0];
  const float* Wq    = (const float*)d_in[3];
  const float* Wk    = (const float*)d_in[4];
  const float* Wv    = (const float*)d_in[5];
  const float* Wb    = (const float*)d_in[6];
  const float* Wa    = (const float*)d_in[7];
  const float* Wg    = (const float*)d_in[8];
  const float* Wo    = (const float*)d_in[9];
  const float* Wl    = (const float*)d_in[10];
  const float* Lp    = (const float*)d_in[11];
  const float* gamma = (const float*)d_in[12];
  const float* gbeta = (const float*)d_in[13];
  float* out = (float*)d_out;
  (void)ws_size;  // peak usage < 181,469,440 proven in round 1

  char* base = (char*)d_ws;
  // P1: qpack -> zbf
  __hip_bfloat16* qpack = (__hip_bfloat16*)(base + 0);                 // 8,388,608
  __hip_bfloat16* zbf   = qpack;                                       // after products
  // P2/P3: kv packs -> Bt (in-place) -> Bc/Vo f32 (in-place)
  __hip_bfloat16* KP16 = (__hip_bfloat16*)(base + 8388608);            // 25,165,824
  __hip_bfloat16* VP16 = (__hip_bfloat16*)(base + 33554432);           // 25,165,824
  // P4 region (50,331,648): early = xb + weights; then G16; then Tc/Qe/Obuf
  char* P4 = base + 58720256;
  __hip_bfloat16* xb   = (__hip_bfloat16*)(P4 + 0);                    // 8,388,608
  __hip_bfloat16* Wqb  = (__hip_bfloat16*)(P4 + 8388608);              // 2,097,152
  __hip_bfloat16* Wkb  = (__hip_bfloat16*)(P4 + 10485760);             // 6,291,456
  __hip_bfloat16* Wvb  = (__hip_bfloat16*)(P4 + 16777216);             // 6,291,456
  __hip_bfloat16* Wgb  = (__hip_bfloat16*)(P4 + 23068672);             // 2,097,152
  __hip_bfloat16* Wlb  = (__hip_bfloat16*)(P4 + 25165824);             // 524,288
  __hip_bfloat16* Wbdb = (__hip_bfloat16*)(P4 + 25690112);             // 262,144
  __hip_bfloat16* G16  = (__hip_bfloat16*)P4;                          // full 50,331,648
  float* Tc   = (float*)(P4 + 0);                                      // 16,777,216
  float* Qe   = (float*)(P4 + 16777216);                               // 16,777,216
  float* Obuf = (float*)(P4 + 33554432);                               // 16,777,216
  // P5 region (50,331,648): early = lwb; then Astk; then S0g (Astk dead)
  char* P5 = base + 109051904;
  float* lwb = (float*)(P5 + 0);                                       // 4,194,304
  __hip_bfloat16* Astk = (__hip_bfloat16*)P5;                          // 50,331,648
  float* S0g = (float*)P5;                                             // 16,777,216
  // P6: persistent small
  char* P6 = base + 159383552;
  float* betp  = (float*)(P6 + 0);                                     // 786,432
  float* decp  = (float*)(P6 + 786432);                                // 262,144
  float* lwcb  = (float*)(P6 + 1048576);                               // 65,536
  float* statb = (float*)(P6 + 1114112);                               // 1,024
  __hip_bfloat16* Wob = (__hip_bfloat16*)(P6 + 1115136);               // 2,097,152
  __hip_bfloat16* ogb = (__hip_bfloat16*)(P6 + 3212288);               // 8,388,608

  const dim3 blk(256);

  // casts
  cast_bf16<<<dim3(4096), blk, 0, stream>>>(x,  xb,  kM * 1024);
  cast_bf16<<<dim3(1024), blk, 0, stream>>>(Wq, Wqb, 1024 * 1024);
  cast_bf16<<<dim3(3072), blk, 0, stream>>>(Wk, Wkb, 3072 * 1024);
  cast_bf16<<<dim3(3072), blk, 0, stream>>>(Wv, Wvb, 3072 * 1024);
  cast_bf16<<<dim3(1024), blk, 0, stream>>>(Wg, Wgb, 1024 * 1024);
  cast_bf16<<<dim3(256),  blk, 0, stream>>>(Wl, Wlb, 256 * 1024);
  cast_bf16<<<dim3(1024), blk, 0, stream>>>(Wo, Wob, 1024 * 1024);
  cast_bd<<<dim3(512), blk, 0, stream>>>(Wb, Wa, Wbdb);

  // projections
  gemm_bf16<6><<<dim3(8, 32),  blk, 0, stream>>>(xb, Wqb,  qpack, nullptr, 1024, nullptr);
  gemm_bf16<5><<<dim3(24, 32), blk, 0, stream>>>(xb, Wkb,  KP16,  nullptr, 3072, nullptr);
  gemm_bf16<5><<<dim3(24, 32), blk, 0, stream>>>(xb, Wvb,  VP16,  nullptr, 3072, nullptr);
  gemm_bf16<3><<<dim3(1, 32),  blk, 0, stream>>>(xb, Wbdb, betp,  decp,    128,  nullptr);
  gemm_bf16<4><<<dim3(2, 32),  blk, 0, stream>>>(xb, Wlb,  lwb,   nullptr, 256,  Lp);
  gemm_bf16<7><<<dim3(8, 32),  blk, 0, stream>>>(xb, Wgb,  ogb,   nullptr, 1024, nullptr);

  lwc_mean<<<dim3(64), blk, 0, stream>>>(lwb, lwcb);

  // chunk operators
  gram_phi<<<dim3(1024), blk, 0, stream>>>(KP16, qpack, G16, Astk);
  chunk_solve<<<dim3(1024), blk, 0, stream>>>(G16, KP16, VP16, betp, decp);
  products<<<dim3(1024), blk, 0, stream>>>(Astk, KP16, VP16, qpack, decp,
                                           Tc, Qe, (float*)KP16, (float*)VP16);

  // sequential state scan (light) + parallel O gemm
  state_scan<<<dim3(64), blk, 0, stream>>>(Tc, (const float*)KP16, lwcb, S0g);
  o_gemm<<<dim3(1024), blk, 0, stream>>>(Qe, S0g, (const float*)VP16, Obuf);

  // group norm + gate
  gn_stats<<<dim3(kB * kH), blk, 0, stream>>>(Obuf, statb);
  gate_kernel<<<dim3((kM * 1024 + 255) / 256), blk, 0, stream>>>(Obuf, ogb, gamma, gbeta,
                                                                 statb, zbf);

  // final projection
  gemm_bf16<0><<<dim3(8, 32), blk, 0, stream>>>(zbf, Wob, out, nullptr, 1024, nullptr);
}

// Round 8
// 979.816 us; speedup vs baseline: 6.4786x; 1.3063x over previous
//
#include <hip/hip_runtime.h>
#include <hip/hip_bf16.h>
#include <math.h>

// Problem constants
constexpr int kB   = 2;
constexpr int kT   = 2048;
constexpr int kH   = 16;
constexpr int kC   = 64;    // chunk size
constexpr int kNc  = 32;    // T / C
constexpr int kM   = kB * kT;   // 4096
constexpr int kK   = 1024;

using bf16x8 = __attribute__((ext_vector_type(8))) short;
using f32x4  = __attribute__((ext_vector_type(4))) float;

__device__ __forceinline__ void glds16(const void* g, void* l) {
  __builtin_amdgcn_global_load_lds(
      (const __attribute__((address_space(1))) unsigned int*)g,
      (__attribute__((address_space(3))) unsigned int*)l, 16, 0, 0);
}

// ---------------------------------------------------------------------------
// bf16 MFMA NT-GEMM (verified structure). MODE:
//  0: f32 plain [rr*N+cc]
//  3: beta(48)/dec(16) sigmoid -> betp [ch][192] f32, decp [ch][64] f32
//  4: softplus(Lp*x) f32 plain (lw)
//  5: silu -> bf16 pack [ch][i=tt*3+j3][d]
//  6: bf16 q pack [ch][t][d]
//  7: bf16 plain [rr*1024+cc] (og)
// ---------------------------------------------------------------------------
template <int MODE>
__global__ __launch_bounds__(256) void gemm_bf16(
    const __hip_bfloat16* __restrict__ A, const __hip_bfloat16* __restrict__ W,
    void* __restrict__ outA, void* __restrict__ outB, int N,
    const float* __restrict__ Lp) {
  __shared__ __hip_bfloat16 As[128 * 32];
  __shared__ __hip_bfloat16 Bs[128 * 32];
  const int tid = threadIdx.x;
  const int w = tid >> 6, lane = tid & 63;
  const int bm = blockIdx.y * 128, bn = blockIdx.x * 128;

  const int sr = tid >> 2, sp = tid & 3;
  const int g0 = sp ^ ((sr >> 1) & 3);
  const __hip_bfloat16* a0 = A + (size_t)(bm + sr) * kK + g0 * 8;
  const __hip_bfloat16* a1 = A + (size_t)(bm + sr + 64) * kK + g0 * 8;
  const __hip_bfloat16* b0 = W + (size_t)(bn + sr) * kK + g0 * 8;
  const __hip_bfloat16* b1 = W + (size_t)(bn + sr + 64) * kK + g0 * 8;
  char* AsB = (char*)As + w * 1024;
  char* BsB = (char*)Bs + w * 1024;

  const int wr = w >> 1, wc = w & 1;
  const int fr = lane & 15, fc = lane >> 4;
  int aOff[4], bOff[4];
#pragma unroll
  for (int f = 0; f < 4; f++) {
    const int ra = wr * 64 + f * 16 + fr;
    aOff[f] = ra * 64 + ((fc ^ ((ra >> 1) & 3)) * 16);
    const int rb = wc * 64 + f * 16 + fr;
    bOff[f] = rb * 64 + ((fc ^ ((rb >> 1) & 3)) * 16);
  }

  f32x4 acc[4][4];
#pragma unroll
  for (int i = 0; i < 4; i++)
#pragma unroll
    for (int j = 0; j < 4; j++) acc[i][j] = (f32x4){0.f, 0.f, 0.f, 0.f};

  for (int k0 = 0; k0 < kK; k0 += 32) {
    __syncthreads();
    glds16(a0 + k0, AsB);
    glds16(a1 + k0, AsB + 4096);
    glds16(b0 + k0, BsB);
    glds16(b1 + k0, BsB + 4096);
    __syncthreads();

    bf16x8 af[4], bfr[4];
#pragma unroll
    for (int f = 0; f < 4; f++) af[f] = *(const bf16x8*)((const char*)As + aOff[f]);
#pragma unroll
    for (int f = 0; f < 4; f++) bfr[f] = *(const bf16x8*)((const char*)Bs + bOff[f]);
#pragma unroll
    for (int i = 0; i < 4; i++)
#pragma unroll
      for (int j = 0; j < 4; j++)
        acc[i][j] = __builtin_amdgcn_mfma_f32_16x16x32_bf16(af[i], bfr[j], acc[i][j], 0, 0, 0);
  }

  const int r0 = bm + wr * 64, c0 = bn + wc * 64;
#pragma unroll
  for (int i = 0; i < 4; i++)
#pragma unroll
    for (int j = 0; j < 4; j++)
#pragma unroll
      for (int e = 0; e < 4; e++) {
        const int rr = r0 + i * 16 + fc * 4 + e;
        const int cc = c0 + j * 16 + fr;
        float vx = acc[i][j][e];
        if constexpr (MODE == 0) {
          ((float*)outA)[(size_t)rr * N + cc] = vx;
        } else if constexpr (MODE == 4) {
          const float y = Lp[cc] * vx;
          vx = fmaxf(y, 0.f) + log1pf(expf(-fabsf(y)));
          ((float*)outA)[(size_t)rr * N + cc] = vx;
        } else if constexpr (MODE == 3) {
          const float s = 1.f / (1.f + expf(-vx));
          const int b = rr >> 11, tok = rr & 2047, chn = tok >> 6, tt = tok & 63;
          if (cc < 48) {
            const int hh = cc / 3, j3 = cc - hh * 3;
            ((float*)outA)[(size_t)((b * 16 + hh) * 32 + chn) * 192 + tt * 3 + j3] = s;
          } else if (cc < 64) {
            const int hh = cc - 48;
            ((float*)outB)[(size_t)((b * 16 + hh) * 32 + chn) * 64 + tt] = s;
          }
        } else if constexpr (MODE == 5) {
          vx = vx / (1.f + expf(-vx));
          const int b = rr >> 11, tok = rr & 2047, chn = tok >> 6, tt = tok & 63;
          const int hh = cc / 192, rem = cc - hh * 192;
          const int d = rem / 3, j3 = rem - d * 3;
          ((__hip_bfloat16*)outA)[(size_t)((b * 16 + hh) * 32 + chn) * 12288 +
                                  (tt * 3 + j3) * 64 + d] = __float2bfloat16(vx);
        } else if constexpr (MODE == 6) {
          const int b = rr >> 11, tok = rr & 2047, chn = tok >> 6, tt = tok & 63;
          const int hh = cc >> 6, d = cc & 63;
          ((__hip_bfloat16*)outA)[(size_t)((b * 16 + hh) * 32 + chn) * 4096 +
                                  tt * 64 + d] = __float2bfloat16(vx);
        } else if constexpr (MODE == 7) {
          ((__hip_bfloat16*)outA)[(size_t)rr * 1024 + cc] = __float2bfloat16(vx);
        }
      }
}

// ---------------------------------------------------------------------------
__global__ void cast_bf16(const float* __restrict__ in, __hip_bfloat16* __restrict__ out, int n) {
  const int i = (blockIdx.x * 256 + threadIdx.x) * 4;
  if (i >= n) return;
  const float4 v = *(const float4*)(in + i);
  __hip_bfloat16 tmp[4] = {__float2bfloat16(v.x), __float2bfloat16(v.y),
                           __float2bfloat16(v.z), __float2bfloat16(v.w)};
  *(ushort4*)(out + i) = *(ushort4*)tmp;
}

__global__ void cast_bd(const float* __restrict__ Wb, const float* __restrict__ Wa,
                        __hip_bfloat16* __restrict__ out) {
  const int idx = blockIdx.x * 256 + threadIdx.x;
  if (idx >= 128 * 1024) return;
  const int r = idx >> 10, k = idx & 1023;
  const float val = (r < 48) ? Wb[r * 1024 + k] : ((r < 64) ? Wa[(r - 48) * 1024 + k] : 0.f);
  out[idx] = __float2bfloat16(val);
}

__global__ void lwc_mean(const float* __restrict__ lw, float* __restrict__ lwc) {
  const int idx = blockIdx.x * 256 + threadIdx.x;
  if (idx >= kB * kNc * kH * 16) return;
  const int l = idx & 15, h = (idx >> 4) & 15, c = (idx >> 8) & 31, b = idx >> 13;
  size_t base = ((size_t)b * kT + (size_t)c * kC) * 256 + h * 16 + l;
  float s = 0.f;
  for (int tt = 0; tt < kC; tt++) s += lw[base + (size_t)tt * 256];
  lwc[idx] = s * (1.f / 64.f);
}

// ---------------------------------------------------------------------------
// gram_phi: per-chunk-head. S = [K(192); Q(64)] (256x64 bf16). Out = S*K^T.
// ---------------------------------------------------------------------------
__global__ __launch_bounds__(256, 1) void gram_phi(
    const __hip_bfloat16* __restrict__ KP16, const __hip_bfloat16* __restrict__ qpack,
    __hip_bfloat16* __restrict__ G16, __hip_bfloat16* __restrict__ Astk) {
  const int ch = blockIdx.x;
  const int tid = threadIdx.x;
  const int w = tid >> 6, lane = tid & 63;
  __shared__ __hip_bfloat16 Sa[256 * 64];  // row-swizzled

  for (int cidx = tid; cidx < 2048; cidx += 256) {
    const int r = cidx >> 3, cko = cidx & 7;
    const __hip_bfloat16* src =
        (r < 192) ? (KP16 + (size_t)ch * 12288 + r * 64 + cko * 8)
                  : (qpack + (size_t)ch * 4096 + (r - 192) * 64 + cko * 8);
    bf16x8 vv = *(const bf16x8*)src;
    *(bf16x8*)((char*)Sa + r * 128 + ((cko ^ ((r >> 1) & 3)) * 16)) = vv;
  }
  __syncthreads();

  const int fr = lane & 15, fc = lane >> 4;
  f32x4 acc[4][12];
#pragma unroll
  for (int i = 0; i < 4; i++)
#pragma unroll
    for (int j = 0; j < 12; j++) acc[i][j] = (f32x4){0.f, 0.f, 0.f, 0.f};

#pragma unroll
  for (int ks = 0; ks < 2; ks++) {
    bf16x8 af[4];
#pragma unroll
    for (int i = 0; i < 4; i++) {
      const int ra = w * 64 + i * 16 + fr;
      af[i] = *(const bf16x8*)((char*)Sa + ra * 128 + (((ks * 4 + fc) ^ ((ra >> 1) & 3)) * 16));
    }
#pragma unroll
    for (int j = 0; j < 12; j++) {
      const int rb = j * 16 + fr;
      bf16x8 bfv = *(const bf16x8*)((char*)Sa + rb * 128 + (((ks * 4 + fc) ^ ((rb >> 1) & 3)) * 16));
#pragma unroll
      for (int i = 0; i < 4; i++)
        acc[i][j] = __builtin_amdgcn_mfma_f32_16x16x32_bf16(af[i], bfv, acc[i][j], 0, 0, 0);
    }
  }

#pragma unroll
  for (int i = 0; i < 4; i++)
#pragma unroll
    for (int j = 0; j < 12; j++)
#pragma unroll
      for (int e = 0; e < 4; e++) {
        const int gr = w * 64 + i * 16 + fc * 4 + e;
        const int gc = j * 16 + fr;
        const float val = acc[i][j][e];
        if (gr < 192) {
          const int sbb = gr >> 6, jbb = gc >> 6;
          if (jbb <= sbb)
            G16[(size_t)ch * 24576 + (size_t)(sbb * (sbb + 1) / 2 + jbb) * 4096 +
                (gr & 63) * 64 + (gc & 63)] = __float2bfloat16(val);
        } else {
          const int t = gr - 192;
          const float mval = ((gc / 3) <= t) ? val : 0.f;
          Astk[(size_t)ch * 24576 + (size_t)(64 + t) * 192 + gc] = __float2bfloat16(mval);
        }
      }

  // KT rows: Astk[ch][d][i] = K[i][d] (from swizzled LDS)
  for (int s = tid; s < 1536; s += 256) {
    const int d = s / 24, i0 = (s % 24) * 8;
    __hip_bfloat16 tmp[8];
#pragma unroll
    for (int e = 0; e < 8; e++) {
      const int i = i0 + e;
      tmp[e] = *(const __hip_bfloat16*)((char*)Sa + i * 128 +
                                        (((d >> 3) ^ ((i >> 1) & 3)) * 16) + (d & 7) * 2);
    }
    *(bf16x8*)(Astk + (size_t)ch * 24576 + (size_t)d * 192 + i0) = *(bf16x8*)tmp;
  }
}

// ---------------------------------------------------------------------------
// chunk_solve: grid (1024, 2). Block (ch, half) solves (I + Ltil) Xt = Rt for
// its 64-column half (half 0: K, half 1: V/c); Ltil[i][j] = beta_j*G[i][j].
// 2 blocks/CU (67 KB LDS). Register-cached updates + float4 tile broadcasts;
// diagonal 16-sub-blocks solved fully in registers.
// Writes Bt[col][i] = beta_i * Xt[i][col] (bf16) in-place over its own strip.
// ---------------------------------------------------------------------------
__global__ __launch_bounds__(256) void chunk_solve(
    const __hip_bfloat16* __restrict__ G16,
    __hip_bfloat16* __restrict__ KP16, __hip_bfloat16* __restrict__ VP16,
    const float* __restrict__ betp, const float* __restrict__ decp) {
  const int ch = blockIdx.x;
  const int half = blockIdx.y;
  const int tid = threadIdx.x;
  constexpr int XS = 65;   // X row stride (odd: transposed reads bank-spread)
  constexpr int TS = 68;   // tile row stride (rows 16B-aligned for float4)
  __shared__ float X[192 * XS];      // 49,920 B
  __shared__ float tile[64 * TS];    // 17,408 B
  __shared__ float bet[192], cpre[64], rc[64];

  if (tid < 192) bet[tid] = betp[(size_t)ch * 192 + tid];
  if (tid < 64) cpre[tid] = decp[(size_t)ch * 64 + tid];
  __syncthreads();
  if (tid == 0) {
    float p = 1.f;
    for (int t = 0; t < 64; t++) { p *= cpre[t]; cpre[t] = p; }
  }
  __syncthreads();
  if (tid < 64) rc[tid] = 1.f / cpre[tid];
  __syncthreads();

  // stage RHS (this half's 64 columns): half 0 -> K, half 1 -> V / c_tau(i)
  __hip_bfloat16* rhs = (half ? VP16 : KP16) + (size_t)ch * 12288;
  for (int v = tid; v < 1536; v += 256) {
    const int i = v >> 3, d0 = (v & 7) * 8;
    bf16x8 vb8 = *(const bf16x8*)(rhs + i * 64 + d0);
    const float sc = half ? rc[i / 3] : 1.f;
#pragma unroll
    for (int e = 0; e < 8; e++)
      X[i * XS + d0 + e] = __bfloat162float(*(((const __hip_bfloat16*)&vb8) + e)) * sc;
  }
  __syncthreads();

  const int col = tid & 63;
  const int rg  = tid >> 6;   // wave id 0..3

  for (int sb = 0; sb < 3; sb++) {
    const int s = sb * 64;
    // ---- off-diagonal rank-64 updates (register-cached, float4 tile reads)
    for (int jb = 0; jb < sb; jb++) {
      const __hip_bfloat16* gt = G16 + (size_t)ch * 24576 +
                                 (size_t)(sb * (sb + 1) / 2 + jb) * 4096;
      for (int idx = tid; idx < 4096; idx += 256)
        tile[(idx >> 6) * TS + (idx & 63)] =
            __bfloat162float(gt[idx]) * bet[jb * 64 + (idx & 63)];
      __syncthreads();

      float acc[16];
#pragma unroll
      for (int n = 0; n < 16; n++) acc[n] = X[(s + rg * 16 + n) * XS + col];
#pragma unroll
      for (int hf = 0; hf < 2; hf++) {
        float xreg[32];
#pragma unroll
        for (int j = 0; j < 32; j++) xreg[j] = X[(jb * 64 + hf * 32 + j) * XS + col];
#pragma unroll
        for (int n = 0; n < 16; n++) {
          const float4* trow = (const float4*)&tile[(rg * 16 + n) * TS + hf * 32];
#pragma unroll
          for (int j4 = 0; j4 < 8; j4++) {
            const float4 tv = trow[j4];
            acc[n] = fmaf(-tv.x, xreg[j4 * 4 + 0], acc[n]);
            acc[n] = fmaf(-tv.y, xreg[j4 * 4 + 1], acc[n]);
            acc[n] = fmaf(-tv.z, xreg[j4 * 4 + 2], acc[n]);
            acc[n] = fmaf(-tv.w, xreg[j4 * 4 + 3], acc[n]);
          }
        }
      }
#pragma unroll
      for (int n = 0; n < 16; n++) X[(s + rg * 16 + n) * XS + col] = acc[n];
      __syncthreads();
    }

    // ---- stage diagonal Ltil block
    {
      const __hip_bfloat16* gt = G16 + (size_t)ch * 24576 +
                                 (size_t)(sb * (sb + 1) / 2 + sb) * 4096;
      for (int idx = tid; idx < 4096; idx += 256)
        tile[(idx >> 6) * TS + (idx & 63)] =
            __bfloat162float(gt[idx]) * bet[s + (idx & 63)];
    }
    __syncthreads();

    // ---- 16-sub-blocked diagonal solve
    for (int db = 0; db < 4; db++) {
      const int l0 = db * 16;
      if (tid < 64) {  // one wave: serial 16-row solve entirely in registers
        float xd[16];
#pragma unroll
        for (int j = 0; j < 16; j++) xd[j] = X[(s + l0 + j) * XS + tid];
#pragma unroll
        for (int ii = 1; ii < 16; ii++)
          for (int jj = 0; jj < ii; jj++)
            xd[ii] = fmaf(-tile[(l0 + ii) * TS + l0 + jj], xd[jj], xd[ii]);
#pragma unroll
        for (int j = 1; j < 16; j++) X[(s + l0 + j) * XS + tid] = xd[j];
      }
      __syncthreads();
      // trailing rank-16 update on rows l0+16..63 (all 4 waves)
      const int rem = 48 - l0;
      if (rem > 0) {
        float xc[16];
#pragma unroll
        for (int j = 0; j < 16; j++) xc[j] = X[(s + l0 + j) * XS + col];
        const int rpt = rem >> 2;  // rows per wave: 12, 8, 4
        for (int n = 0; n < rpt; n++) {
          const int r = l0 + 16 + rg * rpt + n;
          float acc = X[(s + r) * XS + col];
          const float4* trow = (const float4*)&tile[r * TS + l0];
#pragma unroll
          for (int j4 = 0; j4 < 4; j4++) {
            const float4 tv = trow[j4];
            acc = fmaf(-tv.x, xc[j4 * 4 + 0], acc);
            acc = fmaf(-tv.y, xc[j4 * 4 + 1], acc);
            acc = fmaf(-tv.z, xc[j4 * 4 + 2], acc);
            acc = fmaf(-tv.w, xc[j4 * 4 + 3], acc);
          }
          X[(s + r) * XS + col] = acc;
        }
      }
      __syncthreads();
    }
  }

  // ---- write Bt over this half's strip: Bt[col][i] = beta_i * X[i][col]
  for (int v = tid; v < 1536; v += 256) {
    const int c2 = v / 24, i0 = (v % 24) * 8;
    __hip_bfloat16 tmp[8];
#pragma unroll
    for (int e = 0; e < 8; e++)
      tmp[e] = __float2bfloat16(bet[i0 + e] * X[(i0 + e) * XS + c2]);
    *(bf16x8*)(rhs + c2 * 192 + i0) = *(bf16x8*)tmp;
  }
}

// ---------------------------------------------------------------------------
// products: per ch. Out(128x128) = Astk(128x192) x Bt(128x192)^T-NT.
// ---------------------------------------------------------------------------
__global__ __launch_bounds__(256) void products(
    const __hip_bfloat16* __restrict__ Astk,
    const __hip_bfloat16* __restrict__ KP16, const __hip_bfloat16* __restrict__ VP16,
    const __hip_bfloat16* __restrict__ qpack, const float* __restrict__ decp,
    float* __restrict__ Tc, float* __restrict__ Qe,
    float* __restrict__ BcW, float* __restrict__ VoW) {
  const int ch = blockIdx.x;
  const int tid = threadIdx.x;
  const int w = tid >> 6, lane = tid & 63;
  __shared__ __hip_bfloat16 As[128 * 32];
  __shared__ __hip_bfloat16 Bs[128 * 32];
  __shared__ float cpre[64];

  if (tid < 64) cpre[tid] = decp[(size_t)ch * 64 + tid];
  __syncthreads();
  if (tid == 0) {
    float p = 1.f;
    for (int t = 0; t < 64; t++) { p *= cpre[t]; cpre[t] = p; }
  }

  const int sr = tid >> 2, sp = tid & 3;
  const int g0 = sp ^ ((sr >> 1) & 3);
  const __hip_bfloat16* a0 = Astk + (size_t)ch * 24576 + sr * 192 + g0 * 8;
  const __hip_bfloat16* a1 = a0 + 64 * 192;
  const __hip_bfloat16* b0 = KP16 + (size_t)ch * 12288 + sr * 192 + g0 * 8;
  const __hip_bfloat16* b1 = VP16 + (size_t)ch * 12288 + sr * 192 + g0 * 8;
  char* AsB = (char*)As + w * 1024;
  char* BsB = (char*)Bs + w * 1024;

  const int wr = w >> 1, wc = w & 1;
  const int fr = lane & 15, fc = lane >> 4;
  int aOff[4], bOff[4];
#pragma unroll
  for (int f = 0; f < 4; f++) {
    const int ra = wr * 64 + f * 16 + fr;
    aOff[f] = ra * 64 + ((fc ^ ((ra >> 1) & 3)) * 16);
    const int rb = wc * 64 + f * 16 + fr;
    bOff[f] = rb * 64 + ((fc ^ ((rb >> 1) & 3)) * 16);
  }

  f32x4 acc[4][4];
#pragma unroll
  for (int i = 0; i < 4; i++)
#pragma unroll
    for (int j = 0; j < 4; j++) acc[i][j] = (f32x4){0.f, 0.f, 0.f, 0.f};

  for (int k0 = 0; k0 < 192; k0 += 32) {
    __syncthreads();
    glds16(a0 + k0, AsB);
    glds16(a1 + k0, AsB + 4096);
    glds16(b0 + k0, BsB);
    glds16(b1 + k0, BsB + 4096);
    __syncthreads();

    bf16x8 af[4], bfr[4];
#pragma unroll
    for (int f = 0; f < 4; f++) af[f] = *(const bf16x8*)((const char*)As + aOff[f]);
#pragma unroll
    for (int f = 0; f < 4; f++) bfr[f] = *(const bf16x8*)((const char*)Bs + bOff[f]);
#pragma unroll
    for (int i = 0; i < 4; i++)
#pragma unroll
      for (int j = 0; j < 4; j++)
        acc[i][j] = __builtin_amdgcn_mfma_f32_16x16x32_bf16(af[i], bfr[j], acc[i][j], 0, 0, 0);
  }
  __syncthreads();

  const float cC = cpre[63];
#pragma unroll
  for (int i = 0; i < 4; i++)
#pragma unroll
    for (int j = 0; j < 4; j++)
#pragma unroll
      for (int e = 0; e < 4; e++) {
        const int rr = wr * 64 + i * 16 + fc * 4 + e;
        const int cc = wc * 64 + j * 16 + fr;
        const float val = acc[i][j][e];
        if (rr < 64) {
          if (cc < 64)
            Tc[(size_t)ch * 4096 + rr * 64 + cc] = cC * (((rr == cc) ? 1.f : 0.f) - val);
          else
            BcW[(size_t)ch * 6144 + rr * 64 + (cc - 64)] = cC * val;
        } else {
          const int t = rr - 64;
          const float ct = cpre[t];
          if (cc < 64) {
            const float qv = __bfloat162float(qpack[(size_t)ch * 4096 + t * 64 + cc]);
            Qe[(size_t)ch * 4096 + t * 64 + cc] = ct * (qv - val);
          } else {
            VoW[(size_t)ch * 6144 + t * 64 + (cc - 64)] = ct * val;
          }
        }
      }
}

// ---------------------------------------------------------------------------
// state_scan: 64 blocks = (b,h) x v-half. Sequential state pass only.
// ---------------------------------------------------------------------------
__global__ __launch_bounds__(256) void state_scan(
    const float* __restrict__ Tc, const float* __restrict__ BcS,
    const float* __restrict__ lwcb, float* __restrict__ S0g) {
  const int blk = blockIdx.x;
  const int bh = blk >> 1, vh = blk & 1;
  const int b = bh >> 4, h = bh & 15;
  const int vbase = vh * 32;
  const int tid = threadIdx.x;
  const int v = tid & 31;
  const int tg = tid >> 5;  // 0..7

  __shared__ float stL[6][64][32];   // 48 KB
  __shared__ float S0s[64][32];      //  8 KB
  __shared__ float Tt[64][64];       // 16 KB
  __shared__ float Bt_[64][32];      //  8 KB

  for (int idx = tid; idx < 6 * 2048; idx += 256) ((float*)stL)[idx] = 0.f;

  float tReg[16], bReg[8];
  {
    const size_t ch0 = (size_t)bh * 32;
#pragma unroll
    for (int i = 0; i < 16; i++) tReg[i] = Tc[ch0 * 4096 + tid + i * 256];
#pragma unroll
    for (int i = 0; i < 8; i++) {
      const int idx = tid + i * 256;
      bReg[i] = BcS[ch0 * 6144 + (idx >> 5) * 64 + vbase + (idx & 31)];
    }
  }
  __syncthreads();

  for (int c = 0; c < 32; c++) {
    const size_t ch = (size_t)bh * 32 + c;
#pragma unroll
    for (int i = 0; i < 16; i++) ((float*)Tt)[tid + i * 256] = tReg[i];
#pragma unroll
    for (int i = 0; i < 8; i++) ((float*)Bt_)[tid + i * 256] = bReg[i];

    const float* lwp = lwcb + ((size_t)(b * kNc + c) * kH + h) * 16;
    float lw[6];
#pragma unroll
    for (int l = 0; l < 6; l++) lw[l] = lwp[l];
#pragma unroll
    for (int n = 0; n < 8; n++) {
      const int k = n * 8 + tg;
      float s = 0.f;
#pragma unroll
      for (int l = 0; l < 6; l++) s = fmaf(lw[l], stL[l][k][v], s);
      S0s[k][v] = s;
      S0g[ch * 4096 + k * 64 + vbase + v] = s;
    }
    __syncthreads();

    const size_t chn = (size_t)bh * 32 + (c < 31 ? c + 1 : 31);
#pragma unroll
    for (int i = 0; i < 16; i++) tReg[i] = Tc[chn * 4096 + tid + i * 256];
#pragma unroll
    for (int i = 0; i < 8; i++) {
      const int idx = tid + i * 256;
      bReg[i] = BcS[chn * 6144 + (idx >> 5) * 64 + vbase + (idx & 31)];
    }

    const int lev = __builtin_ctz(c + 1);
#pragma unroll
    for (int n = 0; n < 8; n++) {
      const int r = n * 8 + tg;
      float s = Bt_[r][v];
#pragma unroll 8
      for (int k = 0; k < 64; k++) s = fmaf(Tt[r][k], S0s[k][v], s);
      for (int l = 0; l < lev; l++) { s += stL[l][r][v]; stL[l][r][v] = 0.f; }
      stL[lev][r][v] = s;
    }
    __syncthreads();
  }
}

// ---------------------------------------------------------------------------
// o_gemm: 1024 parallel blocks. O = Qe * S0 + Vo.
// ---------------------------------------------------------------------------
__global__ __launch_bounds__(256) void o_gemm(
    const float* __restrict__ Qe, const float* __restrict__ S0g,
    const float* __restrict__ VoS, float* __restrict__ Obuf) {
  const int ch = blockIdx.x;
  const int tid = threadIdx.x;
  const int v = tid & 63;
  const int tg = tid >> 6;  // 0..3
  __shared__ float Qs[64][64];
  __shared__ float Ss[64][64];
  for (int idx = tid; idx < 4096; idx += 256) {
    ((float*)Qs)[idx] = Qe[(size_t)ch * 4096 + idx];
    ((float*)Ss)[idx] = S0g[(size_t)ch * 4096 + idx];
  }
  __syncthreads();
#pragma unroll
  for (int n = 0; n < 16; n++) {
    const int t = n * 4 + tg;
    float o = VoS[(size_t)ch * 6144 + t * 64 + v];
#pragma unroll 8
    for (int k = 0; k < 64; k++) o = fmaf(Qs[t][k], Ss[k][v], o);
    Obuf[(size_t)ch * 4096 + t * 64 + v] = o;
  }
}

// ---------------------------------------------------------------------------
__global__ __launch_bounds__(256) void gn_stats(const float* __restrict__ Obuf,
                                                float* __restrict__ stats) {
  const int bh = blockIdx.x;
  double sum = 0.0, sumsq = 0.0;
  for (int idx = threadIdx.x; idx < kNc * 4096; idx += 256) {
    const float val = Obuf[(size_t)bh * 131072 + idx];
    sum += val;
    sumsq += (double)val * val;
  }
  __shared__ double sred[256], qred[256];
  sred[threadIdx.x] = sum;
  qred[threadIdx.x] = sumsq;
  __syncthreads();
  for (int stp = 128; stp > 0; stp >>= 1) {
    if (threadIdx.x < stp) {
      sred[threadIdx.x] += sred[threadIdx.x + stp];
      qred[threadIdx.x] += qred[threadIdx.x + stp];
    }
    __syncthreads();
  }
  if (threadIdx.x == 0) {
    const double n = (double)kT * 64.0;
    const double mu = sred[0] / n;
    const double var = qred[0] / n - mu * mu;
    stats[bh * 2] = (float)mu;
    stats[bh * 2 + 1] = (float)(1.0 / sqrt(var + 1e-5));
  }
}

__global__ void gate_kernel(const float* __restrict__ Obuf,
                            const __hip_bfloat16* __restrict__ og,
                            const float* __restrict__ gamma, const float* __restrict__ gbeta,
                            const float* __restrict__ stats, __hip_bfloat16* __restrict__ z) {
  const size_t idx = (size_t)blockIdx.x * 256 + threadIdx.x;
  if (idx >= (size_t)kM * 1024) return;
  const int cidx = (int)(idx & 1023);
  const int h = cidx >> 6, v = cidx & 63;
  const size_t m = idx >> 10;
  const int b = (int)(m >> 11);
  const int tok = (int)(m & 2047), c = tok >> 6, tt = tok & 63;
  const float o = Obuf[(size_t)((b * 16 + h) * 32 + c) * 4096 + tt * 64 + v];
  const float mu = stats[(b * 16 + h) * 2];
  const float rstd = stats[(b * 16 + h) * 2 + 1];
  const float val = (o - mu) * rstd * gamma[cidx] + gbeta[cidx];
  const float gt = __bfloat162float(og[idx]);
  z[idx] = __float2bfloat16(val * (1.f / (1.f + expf(-gt))));
}

// ---------------------------------------------------------------------------
extern "C" void kernel_launch(void* const* d_in, const int* in_sizes, int n_in,
                              void* d_out, int out_size, void* d_ws, size_t ws_size,
                              hipStream_t stream) {
  const float* x     = (const float*)d_in[0];
  const float* Wq    = (const float*)d_in[3];
  const float* Wk    = (const float*)d_in[4];
  const float* Wv    = (const float*)d_in[5];
  const float* Wb    = (const float*)d_in[6];
  const float* Wa    = (const float*)d_in[7];
  const float* Wg    = (const float*)d_in[8];
  const float* Wo    = (const float*)d_in[9];
  const float* Wl    = (const float*)d_in[10];
  const float* Lp    = (const float*)d_in[11];
  const float* gamma = (const float*)d_in[12];
  const float* gbeta = (const float*)d_in[13];
  float* out = (float*)d_out;
  (void)ws_size;  // peak usage < 181,469,440 proven in round 1

  char* base = (char*)d_ws;
  // P1: qpack -> zbf
  __hip_bfloat16* qpack = (__hip_bfloat16*)(base + 0);                 // 8,388,608
  __hip_bfloat16* zbf   = qpack;                                       // after products
  // P2/P3: kv packs -> Bt (in-place) -> Bc/Vo f32 (in-place)
  __hip_bfloat16* KP16 = (__hip_bfloat16*)(base + 8388608);            // 25,165,824
  __hip_bfloat16* VP16 = (__hip_bfloat16*)(base + 33554432);           // 25,165,824
  // P4 region (50,331,648): early = xb + weights; then G16; then Tc/Qe/Obuf
  char* P4 = base + 58720256;
  __hip_bfloat16* xb   = (__hip_bfloat16*)(P4 + 0);                    // 8,388,608
  __hip_bfloat16* Wqb  = (__hip_bfloat16*)(P4 + 8388608);              // 2,097,152
  __hip_bfloat16* Wkb  = (__hip_bfloat16*)(P4 + 10485760);             // 6,291,456
  __hip_bfloat16* Wvb  = (__hip_bfloat16*)(P4 + 16777216);             // 6,291,456
  __hip_bfloat16* Wgb  = (__hip_bfloat16*)(P4 + 23068672);             // 2,097,152
  __hip_bfloat16* Wlb  = (__hip_bfloat16*)(P4 + 25165824);             // 524,288
  __hip_bfloat16* Wbdb = (__hip_bfloat16*)(P4 + 25690112);             // 262,144
  __hip_bfloat16* G16  = (__hip_bfloat16*)P4;                          // full 50,331,648
  float* Tc   = (float*)(P4 + 0);                                      // 16,777,216
  float* Qe   = (float*)(P4 + 16777216);                               // 16,777,216
  float* Obuf = (float*)(P4 + 33554432);                               // 16,777,216
  // P5 region (50,331,648): early = lwb; then Astk; then S0g (Astk dead)
  char* P5 = base + 109051904;
  float* lwb = (float*)(P5 + 0);                                       // 4,194,304
  __hip_bfloat16* Astk = (__hip_bfloat16*)P5;                          // 50,331,648
  float* S0g = (float*)P5;                                             // 16,777,216
  // P6: persistent small
  char* P6 = base + 159383552;
  float* betp  = (float*)(P6 + 0);                                     // 786,432
  float* decp  = (float*)(P6 + 786432);                                // 262,144
  float* lwcb  = (float*)(P6 + 1048576);                               // 65,536
  float* statb = (float*)(P6 + 1114112);                               // 1,024
  __hip_bfloat16* Wob = (__hip_bfloat16*)(P6 + 1115136);               // 2,097,152
  __hip_bfloat16* ogb = (__hip_bfloat16*)(P6 + 3212288);               // 8,388,608

  const dim3 blk(256);

  // casts
  cast_bf16<<<dim3(4096), blk, 0, stream>>>(x,  xb,  kM * 1024);
  cast_bf16<<<dim3(1024), blk, 0, stream>>>(Wq, Wqb, 1024 * 1024);
  cast_bf16<<<dim3(3072), blk, 0, stream>>>(Wk, Wkb, 3072 * 1024);
  cast_bf16<<<dim3(3072), blk, 0, stream>>>(Wv, Wvb, 3072 * 1024);
  cast_bf16<<<dim3(1024), blk, 0, stream>>>(Wg, Wgb, 1024 * 1024);
  cast_bf16<<<dim3(256),  blk, 0, stream>>>(Wl, Wlb, 256 * 1024);
  cast_bf16<<<dim3(1024), blk, 0, stream>>>(Wo, Wob, 1024 * 1024);
  cast_bd<<<dim3(512), blk, 0, stream>>>(Wb, Wa, Wbdb);

  // projections
  gemm_bf16<6><<<dim3(8, 32),  blk, 0, stream>>>(xb, Wqb,  qpack, nullptr, 1024, nullptr);
  gemm_bf16<5><<<dim3(24, 32), blk, 0, stream>>>(xb, Wkb,  KP16,  nullptr, 3072, nullptr);
  gemm_bf16<5><<<dim3(24, 32), blk, 0, stream>>>(xb, Wvb,  VP16,  nullptr, 3072, nullptr);
  gemm_bf16<3><<<dim3(1, 32),  blk, 0, stream>>>(xb, Wbdb, betp,  decp,    128,  nullptr);
  gemm_bf16<4><<<dim3(2, 32),  blk, 0, stream>>>(xb, Wlb,  lwb,   nullptr, 256,  Lp);
  gemm_bf16<7><<<dim3(8, 32),  blk, 0, stream>>>(xb, Wgb,  ogb,   nullptr, 1024, nullptr);

  lwc_mean<<<dim3(64), blk, 0, stream>>>(lwb, lwcb);

  // chunk operators
  gram_phi<<<dim3(1024), blk, 0, stream>>>(KP16, qpack, G16, Astk);
  chunk_solve<<<dim3(1024, 2), blk, 0, stream>>>(G16, KP16, VP16, betp, decp);
  products<<<dim3(1024), blk, 0, stream>>>(Astk, KP16, VP16, qpack, decp,
                                           Tc, Qe, (float*)KP16, (float*)VP16);

  // sequential state scan (light) + parallel O gemm
  state_scan<<<dim3(64), blk, 0, stream>>>(Tc, (const float*)KP16, lwcb, S0g);
  o_gemm<<<dim3(1024), blk, 0, stream>>>(Qe, S0g, (const float*)VP16, Obuf);

  // group norm + gate
  gn_stats<<<dim3(kB * kH), blk, 0, stream>>>(Obuf, statb);
  gate_kernel<<<dim3((kM * 1024 + 255) / 256), blk, 0, stream>>>(Obuf, ogb, gamma, gbeta,
                                                                 statb, zbf);

  // final projection
  gemm_bf16<0><<<dim3(8, 32), blk, 0, stream>>>(zbf, Wob, out, nullptr, 1024, nullptr);
}

// Round 9
// 796.161 us; speedup vs baseline: 7.9730x; 1.2307x over previous
//
#include <hip/hip_runtime.h>
#include <hip/hip_bf16.h>
#include <math.h>

// Problem constants
constexpr int kB   = 2;
constexpr int kT   = 2048;
constexpr int kH   = 16;
constexpr int kC   = 64;    // chunk size
constexpr int kNc  = 32;    // T / C
constexpr int kM   = kB * kT;   // 4096
constexpr int kK   = 1024;

using bf16x8 = __attribute__((ext_vector_type(8))) short;
using f32x4  = __attribute__((ext_vector_type(4))) float;

__device__ __forceinline__ void glds16(const void* g, void* l) {
  __builtin_amdgcn_global_load_lds(
      (const __attribute__((address_space(1))) unsigned int*)g,
      (__attribute__((address_space(3))) unsigned int*)l, 16, 0, 0);
}

// ---------------------------------------------------------------------------
// bf16 MFMA NT-GEMM (verified structure). MODE:
//  0: f32 plain [rr*N+cc]
//  3: beta(48)/dec(16) sigmoid -> betp [ch][192] f32, decp [ch][64] f32
//  4: softplus(Lp*x) f32 plain (lw)
//  5: silu -> bf16 pack [ch][i=tt*3+j3][d]
//  6: bf16 q pack [ch][t][d]
//  7: bf16 plain [rr*1024+cc] (og)
// ---------------------------------------------------------------------------
template <int MODE>
__global__ __launch_bounds__(256) void gemm_bf16(
    const __hip_bfloat16* __restrict__ A, const __hip_bfloat16* __restrict__ W,
    void* __restrict__ outA, void* __restrict__ outB, int N,
    const float* __restrict__ Lp) {
  __shared__ __hip_bfloat16 As[128 * 32];
  __shared__ __hip_bfloat16 Bs[128 * 32];
  const int tid = threadIdx.x;
  const int w = tid >> 6, lane = tid & 63;
  const int bm = blockIdx.y * 128, bn = blockIdx.x * 128;

  const int sr = tid >> 2, sp = tid & 3;
  const int g0 = sp ^ ((sr >> 1) & 3);
  const __hip_bfloat16* a0 = A + (size_t)(bm + sr) * kK + g0 * 8;
  const __hip_bfloat16* a1 = A + (size_t)(bm + sr + 64) * kK + g0 * 8;
  const __hip_bfloat16* b0 = W + (size_t)(bn + sr) * kK + g0 * 8;
  const __hip_bfloat16* b1 = W + (size_t)(bn + sr + 64) * kK + g0 * 8;
  char* AsB = (char*)As + w * 1024;
  char* BsB = (char*)Bs + w * 1024;

  const int wr = w >> 1, wc = w & 1;
  const int fr = lane & 15, fc = lane >> 4;
  int aOff[4], bOff[4];
#pragma unroll
  for (int f = 0; f < 4; f++) {
    const int ra = wr * 64 + f * 16 + fr;
    aOff[f] = ra * 64 + ((fc ^ ((ra >> 1) & 3)) * 16);
    const int rb = wc * 64 + f * 16 + fr;
    bOff[f] = rb * 64 + ((fc ^ ((rb >> 1) & 3)) * 16);
  }

  f32x4 acc[4][4];
#pragma unroll
  for (int i = 0; i < 4; i++)
#pragma unroll
    for (int j = 0; j < 4; j++) acc[i][j] = (f32x4){0.f, 0.f, 0.f, 0.f};

  for (int k0 = 0; k0 < kK; k0 += 32) {
    __syncthreads();
    glds16(a0 + k0, AsB);
    glds16(a1 + k0, AsB + 4096);
    glds16(b0 + k0, BsB);
    glds16(b1 + k0, BsB + 4096);
    __syncthreads();

    bf16x8 af[4], bfr[4];
#pragma unroll
    for (int f = 0; f < 4; f++) af[f] = *(const bf16x8*)((const char*)As + aOff[f]);
#pragma unroll
    for (int f = 0; f < 4; f++) bfr[f] = *(const bf16x8*)((const char*)Bs + bOff[f]);
#pragma unroll
    for (int i = 0; i < 4; i++)
#pragma unroll
      for (int j = 0; j < 4; j++)
        acc[i][j] = __builtin_amdgcn_mfma_f32_16x16x32_bf16(af[i], bfr[j], acc[i][j], 0, 0, 0);
  }

  const int r0 = bm + wr * 64, c0 = bn + wc * 64;
#pragma unroll
  for (int i = 0; i < 4; i++)
#pragma unroll
    for (int j = 0; j < 4; j++)
#pragma unroll
      for (int e = 0; e < 4; e++) {
        const int rr = r0 + i * 16 + fc * 4 + e;
        const int cc = c0 + j * 16 + fr;
        float vx = acc[i][j][e];
        if constexpr (MODE == 0) {
          ((float*)outA)[(size_t)rr * N + cc] = vx;
        } else if constexpr (MODE == 4) {
          const float y = Lp[cc] * vx;
          vx = fmaxf(y, 0.f) + log1pf(expf(-fabsf(y)));
          ((float*)outA)[(size_t)rr * N + cc] = vx;
        } else if constexpr (MODE == 3) {
          const float s = 1.f / (1.f + expf(-vx));
          const int b = rr >> 11, tok = rr & 2047, chn = tok >> 6, tt = tok & 63;
          if (cc < 48) {
            const int hh = cc / 3, j3 = cc - hh * 3;
            ((float*)outA)[(size_t)((b * 16 + hh) * 32 + chn) * 192 + tt * 3 + j3] = s;
          } else if (cc < 64) {
            const int hh = cc - 48;
            ((float*)outB)[(size_t)((b * 16 + hh) * 32 + chn) * 64 + tt] = s;
          }
        } else if constexpr (MODE == 5) {
          vx = vx / (1.f + expf(-vx));
          const int b = rr >> 11, tok = rr & 2047, chn = tok >> 6, tt = tok & 63;
          const int hh = cc / 192, rem = cc - hh * 192;
          const int d = rem / 3, j3 = rem - d * 3;
          ((__hip_bfloat16*)outA)[(size_t)((b * 16 + hh) * 32 + chn) * 12288 +
                                  (tt * 3 + j3) * 64 + d] = __float2bfloat16(vx);
        } else if constexpr (MODE == 6) {
          const int b = rr >> 11, tok = rr & 2047, chn = tok >> 6, tt = tok & 63;
          const int hh = cc >> 6, d = cc & 63;
          ((__hip_bfloat16*)outA)[(size_t)((b * 16 + hh) * 32 + chn) * 4096 +
                                  tt * 64 + d] = __float2bfloat16(vx);
        } else if constexpr (MODE == 7) {
          ((__hip_bfloat16*)outA)[(size_t)rr * 1024 + cc] = __float2bfloat16(vx);
        }
      }
}

// ---------------------------------------------------------------------------
__global__ void cast_bf16(const float* __restrict__ in, __hip_bfloat16* __restrict__ out, int n) {
  const int i = (blockIdx.x * 256 + threadIdx.x) * 4;
  if (i >= n) return;
  const float4 v = *(const float4*)(in + i);
  __hip_bfloat16 tmp[4] = {__float2bfloat16(v.x), __float2bfloat16(v.y),
                           __float2bfloat16(v.z), __float2bfloat16(v.w)};
  *(ushort4*)(out + i) = *(ushort4*)tmp;
}

__global__ void cast_bd(const float* __restrict__ Wb, const float* __restrict__ Wa,
                        __hip_bfloat16* __restrict__ out) {
  const int idx = blockIdx.x * 256 + threadIdx.x;
  if (idx >= 128 * 1024) return;
  const int r = idx >> 10, k = idx & 1023;
  const float val = (r < 48) ? Wb[r * 1024 + k] : ((r < 64) ? Wa[(r - 48) * 1024 + k] : 0.f);
  out[idx] = __float2bfloat16(val);
}

__global__ void lwc_mean(const float* __restrict__ lw, float* __restrict__ lwc) {
  const int idx = blockIdx.x * 256 + threadIdx.x;
  if (idx >= kB * kNc * kH * 16) return;
  const int l = idx & 15, h = (idx >> 4) & 15, c = (idx >> 8) & 31, b = idx >> 13;
  size_t base = ((size_t)b * kT + (size_t)c * kC) * 256 + h * 16 + l;
  float s = 0.f;
  for (int tt = 0; tt < kC; tt++) s += lw[base + (size_t)tt * 256];
  lwc[idx] = s * (1.f / 64.f);
}

// ---------------------------------------------------------------------------
// gram_phi: per-chunk-head. S = [K(192); Q(64)] (256x64 bf16). Out = S*K^T.
// ---------------------------------------------------------------------------
__global__ __launch_bounds__(256, 1) void gram_phi(
    const __hip_bfloat16* __restrict__ KP16, const __hip_bfloat16* __restrict__ qpack,
    __hip_bfloat16* __restrict__ G16, __hip_bfloat16* __restrict__ Astk) {
  const int ch = blockIdx.x;
  const int tid = threadIdx.x;
  const int w = tid >> 6, lane = tid & 63;
  __shared__ __hip_bfloat16 Sa[256 * 64];  // row-swizzled

  for (int cidx = tid; cidx < 2048; cidx += 256) {
    const int r = cidx >> 3, cko = cidx & 7;
    const __hip_bfloat16* src =
        (r < 192) ? (KP16 + (size_t)ch * 12288 + r * 64 + cko * 8)
                  : (qpack + (size_t)ch * 4096 + (r - 192) * 64 + cko * 8);
    bf16x8 vv = *(const bf16x8*)src;
    *(bf16x8*)((char*)Sa + r * 128 + ((cko ^ ((r >> 1) & 3)) * 16)) = vv;
  }
  __syncthreads();

  const int fr = lane & 15, fc = lane >> 4;
  f32x4 acc[4][12];
#pragma unroll
  for (int i = 0; i < 4; i++)
#pragma unroll
    for (int j = 0; j < 12; j++) acc[i][j] = (f32x4){0.f, 0.f, 0.f, 0.f};

#pragma unroll
  for (int ks = 0; ks < 2; ks++) {
    bf16x8 af[4];
#pragma unroll
    for (int i = 0; i < 4; i++) {
      const int ra = w * 64 + i * 16 + fr;
      af[i] = *(const bf16x8*)((char*)Sa + ra * 128 + (((ks * 4 + fc) ^ ((ra >> 1) & 3)) * 16));
    }
#pragma unroll
    for (int j = 0; j < 12; j++) {
      const int rb = j * 16 + fr;
      bf16x8 bfv = *(const bf16x8*)((char*)Sa + rb * 128 + (((ks * 4 + fc) ^ ((rb >> 1) & 3)) * 16));
#pragma unroll
      for (int i = 0; i < 4; i++)
        acc[i][j] = __builtin_amdgcn_mfma_f32_16x16x32_bf16(af[i], bfv, acc[i][j], 0, 0, 0);
    }
  }

#pragma unroll
  for (int i = 0; i < 4; i++)
#pragma unroll
    for (int j = 0; j < 12; j++)
#pragma unroll
      for (int e = 0; e < 4; e++) {
        const int gr = w * 64 + i * 16 + fc * 4 + e;
        const int gc = j * 16 + fr;
        const float val = acc[i][j][e];
        if (gr < 192) {
          const int sbb = gr >> 6, jbb = gc >> 6;
          if (jbb <= sbb)
            G16[(size_t)ch * 24576 + (size_t)(sbb * (sbb + 1) / 2 + jbb) * 4096 +
                (gr & 63) * 64 + (gc & 63)] = __float2bfloat16(val);
        } else {
          const int t = gr - 192;
          const float mval = ((gc / 3) <= t) ? val : 0.f;
          Astk[(size_t)ch * 24576 + (size_t)(64 + t) * 192 + gc] = __float2bfloat16(mval);
        }
      }

  // KT rows: Astk[ch][d][i] = K[i][d] (from swizzled LDS)
  for (int s = tid; s < 1536; s += 256) {
    const int d = s / 24, i0 = (s % 24) * 8;
    __hip_bfloat16 tmp[8];
#pragma unroll
    for (int e = 0; e < 8; e++) {
      const int i = i0 + e;
      tmp[e] = *(const __hip_bfloat16*)((char*)Sa + i * 128 +
                                        (((d >> 3) ^ ((i >> 1) & 3)) * 16) + (d & 7) * 2);
    }
    *(bf16x8*)(Astk + (size_t)ch * 24576 + (size_t)d * 192 + i0) = *(bf16x8*)tmp;
  }
}

// ---------------------------------------------------------------------------
// chunk_solve: grid (1024, 2). Block (ch, half) solves (I + Ltil) Xt = Rt for
// its 64-column half (half 0: K, half 1: V/c); Ltil[i][j] = beta_j*G[i][j].
// ---------------------------------------------------------------------------
__global__ __launch_bounds__(256) void chunk_solve(
    const __hip_bfloat16* __restrict__ G16,
    __hip_bfloat16* __restrict__ KP16, __hip_bfloat16* __restrict__ VP16,
    const float* __restrict__ betp, const float* __restrict__ decp) {
  const int ch = blockIdx.x;
  const int half = blockIdx.y;
  const int tid = threadIdx.x;
  constexpr int XS = 65;   // X row stride (odd: transposed reads bank-spread)
  constexpr int TS = 68;   // tile row stride (rows 16B-aligned for float4)
  __shared__ float X[192 * XS];      // 49,920 B
  __shared__ float tile[64 * TS];    // 17,408 B
  __shared__ float bet[192], cpre[64], rc[64];

  if (tid < 192) bet[tid] = betp[(size_t)ch * 192 + tid];
  if (tid < 64) cpre[tid] = decp[(size_t)ch * 64 + tid];
  __syncthreads();
  if (tid == 0) {
    float p = 1.f;
    for (int t = 0; t < 64; t++) { p *= cpre[t]; cpre[t] = p; }
  }
  __syncthreads();
  if (tid < 64) rc[tid] = 1.f / cpre[tid];
  __syncthreads();

  // stage RHS (this half's 64 columns): half 0 -> K, half 1 -> V / c_tau(i)
  __hip_bfloat16* rhs = (half ? VP16 : KP16) + (size_t)ch * 12288;
  for (int v = tid; v < 1536; v += 256) {
    const int i = v >> 3, d0 = (v & 7) * 8;
    bf16x8 vb8 = *(const bf16x8*)(rhs + i * 64 + d0);
    const float sc = half ? rc[i / 3] : 1.f;
#pragma unroll
    for (int e = 0; e < 8; e++)
      X[i * XS + d0 + e] = __bfloat162float(*(((const __hip_bfloat16*)&vb8) + e)) * sc;
  }
  __syncthreads();

  const int col = tid & 63;
  const int rg  = tid >> 6;   // wave id 0..3

  for (int sb = 0; sb < 3; sb++) {
    const int s = sb * 64;
    // ---- off-diagonal rank-64 updates (register-cached, float4 tile reads)
    for (int jb = 0; jb < sb; jb++) {
      const __hip_bfloat16* gt = G16 + (size_t)ch * 24576 +
                                 (size_t)(sb * (sb + 1) / 2 + jb) * 4096;
      for (int idx = tid; idx < 4096; idx += 256)
        tile[(idx >> 6) * TS + (idx & 63)] =
            __bfloat162float(gt[idx]) * bet[jb * 64 + (idx & 63)];
      __syncthreads();

      float acc[16];
#pragma unroll
      for (int n = 0; n < 16; n++) acc[n] = X[(s + rg * 16 + n) * XS + col];
#pragma unroll
      for (int hf = 0; hf < 2; hf++) {
        float xreg[32];
#pragma unroll
        for (int j = 0; j < 32; j++) xreg[j] = X[(jb * 64 + hf * 32 + j) * XS + col];
#pragma unroll
        for (int n = 0; n < 16; n++) {
          const float4* trow = (const float4*)&tile[(rg * 16 + n) * TS + hf * 32];
#pragma unroll
          for (int j4 = 0; j4 < 8; j4++) {
            const float4 tv = trow[j4];
            acc[n] = fmaf(-tv.x, xreg[j4 * 4 + 0], acc[n]);
            acc[n] = fmaf(-tv.y, xreg[j4 * 4 + 1], acc[n]);
            acc[n] = fmaf(-tv.z, xreg[j4 * 4 + 2], acc[n]);
            acc[n] = fmaf(-tv.w, xreg[j4 * 4 + 3], acc[n]);
          }
        }
      }
#pragma unroll
      for (int n = 0; n < 16; n++) X[(s + rg * 16 + n) * XS + col] = acc[n];
      __syncthreads();
    }

    // ---- stage diagonal Ltil block
    {
      const __hip_bfloat16* gt = G16 + (size_t)ch * 24576 +
                                 (size_t)(sb * (sb + 1) / 2 + sb) * 4096;
      for (int idx = tid; idx < 4096; idx += 256)
        tile[(idx >> 6) * TS + (idx & 63)] =
            __bfloat162float(gt[idx]) * bet[s + (idx & 63)];
    }
    __syncthreads();

    // ---- 16-sub-blocked diagonal solve
    for (int db = 0; db < 4; db++) {
      const int l0 = db * 16;
      if (tid < 64) {  // one wave: serial 16-row solve entirely in registers
        float xd[16];
#pragma unroll
        for (int j = 0; j < 16; j++) xd[j] = X[(s + l0 + j) * XS + tid];
#pragma unroll
        for (int ii = 1; ii < 16; ii++)
          for (int jj = 0; jj < ii; jj++)
            xd[ii] = fmaf(-tile[(l0 + ii) * TS + l0 + jj], xd[jj], xd[ii]);
#pragma unroll
        for (int j = 1; j < 16; j++) X[(s + l0 + j) * XS + tid] = xd[j];
      }
      __syncthreads();
      // trailing rank-16 update on rows l0+16..63 (all 4 waves)
      const int rem = 48 - l0;
      if (rem > 0) {
        float xc[16];
#pragma unroll
        for (int j = 0; j < 16; j++) xc[j] = X[(s + l0 + j) * XS + col];
        const int rpt = rem >> 2;  // rows per wave: 12, 8, 4
        for (int n = 0; n < rpt; n++) {
          const int r = l0 + 16 + rg * rpt + n;
          float acc = X[(s + r) * XS + col];
          const float4* trow = (const float4*)&tile[r * TS + l0];
#pragma unroll
          for (int j4 = 0; j4 < 4; j4++) {
            const float4 tv = trow[j4];
            acc = fmaf(-tv.x, xc[j4 * 4 + 0], acc);
            acc = fmaf(-tv.y, xc[j4 * 4 + 1], acc);
            acc = fmaf(-tv.z, xc[j4 * 4 + 2], acc);
            acc = fmaf(-tv.w, xc[j4 * 4 + 3], acc);
          }
          X[(s + r) * XS + col] = acc;
        }
      }
      __syncthreads();
    }
  }

  // ---- write Bt over this half's strip: Bt[col][i] = beta_i * X[i][col]
  for (int v = tid; v < 1536; v += 256) {
    const int c2 = v / 24, i0 = (v % 24) * 8;
    __hip_bfloat16 tmp[8];
#pragma unroll
    for (int e = 0; e < 8; e++)
      tmp[e] = __float2bfloat16(bet[i0 + e] * X[(i0 + e) * XS + c2]);
    *(bf16x8*)(rhs + c2 * 192 + i0) = *(bf16x8*)tmp;
  }
}

// ---------------------------------------------------------------------------
// products: per ch. Out(128x128) = Astk(128x192) x Bt(128x192)^T-NT.
// ---------------------------------------------------------------------------
__global__ __launch_bounds__(256) void products(
    const __hip_bfloat16* __restrict__ Astk,
    const __hip_bfloat16* __restrict__ KP16, const __hip_bfloat16* __restrict__ VP16,
    const __hip_bfloat16* __restrict__ qpack, const float* __restrict__ decp,
    float* __restrict__ Tc, float* __restrict__ Qe,
    float* __restrict__ BcW, float* __restrict__ VoW) {
  const int ch = blockIdx.x;
  const int tid = threadIdx.x;
  const int w = tid >> 6, lane = tid & 63;
  __shared__ __hip_bfloat16 As[128 * 32];
  __shared__ __hip_bfloat16 Bs[128 * 32];
  __shared__ float cpre[64];

  if (tid < 64) cpre[tid] = decp[(size_t)ch * 64 + tid];
  __syncthreads();
  if (tid == 0) {
    float p = 1.f;
    for (int t = 0; t < 64; t++) { p *= cpre[t]; cpre[t] = p; }
  }

  const int sr = tid >> 2, sp = tid & 3;
  const int g0 = sp ^ ((sr >> 1) & 3);
  const __hip_bfloat16* a0 = Astk + (size_t)ch * 24576 + sr * 192 + g0 * 8;
  const __hip_bfloat16* a1 = a0 + 64 * 192;
  const __hip_bfloat16* b0 = KP16 + (size_t)ch * 12288 + sr * 192 + g0 * 8;
  const __hip_bfloat16* b1 = VP16 + (size_t)ch * 12288 + sr * 192 + g0 * 8;
  char* AsB = (char*)As + w * 1024;
  char* BsB = (char*)Bs + w * 1024;

  const int wr = w >> 1, wc = w & 1;
  const int fr = lane & 15, fc = lane >> 4;
  int aOff[4], bOff[4];
#pragma unroll
  for (int f = 0; f < 4; f++) {
    const int ra = wr * 64 + f * 16 + fr;
    aOff[f] = ra * 64 + ((fc ^ ((ra >> 1) & 3)) * 16);
    const int rb = wc * 64 + f * 16 + fr;
    bOff[f] = rb * 64 + ((fc ^ ((rb >> 1) & 3)) * 16);
  }

  f32x4 acc[4][4];
#pragma unroll
  for (int i = 0; i < 4; i++)
#pragma unroll
    for (int j = 0; j < 4; j++) acc[i][j] = (f32x4){0.f, 0.f, 0.f, 0.f};

  for (int k0 = 0; k0 < 192; k0 += 32) {
    __syncthreads();
    glds16(a0 + k0, AsB);
    glds16(a1 + k0, AsB + 4096);
    glds16(b0 + k0, BsB);
    glds16(b1 + k0, BsB + 4096);
    __syncthreads();

    bf16x8 af[4], bfr[4];
#pragma unroll
    for (int f = 0; f < 4; f++) af[f] = *(const bf16x8*)((const char*)As + aOff[f]);
#pragma unroll
    for (int f = 0; f < 4; f++) bfr[f] = *(const bf16x8*)((const char*)Bs + bOff[f]);
#pragma unroll
    for (int i = 0; i < 4; i++)
#pragma unroll
      for (int j = 0; j < 4; j++)
        acc[i][j] = __builtin_amdgcn_mfma_f32_16x16x32_bf16(af[i], bfr[j], acc[i][j], 0, 0, 0);
  }
  __syncthreads();

  const float cC = cpre[63];
#pragma unroll
  for (int i = 0; i < 4; i++)
#pragma unroll
    for (int j = 0; j < 4; j++)
#pragma unroll
      for (int e = 0; e < 4; e++) {
        const int rr = wr * 64 + i * 16 + fc * 4 + e;
        const int cc = wc * 64 + j * 16 + fr;
        const float val = acc[i][j][e];
        if (rr < 64) {
          if (cc < 64)
            Tc[(size_t)ch * 4096 + rr * 64 + cc] = cC * (((rr == cc) ? 1.f : 0.f) - val);
          else
            BcW[(size_t)ch * 6144 + rr * 64 + (cc - 64)] = cC * val;
        } else {
          const int t = rr - 64;
          const float ct = cpre[t];
          if (cc < 64) {
            const float qv = __bfloat162float(qpack[(size_t)ch * 4096 + t * 64 + cc]);
            Qe[(size_t)ch * 4096 + t * 64 + cc] = ct * (qv - val);
          } else {
            VoW[(size_t)ch * 6144 + t * 64 + (cc - 64)] = ct * val;
          }
        }
      }
}

// ---------------------------------------------------------------------------
// state_scan: 256 blocks = (b,h) x 8 v-slices (8 cols each). Sequential state
// pass only. S0s stored transposed [v][k] and Tt padded so the k-loop uses
// ds_read_b128; fma order (k ascending, single chain) identical to round 8
// -> bit-identical output.
// ---------------------------------------------------------------------------
__global__ __launch_bounds__(256) void state_scan(
    const float* __restrict__ Tc, const float* __restrict__ BcS,
    const float* __restrict__ lwcb, float* __restrict__ S0g) {
  const int blk = blockIdx.x;       // bh*8 + vs
  const int bh = blk >> 3, vs = blk & 7;
  const int b = bh >> 4, h = bh & 15;
  const int vbase = vs * 8;
  const int tid = threadIdx.x;
  const int v = tid & 7;            // 0..7 (column within slice)
  const int tg = tid >> 3;          // 0..31

  __shared__ float stL[6][64][8];   // 12 KB
  __shared__ float S0s[8][68];      // [v][k], padded (rows 16B-aligned)
  __shared__ float Tt[64][68];      // padded (rows 16B-aligned)
  __shared__ float Bt_[64][8];

  for (int idx = tid; idx < 6 * 512; idx += 256) ((float*)stL)[idx] = 0.f;

  // prefetch chunk 0 into registers
  float tReg[16], bReg[2];
  {
    const size_t ch0 = (size_t)bh * 32;
#pragma unroll
    for (int i = 0; i < 16; i++) tReg[i] = Tc[ch0 * 4096 + tid + i * 256];
#pragma unroll
    for (int i = 0; i < 2; i++) {
      const int idx = tid + i * 256;
      bReg[i] = BcS[ch0 * 6144 + (idx >> 3) * 64 + vbase + (idx & 7)];
    }
  }
  __syncthreads();  // stL zero-init visible

  for (int c = 0; c < 32; c++) {
    const size_t ch = (size_t)bh * 32 + c;
    // commit prefetched tiles (loop-end barrier protected prior readers)
#pragma unroll
    for (int i = 0; i < 16; i++) {
      const int idx = tid + i * 256;
      Tt[idx >> 6][idx & 63] = tReg[i];
    }
#pragma unroll
    for (int i = 0; i < 2; i++) {
      const int idx = tid + i * 256;
      Bt_[idx >> 3][idx & 7] = bReg[i];
    }

    // S0[v][k] for k = tg, tg+32 (same lw fma order as before)
    const float* lwp = lwcb + ((size_t)(b * kNc + c) * kH + h) * 16;
    float lw[6];
#pragma unroll
    for (int l = 0; l < 6; l++) lw[l] = lwp[l];
#pragma unroll
    for (int n = 0; n < 2; n++) {
      const int k = n * 32 + tg;
      float s = 0.f;
#pragma unroll
      for (int l = 0; l < 6; l++) s = fmaf(lw[l], stL[l][k][v], s);
      S0s[v][k] = s;
      S0g[ch * 4096 + k * 64 + vbase + v] = s;
    }
    __syncthreads();

    // issue prefetch for c+1 (hidden under the matmul below)
    const size_t chn = (size_t)bh * 32 + (c < 31 ? c + 1 : 31);
#pragma unroll
    for (int i = 0; i < 16; i++) tReg[i] = Tc[chn * 4096 + tid + i * 256];
#pragma unroll
    for (int i = 0; i < 2; i++) {
      const int idx = tid + i * 256;
      bReg[i] = BcS[chn * 6144 + (idx >> 3) * 64 + vbase + (idx & 7)];
    }

    // Sf rows r = tg, tg+32 (k ascending single fma chain -> identical math)
    const int lev = __builtin_ctz(c + 1);
#pragma unroll
    for (int n = 0; n < 2; n++) {
      const int r = n * 32 + tg;
      float s = Bt_[r][v];
#pragma unroll
      for (int k4 = 0; k4 < 16; k4++) {
        const float4 t4 = *(const float4*)&Tt[r][k4 * 4];
        const float4 s4 = *(const float4*)&S0s[v][k4 * 4];
        s = fmaf(t4.x, s4.x, s);
        s = fmaf(t4.y, s4.y, s);
        s = fmaf(t4.z, s4.z, s);
        s = fmaf(t4.w, s4.w, s);
      }
      for (int l = 0; l < lev; l++) { s += stL[l][r][v]; stL[l][r][v] = 0.f; }
      stL[lev][r][v] = s;
    }
    __syncthreads();
  }
}

// ---------------------------------------------------------------------------
// o_gemm: 1024 parallel blocks. O = Qe * S0 + Vo.
// ---------------------------------------------------------------------------
__global__ __launch_bounds__(256) void o_gemm(
    const float* __restrict__ Qe, const float* __restrict__ S0g,
    const float* __restrict__ VoS, float* __restrict__ Obuf) {
  const int ch = blockIdx.x;
  const int tid = threadIdx.x;
  const int v = tid & 63;
  const int tg = tid >> 6;  // 0..3
  __shared__ float Qs[64][64];
  __shared__ float Ss[64][64];
  for (int idx = tid; idx < 4096; idx += 256) {
    ((float*)Qs)[idx] = Qe[(size_t)ch * 4096 + idx];
    ((float*)Ss)[idx] = S0g[(size_t)ch * 4096 + idx];
  }
  __syncthreads();
#pragma unroll
  for (int n = 0; n < 16; n++) {
    const int t = n * 4 + tg;
    float o = VoS[(size_t)ch * 6144 + t * 64 + v];
#pragma unroll 8
    for (int k = 0; k < 64; k++) o = fmaf(Qs[t][k], Ss[k][v], o);
    Obuf[(size_t)ch * 4096 + t * 64 + v] = o;
  }
}

// ---------------------------------------------------------------------------
__global__ __launch_bounds__(256) void gn_stats(const float* __restrict__ Obuf,
                                                float* __restrict__ stats) {
  const int bh = blockIdx.x;
  double sum = 0.0, sumsq = 0.0;
  for (int idx = threadIdx.x; idx < kNc * 4096; idx += 256) {
    const float val = Obuf[(size_t)bh * 131072 + idx];
    sum += val;
    sumsq += (double)val * val;
  }
  __shared__ double sred[256], qred[256];
  sred[threadIdx.x] = sum;
  qred[threadIdx.x] = sumsq;
  __syncthreads();
  for (int stp = 128; stp > 0; stp >>= 1) {
    if (threadIdx.x < stp) {
      sred[threadIdx.x] += sred[threadIdx.x + stp];
      qred[threadIdx.x] += qred[threadIdx.x + stp];
    }
    __syncthreads();
  }
  if (threadIdx.x == 0) {
    const double n = (double)kT * 64.0;
    const double mu = sred[0] / n;
    const double var = qred[0] / n - mu * mu;
    stats[bh * 2] = (float)mu;
    stats[bh * 2 + 1] = (float)(1.0 / sqrt(var + 1e-5));
  }
}

__global__ void gate_kernel(const float* __restrict__ Obuf,
                            const __hip_bfloat16* __restrict__ og,
                            const float* __restrict__ gamma, const float* __restrict__ gbeta,
                            const float* __restrict__ stats, __hip_bfloat16* __restrict__ z) {
  const size_t idx = (size_t)blockIdx.x * 256 + threadIdx.x;
  if (idx >= (size_t)kM * 1024) return;
  const int cidx = (int)(idx & 1023);
  const int h = cidx >> 6, v = cidx & 63;
  const size_t m = idx >> 10;
  const int b = (int)(m >> 11);
  const int tok = (int)(m & 2047), c = tok >> 6, tt = tok & 63;
  const float o = Obuf[(size_t)((b * 16 + h) * 32 + c) * 4096 + tt * 64 + v];
  const float mu = stats[(b * 16 + h) * 2];
  const float rstd = stats[(b * 16 + h) * 2 + 1];
  const float val = (o - mu) * rstd * gamma[cidx] + gbeta[cidx];
  const float gt = __bfloat162float(og[idx]);
  z[idx] = __float2bfloat16(val * (1.f / (1.f + expf(-gt))));
}

// ---------------------------------------------------------------------------
extern "C" void kernel_launch(void* const* d_in, const int* in_sizes, int n_in,
                              void* d_out, int out_size, void* d_ws, size_t ws_size,
                              hipStream_t stream) {
  const float* x     = (const float*)d_in[0];
  const float* Wq    = (const float*)d_in[3];
  const float* Wk    = (const float*)d_in[4];
  const float* Wv    = (const float*)d_in[5];
  const float* Wb    = (const float*)d_in[6];
  const float* Wa    = (const float*)d_in[7];
  const float* Wg    = (const float*)d_in[8];
  const float* Wo    = (const float*)d_in[9];
  const float* Wl    = (const float*)d_in[10];
  const float* Lp    = (const float*)d_in[11];
  const float* gamma = (const float*)d_in[12];
  const float* gbeta = (const float*)d_in[13];
  float* out = (float*)d_out;
  (void)ws_size;  // peak usage < 181,469,440 proven in round 1

  char* base = (char*)d_ws;
  // P1: qpack -> zbf
  __hip_bfloat16* qpack = (__hip_bfloat16*)(base + 0);                 // 8,388,608
  __hip_bfloat16* zbf   = qpack;                                       // after products
  // P2/P3: kv packs -> Bt (in-place) -> Bc/Vo f32 (in-place)
  __hip_bfloat16* KP16 = (__hip_bfloat16*)(base + 8388608);            // 25,165,824
  __hip_bfloat16* VP16 = (__hip_bfloat16*)(base + 33554432);           // 25,165,824
  // P4 region (50,331,648): early = xb + weights; then G16; then Tc/Qe/Obuf
  char* P4 = base + 58720256;
  __hip_bfloat16* xb   = (__hip_bfloat16*)(P4 + 0);                    // 8,388,608
  __hip_bfloat16* Wqb  = (__hip_bfloat16*)(P4 + 8388608);              // 2,097,152
  __hip_bfloat16* Wkb  = (__hip_bfloat16*)(P4 + 10485760);             // 6,291,456
  __hip_bfloat16* Wvb  = (__hip_bfloat16*)(P4 + 16777216);             // 6,291,456
  __hip_bfloat16* Wgb  = (__hip_bfloat16*)(P4 + 23068672);             // 2,097,152
  __hip_bfloat16* Wlb  = (__hip_bfloat16*)(P4 + 25165824);             // 524,288
  __hip_bfloat16* Wbdb = (__hip_bfloat16*)(P4 + 25690112);             // 262,144
  __hip_bfloat16* G16  = (__hip_bfloat16*)P4;                          // full 50,331,648
  float* Tc   = (float*)(P4 + 0);                                      // 16,777,216
  float* Qe   = (float*)(P4 + 16777216);                               // 16,777,216
  float* Obuf = (float*)(P4 + 33554432);                               // 16,777,216
  // P5 region (50,331,648): early = lwb; then Astk; then S0g (Astk dead)
  char* P5 = base + 109051904;
  float* lwb = (float*)(P5 + 0);                                       // 4,194,304
  __hip_bfloat16* Astk = (__hip_bfloat16*)P5;                          // 50,331,648
  float* S0g = (float*)P5;                                             // 16,777,216
  // P6: persistent small
  char* P6 = base + 159383552;
  float* betp  = (float*)(P6 + 0);                                     // 786,432
  float* decp  = (float*)(P6 + 786432);                                // 262,144
  float* lwcb  = (float*)(P6 + 1048576);                               // 65,536
  float* statb = (float*)(P6 + 1114112);                               // 1,024
  __hip_bfloat16* Wob = (__hip_bfloat16*)(P6 + 1115136);               // 2,097,152
  __hip_bfloat16* ogb = (__hip_bfloat16*)(P6 + 3212288);               // 8,388,608

  const dim3 blk(256);

  // casts
  cast_bf16<<<dim3(4096), blk, 0, stream>>>(x,  xb,  kM * 1024);
  cast_bf16<<<dim3(1024), blk, 0, stream>>>(Wq, Wqb, 1024 * 1024);
  cast_bf16<<<dim3(3072), blk, 0, stream>>>(Wk, Wkb, 3072 * 1024);
  cast_bf16<<<dim3(3072), blk, 0, stream>>>(Wv, Wvb, 3072 * 1024);
  cast_bf16<<<dim3(1024), blk, 0, stream>>>(Wg, Wgb, 1024 * 1024);
  cast_bf16<<<dim3(256),  blk, 0, stream>>>(Wl, Wlb, 256 * 1024);
  cast_bf16<<<dim3(1024), blk, 0, stream>>>(Wo, Wob, 1024 * 1024);
  cast_bd<<<dim3(512), blk, 0, stream>>>(Wb, Wa, Wbdb);

  // projections
  gemm_bf16<6><<<dim3(8, 32),  blk, 0, stream>>>(xb, Wqb,  qpack, nullptr, 1024, nullptr);
  gemm_bf16<5><<<dim3(24, 32), blk, 0, stream>>>(xb, Wkb,  KP16,  nullptr, 3072, nullptr);
  gemm_bf16<5><<<dim3(24, 32), blk, 0, stream>>>(xb, Wvb,  VP16,  nullptr, 3072, nullptr);
  gemm_bf16<3><<<dim3(1, 32),  blk, 0, stream>>>(xb, Wbdb, betp,  decp,    128,  nullptr);
  gemm_bf16<4><<<dim3(2, 32),  blk, 0, stream>>>(xb, Wlb,  lwb,   nullptr, 256,  Lp);
  gemm_bf16<7><<<dim3(8, 32),  blk, 0, stream>>>(xb, Wgb,  ogb,   nullptr, 1024, nullptr);

  lwc_mean<<<dim3(64), blk, 0, stream>>>(lwb, lwcb);

  // chunk operators
  gram_phi<<<dim3(1024), blk, 0, stream>>>(KP16, qpack, G16, Astk);
  chunk_solve<<<dim3(1024, 2), blk, 0, stream>>>(G16, KP16, VP16, betp, decp);
  products<<<dim3(1024), blk, 0, stream>>>(Astk, KP16, VP16, qpack, decp,
                                           Tc, Qe, (float*)KP16, (float*)VP16);

  // sequential state scan (256 blocks) + parallel O gemm
  state_scan<<<dim3(256), blk, 0, stream>>>(Tc, (const float*)KP16, lwcb, S0g);
  o_gemm<<<dim3(1024), blk, 0, stream>>>(Qe, S0g, (const float*)VP16, Obuf);

  // group norm + gate
  gn_stats<<<dim3(kB * kH), blk, 0, stream>>>(Obuf, statb);
  gate_kernel<<<dim3((kM * 1024 + 255) / 256), blk, 0, stream>>>(Obuf, ogb, gamma, gbeta,
                                                                 statb, zbf);

  // final projection
  gemm_bf16<0><<<dim3(8, 32), blk, 0, stream>>>(zbf, Wob, out, nullptr, 1024, nullptr);
}

// Round 11
// 716.296 us; speedup vs baseline: 8.8620x; 1.1115x over previous
//
#include <hip/hip_runtime.h>
#include <hip/hip_bf16.h>
#include <math.h>

// Problem constants
constexpr int kB   = 2;
constexpr int kT   = 2048;
constexpr int kH   = 16;
constexpr int kC   = 64;    // chunk size
constexpr int kNc  = 32;    // T / C
constexpr int kM   = kB * kT;   // 4096
constexpr int kK   = 1024;

using bf16x8 = __attribute__((ext_vector_type(8))) short;
using f32x4  = __attribute__((ext_vector_type(4))) float;

__device__ __forceinline__ void glds16(const void* g, void* l) {
  __builtin_amdgcn_global_load_lds(
      (const __attribute__((address_space(1))) unsigned int*)g,
      (__attribute__((address_space(3))) unsigned int*)l, 16, 0, 0);
}

// ---------------------------------------------------------------------------
// bf16 MFMA NT-GEMM (verified structure). MODE:
//  0: f32 plain [rr*N+cc]
//  3: beta(48)/dec(16) sigmoid -> betp [ch][192] f32, decp [ch][64] f32
//  4: softplus(Lp*x) f32 plain (lw)
//  5: silu -> bf16 pack [ch][i=tt*3+j3][d], coalesced via LDS tile epilogue
//  6: bf16 q pack [ch][t][d]
//  7: bf16 plain [rr*1024+cc] (og)
// ---------------------------------------------------------------------------
template <int MODE>
__global__ __launch_bounds__(256) void gemm_bf16(
    const __hip_bfloat16* __restrict__ A, const __hip_bfloat16* __restrict__ W,
    void* __restrict__ outA, void* __restrict__ outB, int N,
    const float* __restrict__ Lp) {
  __shared__ __hip_bfloat16 As[128 * 32];
  __shared__ __hip_bfloat16 Bs[128 * 32];
  const int tid = threadIdx.x;
  const int w = tid >> 6, lane = tid & 63;
  const int bm = blockIdx.y * 128, bn = blockIdx.x * 128;

  const int sr = tid >> 2, sp = tid & 3;
  const int g0 = sp ^ ((sr >> 1) & 3);
  const __hip_bfloat16* a0 = A + (size_t)(bm + sr) * kK + g0 * 8;
  const __hip_bfloat16* a1 = A + (size_t)(bm + sr + 64) * kK + g0 * 8;
  const __hip_bfloat16* b0 = W + (size_t)(bn + sr) * kK + g0 * 8;
  const __hip_bfloat16* b1 = W + (size_t)(bn + sr + 64) * kK + g0 * 8;
  char* AsB = (char*)As + w * 1024;
  char* BsB = (char*)Bs + w * 1024;

  const int wr = w >> 1, wc = w & 1;
  const int fr = lane & 15, fc = lane >> 4;
  int aOff[4], bOff[4];
#pragma unroll
  for (int f = 0; f < 4; f++) {
    const int ra = wr * 64 + f * 16 + fr;
    aOff[f] = ra * 64 + ((fc ^ ((ra >> 1) & 3)) * 16);
    const int rb = wc * 64 + f * 16 + fr;
    bOff[f] = rb * 64 + ((fc ^ ((rb >> 1) & 3)) * 16);
  }

  f32x4 acc[4][4];
#pragma unroll
  for (int i = 0; i < 4; i++)
#pragma unroll
    for (int j = 0; j < 4; j++) acc[i][j] = (f32x4){0.f, 0.f, 0.f, 0.f};

  for (int k0 = 0; k0 < kK; k0 += 32) {
    __syncthreads();
    glds16(a0 + k0, AsB);
    glds16(a1 + k0, AsB + 4096);
    glds16(b0 + k0, BsB);
    glds16(b1 + k0, BsB + 4096);
    __syncthreads();

    bf16x8 af[4], bfr[4];
#pragma unroll
    for (int f = 0; f < 4; f++) af[f] = *(const bf16x8*)((const char*)As + aOff[f]);
#pragma unroll
    for (int f = 0; f < 4; f++) bfr[f] = *(const bf16x8*)((const char*)Bs + bOff[f]);
#pragma unroll
    for (int i = 0; i < 4; i++)
#pragma unroll
      for (int j = 0; j < 4; j++)
        acc[i][j] = __builtin_amdgcn_mfma_f32_16x16x32_bf16(af[i], bfr[j], acc[i][j], 0, 0, 0);
  }

  if constexpr (MODE == 5) {
    // stage silu'd tile in LDS, then write destination-major coalesced runs
    __shared__ __hip_bfloat16 Ct[128][129];
#pragma unroll
    for (int i = 0; i < 4; i++)
#pragma unroll
      for (int j = 0; j < 4; j++)
#pragma unroll
        for (int e = 0; e < 4; e++) {
          const int rl = wr * 64 + i * 16 + fc * 4 + e;
          const int cl = wc * 64 + j * 16 + fr;
          float vx = acc[i][j][e];
          vx = vx / (1.f + expf(-vx));
          Ct[rl][cl] = __float2bfloat16(vx);
        }
    __syncthreads();
    const int cc0 = bn;
    const int hh0 = cc0 / 192;
    const int dl = tid & 31, rq = tid >> 5;
    for (int cmb = 0; cmb < 6; cmb++) {
      const int hh = hh0 + cmb / 3;
      if (hh >= 16) continue;
      const int j3 = cmb % 3;
      const int off = cc0 - hh * 192 - j3;     // cc = hh*192 + 3d + j3
      const int d_lo = (off <= 0) ? 0 : (off + 2) / 3;
      const int hi_num = off + 127;
      if (hi_num < 0) continue;
      const int d_hi = (hi_num / 3) > 63 ? 63 : (hi_num / 3);
      if (d_hi < d_lo) continue;
      for (int r0 = 0; r0 < 128; r0 += 8) {
        const int rl = r0 + rq;
        const int token = bm + rl;
        const int b = token >> 11, tok = token & 2047, chn = tok >> 6, tt = tok & 63;
        __hip_bfloat16* dst = (__hip_bfloat16*)outA +
            (size_t)((b * 16 + hh) * 32 + chn) * 12288 + (tt * 3 + j3) * 64;
        for (int dd = d_lo + dl; dd <= d_hi; dd += 32)
          dst[dd] = Ct[rl][hh * 192 + 3 * dd + j3 - cc0];
      }
    }
    return;
  }

  const int r0 = bm + wr * 64, c0 = bn + wc * 64;
#pragma unroll
  for (int i = 0; i < 4; i++)
#pragma unroll
    for (int j = 0; j < 4; j++)
#pragma unroll
      for (int e = 0; e < 4; e++) {
        const int rr = r0 + i * 16 + fc * 4 + e;
        const int cc = c0 + j * 16 + fr;
        float vx = acc[i][j][e];
        if constexpr (MODE == 0) {
          ((float*)outA)[(size_t)rr * N + cc] = vx;
        } else if constexpr (MODE == 4) {
          const float y = Lp[cc] * vx;
          vx = fmaxf(y, 0.f) + log1pf(expf(-fabsf(y)));
          ((float*)outA)[(size_t)rr * N + cc] = vx;
        } else if constexpr (MODE == 3) {
          const float s = 1.f / (1.f + expf(-vx));
          const int b = rr >> 11, tok = rr & 2047, chn = tok >> 6, tt = tok & 63;
          if (cc < 48) {
            const int hh = cc / 3, j3 = cc - hh * 3;
            ((float*)outA)[(size_t)((b * 16 + hh) * 32 + chn) * 192 + tt * 3 + j3] = s;
          } else if (cc < 64) {
            const int hh = cc - 48;
            ((float*)outB)[(size_t)((b * 16 + hh) * 32 + chn) * 64 + tt] = s;
          }
        } else if constexpr (MODE == 6) {
          const int b = rr >> 11, tok = rr & 2047, chn = tok >> 6, tt = tok & 63;
          const int hh = cc >> 6, d = cc & 63;
          ((__hip_bfloat16*)outA)[(size_t)((b * 16 + hh) * 32 + chn) * 4096 +
                                  tt * 64 + d] = __float2bfloat16(vx);
        } else if constexpr (MODE == 7) {
          ((__hip_bfloat16*)outA)[(size_t)rr * 1024 + cc] = __float2bfloat16(vx);
        }
      }
}

// ---------------------------------------------------------------------------
// cast_all: fused f32->bf16 casts for x + all weights + packed Wb/Wa tile.
// ---------------------------------------------------------------------------
__global__ void cast_all(const float* __restrict__ x, const float* __restrict__ Wq,
                         const float* __restrict__ Wk, const float* __restrict__ Wv,
                         const float* __restrict__ Wg, const float* __restrict__ Wl,
                         const float* __restrict__ Wo, const float* __restrict__ Wb,
                         const float* __restrict__ Wa,
                         __hip_bfloat16* __restrict__ xb, __hip_bfloat16* __restrict__ Wqb,
                         __hip_bfloat16* __restrict__ Wkb, __hip_bfloat16* __restrict__ Wvb,
                         __hip_bfloat16* __restrict__ Wgb, __hip_bfloat16* __restrict__ Wlb,
                         __hip_bfloat16* __restrict__ Wob, __hip_bfloat16* __restrict__ Wbdb) {
  const int gb = blockIdx.x, tid = threadIdx.x;
  const float* src; __hip_bfloat16* dst; int base;
  if (gb < 4096)       { src = x;  dst = xb;  base = gb; }
  else if (gb < 5120)  { src = Wq; dst = Wqb; base = gb - 4096; }
  else if (gb < 8192)  { src = Wk; dst = Wkb; base = gb - 5120; }
  else if (gb < 11264) { src = Wv; dst = Wvb; base = gb - 8192; }
  else if (gb < 12288) { src = Wg; dst = Wgb; base = gb - 11264; }
  else if (gb < 12544) { src = Wl; dst = Wlb; base = gb - 12288; }
  else if (gb < 13568) { src = Wo; dst = Wob; base = gb - 12544; }
  else {
    const int idx = (gb - 13568) * 256 + tid;
    if (idx < 128 * 1024) {
      const int r = idx >> 10, k = idx & 1023;
      const float val = (r < 48) ? Wb[r * 1024 + k]
                                 : ((r < 64) ? Wa[(r - 48) * 1024 + k] : 0.f);
      Wbdb[idx] = __float2bfloat16(val);
    }
    return;
  }
  const int i = (base * 256 + tid) * 4;
  const float4 v = *(const float4*)(src + i);
  __hip_bfloat16 tmp[4] = {__float2bfloat16(v.x), __float2bfloat16(v.y),
                           __float2bfloat16(v.z), __float2bfloat16(v.w)};
  *(ushort4*)(dst + i) = *(ushort4*)tmp;
}

__global__ void lwc_mean(const float* __restrict__ lw, float* __restrict__ lwc) {
  const int idx = blockIdx.x * 256 + threadIdx.x;
  if (idx >= kB * kNc * kH * 16) return;
  const int l = idx & 15, h = (idx >> 4) & 15, c = (idx >> 8) & 31, b = idx >> 13;
  size_t base = ((size_t)b * kT + (size_t)c * kC) * 256 + h * 16 + l;
  float s = 0.f;
  for (int tt = 0; tt < kC; tt++) s += lw[base + (size_t)tt * 256];
  lwc[idx] = s * (1.f / 64.f);
}

// ---------------------------------------------------------------------------
// gram_phi: per-chunk-head. S = [K(192); Q(64)] (256x64 bf16). Out = S*K^T.
// ---------------------------------------------------------------------------
__global__ __launch_bounds__(256, 1) void gram_phi(
    const __hip_bfloat16* __restrict__ KP16, const __hip_bfloat16* __restrict__ qpack,
    __hip_bfloat16* __restrict__ G16, __hip_bfloat16* __restrict__ Astk) {
  const int ch = blockIdx.x;
  const int tid = threadIdx.x;
  const int w = tid >> 6, lane = tid & 63;
  __shared__ __hip_bfloat16 Sa[256 * 64];  // row-swizzled

  for (int cidx = tid; cidx < 2048; cidx += 256) {
    const int r = cidx >> 3, cko = cidx & 7;
    const __hip_bfloat16* src =
        (r < 192) ? (KP16 + (size_t)ch * 12288 + r * 64 + cko * 8)
                  : (qpack + (size_t)ch * 4096 + (r - 192) * 64 + cko * 8);
    bf16x8 vv = *(const bf16x8*)src;
    *(bf16x8*)((char*)Sa + r * 128 + ((cko ^ ((r >> 1) & 3)) * 16)) = vv;
  }
  __syncthreads();

  const int fr = lane & 15, fc = lane >> 4;
  f32x4 acc[4][12];
#pragma unroll
  for (int i = 0; i < 4; i++)
#pragma unroll
    for (int j = 0; j < 12; j++) acc[i][j] = (f32x4){0.f, 0.f, 0.f, 0.f};

#pragma unroll
  for (int ks = 0; ks < 2; ks++) {
    bf16x8 af[4];
#pragma unroll
    for (int i = 0; i < 4; i++) {
      const int ra = w * 64 + i * 16 + fr;
      af[i] = *(const bf16x8*)((char*)Sa + ra * 128 + (((ks * 4 + fc) ^ ((ra >> 1) & 3)) * 16));
    }
#pragma unroll
    for (int j = 0; j < 12; j++) {
      const int rb = j * 16 + fr;
      bf16x8 bfv = *(const bf16x8*)((char*)Sa + rb * 128 + (((ks * 4 + fc) ^ ((rb >> 1) & 3)) * 16));
#pragma unroll
      for (int i = 0; i < 4; i++)
        acc[i][j] = __builtin_amdgcn_mfma_f32_16x16x32_bf16(af[i], bfv, acc[i][j], 0, 0, 0);
    }
  }

#pragma unroll
  for (int i = 0; i < 4; i++)
#pragma unroll
    for (int j = 0; j < 12; j++)
#pragma unroll
      for (int e = 0; e < 4; e++) {
        const int gr = w * 64 + i * 16 + fc * 4 + e;
        const int gc = j * 16 + fr;
        const float val = acc[i][j][e];
        if (gr < 192) {
          const int sbb = gr >> 6, jbb = gc >> 6;
          if (jbb <= sbb)
            G16[(size_t)ch * 24576 + (size_t)(sbb * (sbb + 1) / 2 + jbb) * 4096 +
                (gr & 63) * 64 + (gc & 63)] = __float2bfloat16(val);
        } else {
          const int t = gr - 192;
          const float mval = ((gc / 3) <= t) ? val : 0.f;
          Astk[(size_t)ch * 24576 + (size_t)(64 + t) * 192 + gc] = __float2bfloat16(mval);
        }
      }

  // KT rows: Astk[ch][d][i] = K[i][d] (from swizzled LDS)
  for (int s = tid; s < 1536; s += 256) {
    const int d = s / 24, i0 = (s % 24) * 8;
    __hip_bfloat16 tmp[8];
#pragma unroll
    for (int e = 0; e < 8; e++) {
      const int i = i0 + e;
      tmp[e] = *(const __hip_bfloat16*)((char*)Sa + i * 128 +
                                        (((d >> 3) ^ ((i >> 1) & 3)) * 16) + (d & 7) * 2);
    }
    *(bf16x8*)(Astk + (size_t)ch * 24576 + (size_t)d * 192 + i0) = *(bf16x8*)tmp;
  }
}

// ---------------------------------------------------------------------------
// chunk_solve: grid (1024, 2) — EXACT round-9 version (known good). Block
// (ch, half) solves (I + Ltil) Xt = Rt for its 64-column half (half 0: K,
// half 1: V/c); Ltil[i][j] = beta_j*G[i][j]. In-place Bt write is safe: each
// block owns one whole buffer strip.
// ---------------------------------------------------------------------------
__global__ __launch_bounds__(256) void chunk_solve(
    const __hip_bfloat16* __restrict__ G16,
    __hip_bfloat16* __restrict__ KP16, __hip_bfloat16* __restrict__ VP16,
    const float* __restrict__ betp, const float* __restrict__ decp) {
  const int ch = blockIdx.x;
  const int half = blockIdx.y;
  const int tid = threadIdx.x;
  constexpr int XS = 65;   // X row stride (odd: transposed reads bank-spread)
  constexpr int TS = 68;   // tile row stride (rows 16B-aligned for float4)
  __shared__ float X[192 * XS];      // 49,920 B
  __shared__ float tile[64 * TS];    // 17,408 B
  __shared__ float bet[192], cpre[64], rc[64];

  if (tid < 192) bet[tid] = betp[(size_t)ch * 192 + tid];
  if (tid < 64) cpre[tid] = decp[(size_t)ch * 64 + tid];
  __syncthreads();
  if (tid == 0) {
    float p = 1.f;
    for (int t = 0; t < 64; t++) { p *= cpre[t]; cpre[t] = p; }
  }
  __syncthreads();
  if (tid < 64) rc[tid] = 1.f / cpre[tid];
  __syncthreads();

  // stage RHS (this half's 64 columns): half 0 -> K, half 1 -> V / c_tau(i)
  __hip_bfloat16* rhs = (half ? VP16 : KP16) + (size_t)ch * 12288;
  for (int v = tid; v < 1536; v += 256) {
    const int i = v >> 3, d0 = (v & 7) * 8;
    bf16x8 vb8 = *(const bf16x8*)(rhs + i * 64 + d0);
    const float sc = half ? rc[i / 3] : 1.f;
#pragma unroll
    for (int e = 0; e < 8; e++)
      X[i * XS + d0 + e] = __bfloat162float(*(((const __hip_bfloat16*)&vb8) + e)) * sc;
  }
  __syncthreads();

  const int col = tid & 63;
  const int rg  = tid >> 6;   // wave id 0..3

  for (int sb = 0; sb < 3; sb++) {
    const int s = sb * 64;
    // ---- off-diagonal rank-64 updates (register-cached, float4 tile reads)
    for (int jb = 0; jb < sb; jb++) {
      const __hip_bfloat16* gt = G16 + (size_t)ch * 24576 +
                                 (size_t)(sb * (sb + 1) / 2 + jb) * 4096;
      for (int idx = tid; idx < 4096; idx += 256)
        tile[(idx >> 6) * TS + (idx & 63)] =
            __bfloat162float(gt[idx]) * bet[jb * 64 + (idx & 63)];
      __syncthreads();

      float acc[16];
#pragma unroll
      for (int n = 0; n < 16; n++) acc[n] = X[(s + rg * 16 + n) * XS + col];
#pragma unroll
      for (int hf = 0; hf < 2; hf++) {
        float xreg[32];
#pragma unroll
        for (int j = 0; j < 32; j++) xreg[j] = X[(jb * 64 + hf * 32 + j) * XS + col];
#pragma unroll
        for (int n = 0; n < 16; n++) {
          const float4* trow = (const float4*)&tile[(rg * 16 + n) * TS + hf * 32];
#pragma unroll
          for (int j4 = 0; j4 < 8; j4++) {
            const float4 tv = trow[j4];
            acc[n] = fmaf(-tv.x, xreg[j4 * 4 + 0], acc[n]);
            acc[n] = fmaf(-tv.y, xreg[j4 * 4 + 1], acc[n]);
            acc[n] = fmaf(-tv.z, xreg[j4 * 4 + 2], acc[n]);
            acc[n] = fmaf(-tv.w, xreg[j4 * 4 + 3], acc[n]);
          }
        }
      }
#pragma unroll
      for (int n = 0; n < 16; n++) X[(s + rg * 16 + n) * XS + col] = acc[n];
      __syncthreads();
    }

    // ---- stage diagonal Ltil block
    {
      const __hip_bfloat16* gt = G16 + (size_t)ch * 24576 +
                                 (size_t)(sb * (sb + 1) / 2 + sb) * 4096;
      for (int idx = tid; idx < 4096; idx += 256)
        tile[(idx >> 6) * TS + (idx & 63)] =
            __bfloat162float(gt[idx]) * bet[s + (idx & 63)];
    }
    __syncthreads();

    // ---- 16-sub-blocked diagonal solve
    for (int db = 0; db < 4; db++) {
      const int l0 = db * 16;
      if (tid < 64) {  // one wave: serial 16-row solve entirely in registers
        float xd[16];
#pragma unroll
        for (int j = 0; j < 16; j++) xd[j] = X[(s + l0 + j) * XS + tid];
#pragma unroll
        for (int ii = 1; ii < 16; ii++)
          for (int jj = 0; jj < ii; jj++)
            xd[ii] = fmaf(-tile[(l0 + ii) * TS + l0 + jj], xd[jj], xd[ii]);
#pragma unroll
        for (int j = 1; j < 16; j++) X[(s + l0 + j) * XS + tid] = xd[j];
      }
      __syncthreads();
      // trailing rank-16 update on rows l0+16..63 (all 4 waves)
      const int rem = 48 - l0;
      if (rem > 0) {
        float xc[16];
#pragma unroll
        for (int j = 0; j < 16; j++) xc[j] = X[(s + l0 + j) * XS + col];
        const int rpt = rem >> 2;  // rows per wave: 12, 8, 4
        for (int n = 0; n < rpt; n++) {
          const int r = l0 + 16 + rg * rpt + n;
          float acc = X[(s + r) * XS + col];
          const float4* trow = (const float4*)&tile[r * TS + l0];
#pragma unroll
          for (int j4 = 0; j4 < 4; j4++) {
            const float4 tv = trow[j4];
            acc = fmaf(-tv.x, xc[j4 * 4 + 0], acc);
            acc = fmaf(-tv.y, xc[j4 * 4 + 1], acc);
            acc = fmaf(-tv.z, xc[j4 * 4 + 2], acc);
            acc = fmaf(-tv.w, xc[j4 * 4 + 3], acc);
          }
          X[(s + r) * XS + col] = acc;
        }
      }
      __syncthreads();
    }
  }

  // ---- write Bt over this half's strip: Bt[col][i] = beta_i * X[i][col]
  for (int v = tid; v < 1536; v += 256) {
    const int c2 = v / 24, i0 = (v % 24) * 8;
    __hip_bfloat16 tmp[8];
#pragma unroll
    for (int e = 0; e < 8; e++)
      tmp[e] = __float2bfloat16(bet[i0 + e] * X[(i0 + e) * XS + c2]);
    *(bf16x8*)(rhs + c2 * 192 + i0) = *(bf16x8*)tmp;
  }
}

// ---------------------------------------------------------------------------
// products: per ch. Out(128x128) = Astk(128x192) x Bt(128x192)^T-NT.
// ---------------------------------------------------------------------------
__global__ __launch_bounds__(256) void products(
    const __hip_bfloat16* __restrict__ Astk,
    const __hip_bfloat16* __restrict__ KP16, const __hip_bfloat16* __restrict__ VP16,
    const __hip_bfloat16* __restrict__ qpack, const float* __restrict__ decp,
    float* __restrict__ Tc, float* __restrict__ Qe,
    float* __restrict__ BcW, float* __restrict__ VoW) {
  const int ch = blockIdx.x;
  const int tid = threadIdx.x;
  const int w = tid >> 6, lane = tid & 63;
  __shared__ __hip_bfloat16 As[128 * 32];
  __shared__ __hip_bfloat16 Bs[128 * 32];
  __shared__ float cpre[64];

  if (tid < 64) cpre[tid] = decp[(size_t)ch * 64 + tid];
  __syncthreads();
  if (tid == 0) {
    float p = 1.f;
    for (int t = 0; t < 64; t++) { p *= cpre[t]; cpre[t] = p; }
  }

  const int sr = tid >> 2, sp = tid & 3;
  const int g0 = sp ^ ((sr >> 1) & 3);
  const __hip_bfloat16* a0 = Astk + (size_t)ch * 24576 + sr * 192 + g0 * 8;
  const __hip_bfloat16* a1 = a0 + 64 * 192;
  const __hip_bfloat16* b0 = KP16 + (size_t)ch * 12288 + sr * 192 + g0 * 8;
  const __hip_bfloat16* b1 = VP16 + (size_t)ch * 12288 + sr * 192 + g0 * 8;
  char* AsB = (char*)As + w * 1024;
  char* BsB = (char*)Bs + w * 1024;

  const int wr = w >> 1, wc = w & 1;
  const int fr = lane & 15, fc = lane >> 4;
  int aOff[4], bOff[4];
#pragma unroll
  for (int f = 0; f < 4; f++) {
    const int ra = wr * 64 + f * 16 + fr;
    aOff[f] = ra * 64 + ((fc ^ ((ra >> 1) & 3)) * 16);
    const int rb = wc * 64 + f * 16 + fr;
    bOff[f] = rb * 64 + ((fc ^ ((rb >> 1) & 3)) * 16);
  }

  f32x4 acc[4][4];
#pragma unroll
  for (int i = 0; i < 4; i++)
#pragma unroll
    for (int j = 0; j < 4; j++) acc[i][j] = (f32x4){0.f, 0.f, 0.f, 0.f};

  for (int k0 = 0; k0 < 192; k0 += 32) {
    __syncthreads();
    glds16(a0 + k0, AsB);
    glds16(a1 + k0, AsB + 4096);
    glds16(b0 + k0, BsB);
    glds16(b1 + k0, BsB + 4096);
    __syncthreads();

    bf16x8 af[4], bfr[4];
#pragma unroll
    for (int f = 0; f < 4; f++) af[f] = *(const bf16x8*)((const char*)As + aOff[f]);
#pragma unroll
    for (int f = 0; f < 4; f++) bfr[f] = *(const bf16x8*)((const char*)Bs + bOff[f]);
#pragma unroll
    for (int i = 0; i < 4; i++)
#pragma unroll
      for (int j = 0; j < 4; j++)
        acc[i][j] = __builtin_amdgcn_mfma_f32_16x16x32_bf16(af[i], bfr[j], acc[i][j], 0, 0, 0);
  }
  __syncthreads();

  const float cC = cpre[63];
#pragma unroll
  for (int i = 0; i < 4; i++)
#pragma unroll
    for (int j = 0; j < 4; j++)
#pragma unroll
      for (int e = 0; e < 4; e++) {
        const int rr = wr * 64 + i * 16 + fc * 4 + e;
        const int cc = wc * 64 + j * 16 + fr;
        const float val = acc[i][j][e];
        if (rr < 64) {
          if (cc < 64)
            Tc[(size_t)ch * 4096 + rr * 64 + cc] = cC * (((rr == cc) ? 1.f : 0.f) - val);
          else
            BcW[(size_t)ch * 6144 + rr * 64 + (cc - 64)] = cC * val;
        } else {
          const int t = rr - 64;
          const float ct = cpre[t];
          if (cc < 64) {
            const float qv = __bfloat162float(qpack[(size_t)ch * 4096 + t * 64 + cc]);
            Qe[(size_t)ch * 4096 + t * 64 + cc] = ct * (qv - val);
          } else {
            VoW[(size_t)ch * 6144 + t * 64 + (cc - 64)] = ct * val;
          }
        }
      }
}

// ---------------------------------------------------------------------------
// state_scan: 256 blocks = (b,h) x 8 v-slices. Sequential state pass only.
// ---------------------------------------------------------------------------
__global__ __launch_bounds__(256) void state_scan(
    const float* __restrict__ Tc, const float* __restrict__ BcS,
    const float* __restrict__ lwcb, float* __restrict__ S0g) {
  const int blk = blockIdx.x;       // bh*8 + vs
  const int bh = blk >> 3, vs = blk & 7;
  const int b = bh >> 4, h = bh & 15;
  const int vbase = vs * 8;
  const int tid = threadIdx.x;
  const int v = tid & 7;
  const int tg = tid >> 3;          // 0..31

  __shared__ float stL[6][64][8];
  __shared__ float S0s[8][68];
  __shared__ float Tt[64][68];
  __shared__ float Bt_[64][8];

  for (int idx = tid; idx < 6 * 512; idx += 256) ((float*)stL)[idx] = 0.f;

  float tReg[16], bReg[2];
  {
    const size_t ch0 = (size_t)bh * 32;
#pragma unroll
    for (int i = 0; i < 16; i++) tReg[i] = Tc[ch0 * 4096 + tid + i * 256];
#pragma unroll
    for (int i = 0; i < 2; i++) {
      const int idx = tid + i * 256;
      bReg[i] = BcS[ch0 * 6144 + (idx >> 3) * 64 + vbase + (idx & 7)];
    }
  }
  __syncthreads();

  for (int c = 0; c < 32; c++) {
    const size_t ch = (size_t)bh * 32 + c;
#pragma unroll
    for (int i = 0; i < 16; i++) {
      const int idx = tid + i * 256;
      Tt[idx >> 6][idx & 63] = tReg[i];
    }
#pragma unroll
    for (int i = 0; i < 2; i++) {
      const int idx = tid + i * 256;
      Bt_[idx >> 3][idx & 7] = bReg[i];
    }

    const float* lwp = lwcb + ((size_t)(b * kNc + c) * kH + h) * 16;
    float lw[6];
#pragma unroll
    for (int l = 0; l < 6; l++) lw[l] = lwp[l];
#pragma unroll
    for (int n = 0; n < 2; n++) {
      const int k = n * 32 + tg;
      float s = 0.f;
#pragma unroll
      for (int l = 0; l < 6; l++) s = fmaf(lw[l], stL[l][k][v], s);
      S0s[v][k] = s;
      S0g[ch * 4096 + k * 64 + vbase + v] = s;
    }
    __syncthreads();

    const size_t chn = (size_t)bh * 32 + (c < 31 ? c + 1 : 31);
#pragma unroll
    for (int i = 0; i < 16; i++) tReg[i] = Tc[chn * 4096 + tid + i * 256];
#pragma unroll
    for (int i = 0; i < 2; i++) {
      const int idx = tid + i * 256;
      bReg[i] = BcS[chn * 6144 + (idx >> 3) * 64 + vbase + (idx & 7)];
    }

    const int lev = __builtin_ctz(c + 1);
#pragma unroll
    for (int n = 0; n < 2; n++) {
      const int r = n * 32 + tg;
      float s = Bt_[r][v];
#pragma unroll
      for (int k4 = 0; k4 < 16; k4++) {
        const float4 t4 = *(const float4*)&Tt[r][k4 * 4];
        const float4 s4 = *(const float4*)&S0s[v][k4 * 4];
        s = fmaf(t4.x, s4.x, s);
        s = fmaf(t4.y, s4.y, s);
        s = fmaf(t4.z, s4.z, s);
        s = fmaf(t4.w, s4.w, s);
      }
      for (int l = 0; l < lev; l++) { s += stL[l][r][v]; stL[l][r][v] = 0.f; }
      stL[lev][r][v] = s;
    }
    __syncthreads();
  }
}

// ---------------------------------------------------------------------------
// o_gemm: 1024 parallel blocks. O = Qe * S0 + Vo.
// ---------------------------------------------------------------------------
__global__ __launch_bounds__(256) void o_gemm(
    const float* __restrict__ Qe, const float* __restrict__ S0g,
    const float* __restrict__ VoS, float* __restrict__ Obuf) {
  const int ch = blockIdx.x;
  const int tid = threadIdx.x;
  const int v = tid & 63;
  const int tg = tid >> 6;  // 0..3
  __shared__ float Qs[64][64];
  __shared__ float Ss[64][64];
  for (int idx = tid; idx < 4096; idx += 256) {
    ((float*)Qs)[idx] = Qe[(size_t)ch * 4096 + idx];
    ((float*)Ss)[idx] = S0g[(size_t)ch * 4096 + idx];
  }
  __syncthreads();
#pragma unroll
  for (int n = 0; n < 16; n++) {
    const int t = n * 4 + tg;
    float o = VoS[(size_t)ch * 6144 + t * 64 + v];
#pragma unroll 8
    for (int k = 0; k < 64; k++) o = fmaf(Qs[t][k], Ss[k][v], o);
    Obuf[(size_t)ch * 4096 + t * 64 + v] = o;
  }
}

// ---------------------------------------------------------------------------
// gn_stats1/2: two-phase deterministic group-norm statistics.
// ---------------------------------------------------------------------------
__global__ __launch_bounds__(256) void gn_stats1(const float* __restrict__ Obuf,
                                                 double* __restrict__ part) {
  const int blk = blockIdx.x;  // bh*8 + slice
  const size_t base = (size_t)blk * 16384;
  double sum = 0.0, sumsq = 0.0;
  for (int idx = threadIdx.x; idx < 16384; idx += 256) {
    const float val = Obuf[base + idx];
    sum += val;
    sumsq += (double)val * val;
  }
  __shared__ double sred[256], qred[256];
  sred[threadIdx.x] = sum;
  qred[threadIdx.x] = sumsq;
  __syncthreads();
  for (int stp = 128; stp > 0; stp >>= 1) {
    if (threadIdx.x < stp) {
      sred[threadIdx.x] += sred[threadIdx.x + stp];
      qred[threadIdx.x] += qred[threadIdx.x + stp];
    }
    __syncthreads();
  }
  if (threadIdx.x == 0) {
    part[blk * 2] = sred[0];
    part[blk * 2 + 1] = qred[0];
  }
}

__global__ void gn_stats2(const double* __restrict__ part, float* __restrict__ stats) {
  const int bh = threadIdx.x;
  if (bh >= 32) return;
  double s = 0.0, qq = 0.0;
  for (int i = 0; i < 8; i++) {
    s += part[(bh * 8 + i) * 2];
    qq += part[(bh * 8 + i) * 2 + 1];
  }
  const double n = (double)kT * 64.0;
  const double mu = s / n;
  const double var = qq / n - mu * mu;
  stats[bh * 2] = (float)mu;
  stats[bh * 2 + 1] = (float)(1.0 / sqrt(var + 1e-5));
}

__global__ void gate_kernel(const float* __restrict__ Obuf,
                            const __hip_bfloat16* __restrict__ og,
                            const float* __restrict__ gamma, const float* __restrict__ gbeta,
                            const float* __restrict__ stats, __hip_bfloat16* __restrict__ z) {
  const size_t idx = (size_t)blockIdx.x * 256 + threadIdx.x;
  if (idx >= (size_t)kM * 1024) return;
  const int cidx = (int)(idx & 1023);
  const int h = cidx >> 6, v = cidx & 63;
  const size_t m = idx >> 10;
  const int b = (int)(m >> 11);
  const int tok = (int)(m & 2047), c = tok >> 6, tt = tok & 63;
  const float o = Obuf[(size_t)((b * 16 + h) * 32 + c) * 4096 + tt * 64 + v];
  const float mu = stats[(b * 16 + h) * 2];
  const float rstd = stats[(b * 16 + h) * 2 + 1];
  const float val = (o - mu) * rstd * gamma[cidx] + gbeta[cidx];
  const float gt = __bfloat162float(og[idx]);
  z[idx] = __float2bfloat16(val * (1.f / (1.f + expf(-gt))));
}

// ---------------------------------------------------------------------------
extern "C" void kernel_launch(void* const* d_in, const int* in_sizes, int n_in,
                              void* d_out, int out_size, void* d_ws, size_t ws_size,
                              hipStream_t stream) {
  const float* x     = (const float*)d_in[0];
  const float* Wq    = (const float*)d_in[3];
  const float* Wk    = (const float*)d_in[4];
  const float* Wv    = (const float*)d_in[5];
  const float* Wb    = (const float*)d_in[6];
  const float* Wa    = (const float*)d_in[7];
  const float* Wg    = (const float*)d_in[8];
  const float* Wo    = (const float*)d_in[9];
  const float* Wl    = (const float*)d_in[10];
  const float* Lp    = (const float*)d_in[11];
  const float* gamma = (const float*)d_in[12];
  const float* gbeta = (const float*)d_in[13];
  float* out = (float*)d_out;
  (void)ws_size;  // peak usage < 181,469,440 proven in round 1

  char* base = (char*)d_ws;
  // P1: qpack -> zbf
  __hip_bfloat16* qpack = (__hip_bfloat16*)(base + 0);                 // 8,388,608
  __hip_bfloat16* zbf   = qpack;                                       // after products
  // P2/P3: kv packs -> Bt (in-place) -> Bc/Vo f32 (in-place)
  __hip_bfloat16* KP16 = (__hip_bfloat16*)(base + 8388608);            // 25,165,824
  __hip_bfloat16* VP16 = (__hip_bfloat16*)(base + 33554432);           // 25,165,824
  // P4 region (50,331,648): early = xb + weights; then G16; then Tc/Qe/Obuf
  char* P4 = base + 58720256;
  __hip_bfloat16* xb   = (__hip_bfloat16*)(P4 + 0);                    // 8,388,608
  __hip_bfloat16* Wqb  = (__hip_bfloat16*)(P4 + 8388608);              // 2,097,152
  __hip_bfloat16* Wkb  = (__hip_bfloat16*)(P4 + 10485760);             // 6,291,456
  __hip_bfloat16* Wvb  = (__hip_bfloat16*)(P4 + 16777216);             // 6,291,456
  __hip_bfloat16* Wgb  = (__hip_bfloat16*)(P4 + 23068672);             // 2,097,152
  __hip_bfloat16* Wlb  = (__hip_bfloat16*)(P4 + 25165824);             // 524,288
  __hip_bfloat16* Wbdb = (__hip_bfloat16*)(P4 + 25690112);             // 262,144
  __hip_bfloat16* G16  = (__hip_bfloat16*)P4;                          // full 50,331,648
  float* Tc   = (float*)(P4 + 0);                                      // 16,777,216
  float* Qe   = (float*)(P4 + 16777216);                               // 16,777,216
  float* Obuf = (float*)(P4 + 33554432);                               // 16,777,216
  // P5 region (50,331,648): early = lwb; then Astk; then S0g (Astk dead)
  char* P5 = base + 109051904;
  float* lwb = (float*)(P5 + 0);                                       // 4,194,304
  __hip_bfloat16* Astk = (__hip_bfloat16*)P5;                          // 50,331,648
  float* S0g = (float*)P5;                                             // 16,777,216
  // P6: persistent small
  char* P6 = base + 159383552;
  float* betp  = (float*)(P6 + 0);                                     // 786,432
  float* decp  = (float*)(P6 + 786432);                                // 262,144
  float* lwcb  = (float*)(P6 + 1048576);                               // 65,536
  float* statb = (float*)(P6 + 1114112);                               // 1,024
  __hip_bfloat16* Wob = (__hip_bfloat16*)(P6 + 1115136);               // 2,097,152
  __hip_bfloat16* ogb = (__hip_bfloat16*)(P6 + 3212288);               // 8,388,608
  double* gnpart = (double*)(base + 170984448);                        // 4,096

  const dim3 blk(256);

  // fused casts (x + all weights + bd pack)
  cast_all<<<dim3(14080), blk, 0, stream>>>(x, Wq, Wk, Wv, Wg, Wl, Wo, Wb, Wa,
                                            xb, Wqb, Wkb, Wvb, Wgb, Wlb, Wob, Wbdb);

  // projections
  gemm_bf16<6><<<dim3(8, 32),  blk, 0, stream>>>(xb, Wqb,  qpack, nullptr, 1024, nullptr);
  gemm_bf16<5><<<dim3(24, 32), blk, 0, stream>>>(xb, Wkb,  KP16,  nullptr, 3072, nullptr);
  gemm_bf16<5><<<dim3(24, 32), blk, 0, stream>>>(xb, Wvb,  VP16,  nullptr, 3072, nullptr);
  gemm_bf16<3><<<dim3(1, 32),  blk, 0, stream>>>(xb, Wbdb, betp,  decp,    128,  nullptr);
  gemm_bf16<4><<<dim3(2, 32),  blk, 0, stream>>>(xb, Wlb,  lwb,   nullptr, 256,  Lp);
  gemm_bf16<7><<<dim3(8, 32),  blk, 0, stream>>>(xb, Wgb,  ogb,   nullptr, 1024, nullptr);

  lwc_mean<<<dim3(64), blk, 0, stream>>>(lwb, lwcb);

  // chunk operators
  gram_phi<<<dim3(1024), blk, 0, stream>>>(KP16, qpack, G16, Astk);
  chunk_solve<<<dim3(1024, 2), blk, 0, stream>>>(G16, KP16, VP16, betp, decp);
  products<<<dim3(1024), blk, 0, stream>>>(Astk, KP16, VP16, qpack, decp,
                                           Tc, Qe, (float*)KP16, (float*)VP16);

  // sequential state scan (256 blocks) + parallel O gemm
  state_scan<<<dim3(256), blk, 0, stream>>>(Tc, (const float*)KP16, lwcb, S0g);
  o_gemm<<<dim3(1024), blk, 0, stream>>>(Qe, S0g, (const float*)VP16, Obuf);

  // group norm + gate
  gn_stats1<<<dim3(256), blk, 0, stream>>>(Obuf, gnpart);
  gn_stats2<<<dim3(1), dim3(64), 0, stream>>>(gnpart, statb);
  gate_kernel<<<dim3((kM * 1024 + 255) / 256), blk, 0, stream>>>(Obuf, ogb, gamma, gbeta,
                                                                 statb, zbf);

  // final projection
  gemm_bf16<0><<<dim3(8, 32), blk, 0, stream>>>(zbf, Wob, out, nullptr, 1024, nullptr);
}

// Round 12
// 678.787 us; speedup vs baseline: 9.3517x; 1.0553x over previous
//
#include <hip/hip_runtime.h>
#include <hip/hip_bf16.h>
#include <math.h>

// Problem constants
constexpr int kB   = 2;
constexpr int kT   = 2048;
constexpr int kH   = 16;
constexpr int kC   = 64;    // chunk size
constexpr int kNc  = 32;    // T / C
constexpr int kM   = kB * kT;   // 4096
constexpr int kK   = 1024;

using bf16x8 = __attribute__((ext_vector_type(8))) short;
using f32x4  = __attribute__((ext_vector_type(4))) float;

__device__ __forceinline__ void glds16(const void* g, void* l) {
  __builtin_amdgcn_global_load_lds(
      (const __attribute__((address_space(1))) unsigned int*)g,
      (__attribute__((address_space(3))) unsigned int*)l, 16, 0, 0);
}

// ---------------------------------------------------------------------------
// bf16 MFMA NT-GEMM (verified structure). MODE:
//  0: f32 plain [rr*N+cc]
//  3: beta(48)/dec(16) sigmoid -> betp [ch][192] f32, decp [ch][64] f32
//  4: softplus(Lp*x) f32 plain (lw)
//  5: silu -> bf16 pack [ch][i=tt*3+j3][d], coalesced via LDS tile epilogue
//  6: bf16 q pack [ch][t][d]
//  7: bf16 plain [rr*1024+cc] (og)
// ---------------------------------------------------------------------------
template <int MODE>
__global__ __launch_bounds__(256) void gemm_bf16(
    const __hip_bfloat16* __restrict__ A, const __hip_bfloat16* __restrict__ W,
    void* __restrict__ outA, void* __restrict__ outB, int N,
    const float* __restrict__ Lp) {
  __shared__ __hip_bfloat16 As[128 * 32];
  __shared__ __hip_bfloat16 Bs[128 * 32];
  const int tid = threadIdx.x;
  const int w = tid >> 6, lane = tid & 63;
  const int bm = blockIdx.y * 128, bn = blockIdx.x * 128;

  const int sr = tid >> 2, sp = tid & 3;
  const int g0 = sp ^ ((sr >> 1) & 3);
  const __hip_bfloat16* a0 = A + (size_t)(bm + sr) * kK + g0 * 8;
  const __hip_bfloat16* a1 = A + (size_t)(bm + sr + 64) * kK + g0 * 8;
  const __hip_bfloat16* b0 = W + (size_t)(bn + sr) * kK + g0 * 8;
  const __hip_bfloat16* b1 = W + (size_t)(bn + sr + 64) * kK + g0 * 8;
  char* AsB = (char*)As + w * 1024;
  char* BsB = (char*)Bs + w * 1024;

  const int wr = w >> 1, wc = w & 1;
  const int fr = lane & 15, fc = lane >> 4;
  int aOff[4], bOff[4];
#pragma unroll
  for (int f = 0; f < 4; f++) {
    const int ra = wr * 64 + f * 16 + fr;
    aOff[f] = ra * 64 + ((fc ^ ((ra >> 1) & 3)) * 16);
    const int rb = wc * 64 + f * 16 + fr;
    bOff[f] = rb * 64 + ((fc ^ ((rb >> 1) & 3)) * 16);
  }

  f32x4 acc[4][4];
#pragma unroll
  for (int i = 0; i < 4; i++)
#pragma unroll
    for (int j = 0; j < 4; j++) acc[i][j] = (f32x4){0.f, 0.f, 0.f, 0.f};

  for (int k0 = 0; k0 < kK; k0 += 32) {
    __syncthreads();
    glds16(a0 + k0, AsB);
    glds16(a1 + k0, AsB + 4096);
    glds16(b0 + k0, BsB);
    glds16(b1 + k0, BsB + 4096);
    __syncthreads();

    bf16x8 af[4], bfr[4];
#pragma unroll
    for (int f = 0; f < 4; f++) af[f] = *(const bf16x8*)((const char*)As + aOff[f]);
#pragma unroll
    for (int f = 0; f < 4; f++) bfr[f] = *(const bf16x8*)((const char*)Bs + bOff[f]);
#pragma unroll
    for (int i = 0; i < 4; i++)
#pragma unroll
      for (int j = 0; j < 4; j++)
        acc[i][j] = __builtin_amdgcn_mfma_f32_16x16x32_bf16(af[i], bfr[j], acc[i][j], 0, 0, 0);
  }

  if constexpr (MODE == 5) {
    // stage silu'd tile in LDS, then write destination-major coalesced runs
    __shared__ __hip_bfloat16 Ct[128][129];
#pragma unroll
    for (int i = 0; i < 4; i++)
#pragma unroll
      for (int j = 0; j < 4; j++)
#pragma unroll
        for (int e = 0; e < 4; e++) {
          const int rl = wr * 64 + i * 16 + fc * 4 + e;
          const int cl = wc * 64 + j * 16 + fr;
          float vx = acc[i][j][e];
          vx = vx / (1.f + expf(-vx));
          Ct[rl][cl] = __float2bfloat16(vx);
        }
    __syncthreads();
    const int cc0 = bn;
    const int hh0 = cc0 / 192;
    const int dl = tid & 31, rq = tid >> 5;
    for (int cmb = 0; cmb < 6; cmb++) {
      const int hh = hh0 + cmb / 3;
      if (hh >= 16) continue;
      const int j3 = cmb % 3;
      const int off = cc0 - hh * 192 - j3;     // cc = hh*192 + 3d + j3
      const int d_lo = (off <= 0) ? 0 : (off + 2) / 3;
      const int hi_num = off + 127;
      if (hi_num < 0) continue;
      const int d_hi = (hi_num / 3) > 63 ? 63 : (hi_num / 3);
      if (d_hi < d_lo) continue;
      for (int r0 = 0; r0 < 128; r0 += 8) {
        const int rl = r0 + rq;
        const int token = bm + rl;
        const int b = token >> 11, tok = token & 2047, chn = tok >> 6, tt = tok & 63;
        __hip_bfloat16* dst = (__hip_bfloat16*)outA +
            (size_t)((b * 16 + hh) * 32 + chn) * 12288 + (tt * 3 + j3) * 64;
        for (int dd = d_lo + dl; dd <= d_hi; dd += 32)
          dst[dd] = Ct[rl][hh * 192 + 3 * dd + j3 - cc0];
      }
    }
    return;
  }

  const int r0 = bm + wr * 64, c0 = bn + wc * 64;
#pragma unroll
  for (int i = 0; i < 4; i++)
#pragma unroll
    for (int j = 0; j < 4; j++)
#pragma unroll
      for (int e = 0; e < 4; e++) {
        const int rr = r0 + i * 16 + fc * 4 + e;
        const int cc = c0 + j * 16 + fr;
        float vx = acc[i][j][e];
        if constexpr (MODE == 0) {
          ((float*)outA)[(size_t)rr * N + cc] = vx;
        } else if constexpr (MODE == 4) {
          const float y = Lp[cc] * vx;
          vx = fmaxf(y, 0.f) + log1pf(expf(-fabsf(y)));
          ((float*)outA)[(size_t)rr * N + cc] = vx;
        } else if constexpr (MODE == 3) {
          const float s = 1.f / (1.f + expf(-vx));
          const int b = rr >> 11, tok = rr & 2047, chn = tok >> 6, tt = tok & 63;
          if (cc < 48) {
            const int hh = cc / 3, j3 = cc - hh * 3;
            ((float*)outA)[(size_t)((b * 16 + hh) * 32 + chn) * 192 + tt * 3 + j3] = s;
          } else if (cc < 64) {
            const int hh = cc - 48;
            ((float*)outB)[(size_t)((b * 16 + hh) * 32 + chn) * 64 + tt] = s;
          }
        } else if constexpr (MODE == 6) {
          const int b = rr >> 11, tok = rr & 2047, chn = tok >> 6, tt = tok & 63;
          const int hh = cc >> 6, d = cc & 63;
          ((__hip_bfloat16*)outA)[(size_t)((b * 16 + hh) * 32 + chn) * 4096 +
                                  tt * 64 + d] = __float2bfloat16(vx);
        } else if constexpr (MODE == 7) {
          ((__hip_bfloat16*)outA)[(size_t)rr * 1024 + cc] = __float2bfloat16(vx);
        }
      }
}

// ---------------------------------------------------------------------------
// cast_all: fused f32->bf16 casts for x + all weights + packed Wb/Wa tile.
// ---------------------------------------------------------------------------
__global__ void cast_all(const float* __restrict__ x, const float* __restrict__ Wq,
                         const float* __restrict__ Wk, const float* __restrict__ Wv,
                         const float* __restrict__ Wg, const float* __restrict__ Wl,
                         const float* __restrict__ Wo, const float* __restrict__ Wb,
                         const float* __restrict__ Wa,
                         __hip_bfloat16* __restrict__ xb, __hip_bfloat16* __restrict__ Wqb,
                         __hip_bfloat16* __restrict__ Wkb, __hip_bfloat16* __restrict__ Wvb,
                         __hip_bfloat16* __restrict__ Wgb, __hip_bfloat16* __restrict__ Wlb,
                         __hip_bfloat16* __restrict__ Wob, __hip_bfloat16* __restrict__ Wbdb) {
  const int gb = blockIdx.x, tid = threadIdx.x;
  const float* src; __hip_bfloat16* dst; int base;
  if (gb < 4096)       { src = x;  dst = xb;  base = gb; }
  else if (gb < 5120)  { src = Wq; dst = Wqb; base = gb - 4096; }
  else if (gb < 8192)  { src = Wk; dst = Wkb; base = gb - 5120; }
  else if (gb < 11264) { src = Wv; dst = Wvb; base = gb - 8192; }
  else if (gb < 12288) { src = Wg; dst = Wgb; base = gb - 11264; }
  else if (gb < 12544) { src = Wl; dst = Wlb; base = gb - 12288; }
  else if (gb < 13568) { src = Wo; dst = Wob; base = gb - 12544; }
  else {
    const int idx = (gb - 13568) * 256 + tid;
    if (idx < 128 * 1024) {
      const int r = idx >> 10, k = idx & 1023;
      const float val = (r < 48) ? Wb[r * 1024 + k]
                                 : ((r < 64) ? Wa[(r - 48) * 1024 + k] : 0.f);
      Wbdb[idx] = __float2bfloat16(val);
    }
    return;
  }
  const int i = (base * 256 + tid) * 4;
  const float4 v = *(const float4*)(src + i);
  __hip_bfloat16 tmp[4] = {__float2bfloat16(v.x), __float2bfloat16(v.y),
                           __float2bfloat16(v.z), __float2bfloat16(v.w)};
  *(ushort4*)(dst + i) = *(ushort4*)tmp;
}

__global__ void lwc_mean(const float* __restrict__ lw, float* __restrict__ lwc) {
  const int idx = blockIdx.x * 256 + threadIdx.x;
  if (idx >= kB * kNc * kH * 16) return;
  const int l = idx & 15, h = (idx >> 4) & 15, c = (idx >> 8) & 31, b = idx >> 13;
  size_t base = ((size_t)b * kT + (size_t)c * kC) * 256 + h * 16 + l;
  float s = 0.f;
  for (int tt = 0; tt < kC; tt++) s += lw[base + (size_t)tt * 256];
  lwc[idx] = s * (1.f / 64.f);
}

// ---------------------------------------------------------------------------
// gram_phi: per-chunk-head. S = [K(192); Q(64)] (256x64 bf16). Out = S*K^T.
// ---------------------------------------------------------------------------
__global__ __launch_bounds__(256, 1) void gram_phi(
    const __hip_bfloat16* __restrict__ KP16, const __hip_bfloat16* __restrict__ qpack,
    __hip_bfloat16* __restrict__ G16, __hip_bfloat16* __restrict__ Astk) {
  const int ch = blockIdx.x;
  const int tid = threadIdx.x;
  const int w = tid >> 6, lane = tid & 63;
  __shared__ __hip_bfloat16 Sa[256 * 64];  // row-swizzled

  for (int cidx = tid; cidx < 2048; cidx += 256) {
    const int r = cidx >> 3, cko = cidx & 7;
    const __hip_bfloat16* src =
        (r < 192) ? (KP16 + (size_t)ch * 12288 + r * 64 + cko * 8)
                  : (qpack + (size_t)ch * 4096 + (r - 192) * 64 + cko * 8);
    bf16x8 vv = *(const bf16x8*)src;
    *(bf16x8*)((char*)Sa + r * 128 + ((cko ^ ((r >> 1) & 3)) * 16)) = vv;
  }
  __syncthreads();

  const int fr = lane & 15, fc = lane >> 4;
  f32x4 acc[4][12];
#pragma unroll
  for (int i = 0; i < 4; i++)
#pragma unroll
    for (int j = 0; j < 12; j++) acc[i][j] = (f32x4){0.f, 0.f, 0.f, 0.f};

#pragma unroll
  for (int ks = 0; ks < 2; ks++) {
    bf16x8 af[4];
#pragma unroll
    for (int i = 0; i < 4; i++) {
      const int ra = w * 64 + i * 16 + fr;
      af[i] = *(const bf16x8*)((char*)Sa + ra * 128 + (((ks * 4 + fc) ^ ((ra >> 1) & 3)) * 16));
    }
#pragma unroll
    for (int j = 0; j < 12; j++) {
      const int rb = j * 16 + fr;
      bf16x8 bfv = *(const bf16x8*)((char*)Sa + rb * 128 + (((ks * 4 + fc) ^ ((rb >> 1) & 3)) * 16));
#pragma unroll
      for (int i = 0; i < 4; i++)
        acc[i][j] = __builtin_amdgcn_mfma_f32_16x16x32_bf16(af[i], bfv, acc[i][j], 0, 0, 0);
    }
  }

#pragma unroll
  for (int i = 0; i < 4; i++)
#pragma unroll
    for (int j = 0; j < 12; j++)
#pragma unroll
      for (int e = 0; e < 4; e++) {
        const int gr = w * 64 + i * 16 + fc * 4 + e;
        const int gc = j * 16 + fr;
        const float val = acc[i][j][e];
        if (gr < 192) {
          const int sbb = gr >> 6, jbb = gc >> 6;
          if (jbb <= sbb)
            G16[(size_t)ch * 24576 + (size_t)(sbb * (sbb + 1) / 2 + jbb) * 4096 +
                (gr & 63) * 64 + (gc & 63)] = __float2bfloat16(val);
        } else {
          const int t = gr - 192;
          const float mval = ((gc / 3) <= t) ? val : 0.f;
          Astk[(size_t)ch * 24576 + (size_t)(64 + t) * 192 + gc] = __float2bfloat16(mval);
        }
      }

  // KT rows: Astk[ch][d][i] = K[i][d] (from swizzled LDS)
  for (int s = tid; s < 1536; s += 256) {
    const int d = s / 24, i0 = (s % 24) * 8;
    __hip_bfloat16 tmp[8];
#pragma unroll
    for (int e = 0; e < 8; e++) {
      const int i = i0 + e;
      tmp[e] = *(const __hip_bfloat16*)((char*)Sa + i * 128 +
                                        (((d >> 3) ^ ((i >> 1) & 3)) * 16) + (d & 7) * 2);
    }
    *(bf16x8*)(Astk + (size_t)ch * 24576 + (size_t)d * 192 + i0) = *(bf16x8*)tmp;
  }
}

// ---------------------------------------------------------------------------
// chunk_solve: grid (1024, 2). Block (ch, half) solves (I + Ltil) Xt = Rt for
// its 64-column half (half 0: K, half 1: V/c); Ltil[i][j] = beta_j*G[i][j].
// 4x4 register-blocked updates (thread (ty,tx) owns 4 rows x 4 cols) with
// float4 LDS reads; per-output fma order k-ascending == round-11 version ->
// bit-identical output. XS=68 keeps rows 16B-aligned and bank-decorrelated.
// In-place Bt write is safe: each block owns one whole buffer strip.
// ---------------------------------------------------------------------------
__global__ __launch_bounds__(256) void chunk_solve(
    const __hip_bfloat16* __restrict__ G16,
    __hip_bfloat16* __restrict__ KP16, __hip_bfloat16* __restrict__ VP16,
    const float* __restrict__ betp, const float* __restrict__ decp) {
  const int ch = blockIdx.x;
  const int half = blockIdx.y;
  const int tid = threadIdx.x;
  constexpr int XS = 68;   // X row stride (rows 16B-aligned; bank = 4r+c)
  constexpr int TS = 68;   // tile row stride
  __shared__ float X[192 * XS];      // 52,224 B
  __shared__ float tile[64 * TS];    // 17,408 B
  __shared__ float bet[192], cpre[64], rc[64];

  if (tid < 192) bet[tid] = betp[(size_t)ch * 192 + tid];
  if (tid < 64) cpre[tid] = decp[(size_t)ch * 64 + tid];
  __syncthreads();
  if (tid == 0) {
    float p = 1.f;
    for (int t = 0; t < 64; t++) { p *= cpre[t]; cpre[t] = p; }
  }
  __syncthreads();
  if (tid < 64) rc[tid] = 1.f / cpre[tid];
  __syncthreads();

  // stage RHS (this half's 64 columns): half 0 -> K, half 1 -> V / c_tau(i)
  __hip_bfloat16* rhs = (half ? VP16 : KP16) + (size_t)ch * 12288;
  for (int v = tid; v < 1536; v += 256) {
    const int i = v >> 3, d0 = (v & 7) * 8;
    bf16x8 vb8 = *(const bf16x8*)(rhs + i * 64 + d0);
    const float sc = half ? rc[i / 3] : 1.f;
#pragma unroll
    for (int e = 0; e < 8; e++)
      X[i * XS + d0 + e] = __bfloat162float(*(((const __hip_bfloat16*)&vb8) + e)) * sc;
  }
  __syncthreads();

  const int ty = tid >> 4, tx = tid & 15;   // 16 x 16 thread grid
  const int col4 = tx * 4;

  for (int sb = 0; sb < 3; sb++) {
    const int s = sb * 64;
    // ---- off-diagonal rank-64 updates (4x4 register blocked)
    for (int jb = 0; jb < sb; jb++) {
      const __hip_bfloat16* gt = G16 + (size_t)ch * 24576 +
                                 (size_t)(sb * (sb + 1) / 2 + jb) * 4096;
      for (int idx = tid; idx < 4096; idx += 256)
        tile[(idx >> 6) * TS + (idx & 63)] =
            __bfloat162float(gt[idx]) * bet[jb * 64 + (idx & 63)];
      __syncthreads();

      const int j0 = jb * 64;
      const int r0 = s + ty * 4;
      float4 acc[4];
#pragma unroll
      for (int r = 0; r < 4; r++) acc[r] = *(const float4*)&X[(r0 + r) * XS + col4];
#pragma unroll
      for (int k4 = 0; k4 < 16; k4++) {
        float4 xv[4];
#pragma unroll
        for (int e = 0; e < 4; e++)
          xv[e] = *(const float4*)&X[(j0 + k4 * 4 + e) * XS + col4];
#pragma unroll
        for (int r = 0; r < 4; r++) {
          const float4 t = *(const float4*)&tile[(ty * 4 + r) * TS + k4 * 4];
          acc[r].x = fmaf(-t.x, xv[0].x, acc[r].x);
          acc[r].y = fmaf(-t.x, xv[0].y, acc[r].y);
          acc[r].z = fmaf(-t.x, xv[0].z, acc[r].z);
          acc[r].w = fmaf(-t.x, xv[0].w, acc[r].w);
          acc[r].x = fmaf(-t.y, xv[1].x, acc[r].x);
          acc[r].y = fmaf(-t.y, xv[1].y, acc[r].y);
          acc[r].z = fmaf(-t.y, xv[1].z, acc[r].z);
          acc[r].w = fmaf(-t.y, xv[1].w, acc[r].w);
          acc[r].x = fmaf(-t.z, xv[2].x, acc[r].x);
          acc[r].y = fmaf(-t.z, xv[2].y, acc[r].y);
          acc[r].z = fmaf(-t.z, xv[2].z, acc[r].z);
          acc[r].w = fmaf(-t.z, xv[2].w, acc[r].w);
          acc[r].x = fmaf(-t.w, xv[3].x, acc[r].x);
          acc[r].y = fmaf(-t.w, xv[3].y, acc[r].y);
          acc[r].z = fmaf(-t.w, xv[3].z, acc[r].z);
          acc[r].w = fmaf(-t.w, xv[3].w, acc[r].w);
        }
      }
#pragma unroll
      for (int r = 0; r < 4; r++) *(float4*)&X[(r0 + r) * XS + col4] = acc[r];
      __syncthreads();
    }

    // ---- stage diagonal Ltil block
    {
      const __hip_bfloat16* gt = G16 + (size_t)ch * 24576 +
                                 (size_t)(sb * (sb + 1) / 2 + sb) * 4096;
      for (int idx = tid; idx < 4096; idx += 256)
        tile[(idx >> 6) * TS + (idx & 63)] =
            __bfloat162float(gt[idx]) * bet[s + (idx & 63)];
    }
    __syncthreads();

    // ---- 16-sub-blocked diagonal solve
    for (int db = 0; db < 4; db++) {
      const int l0 = db * 16;
      if (tid < 64) {  // one wave: serial 16-row solve entirely in registers
        float xd[16];
#pragma unroll
        for (int j = 0; j < 16; j++) xd[j] = X[(s + l0 + j) * XS + tid];
#pragma unroll
        for (int ii = 1; ii < 16; ii++)
          for (int jj = 0; jj < ii; jj++)
            xd[ii] = fmaf(-tile[(l0 + ii) * TS + l0 + jj], xd[jj], xd[ii]);
#pragma unroll
        for (int j = 1; j < 16; j++) X[(s + l0 + j) * XS + tid] = xd[j];
      }
      __syncthreads();
      // trailing rank-16 update on rows l0+16..63 (4x4 register blocked)
      const int rem = 48 - l0;
      if (rem > 0) {
        const int ng = rem >> 2;   // row-groups of 4: 12, 8, 4
        if (ty < ng) {
          const int r0 = s + l0 + 16 + ty * 4;
          float4 acc[4];
#pragma unroll
          for (int r = 0; r < 4; r++) acc[r] = *(const float4*)&X[(r0 + r) * XS + col4];
#pragma unroll
          for (int k4 = 0; k4 < 4; k4++) {
            float4 xv[4];
#pragma unroll
            for (int e = 0; e < 4; e++)
              xv[e] = *(const float4*)&X[(s + l0 + k4 * 4 + e) * XS + col4];
#pragma unroll
            for (int r = 0; r < 4; r++) {
              const float4 t = *(const float4*)&tile[(l0 + 16 + ty * 4 + r) * TS + l0 + k4 * 4];
              acc[r].x = fmaf(-t.x, xv[0].x, acc[r].x);
              acc[r].y = fmaf(-t.x, xv[0].y, acc[r].y);
              acc[r].z = fmaf(-t.x, xv[0].z, acc[r].z);
              acc[r].w = fmaf(-t.x, xv[0].w, acc[r].w);
              acc[r].x = fmaf(-t.y, xv[1].x, acc[r].x);
              acc[r].y = fmaf(-t.y, xv[1].y, acc[r].y);
              acc[r].z = fmaf(-t.y, xv[1].z, acc[r].z);
              acc[r].w = fmaf(-t.y, xv[1].w, acc[r].w);
              acc[r].x = fmaf(-t.z, xv[2].x, acc[r].x);
              acc[r].y = fmaf(-t.z, xv[2].y, acc[r].y);
              acc[r].z = fmaf(-t.z, xv[2].z, acc[r].z);
              acc[r].w = fmaf(-t.z, xv[2].w, acc[r].w);
              acc[r].x = fmaf(-t.w, xv[3].x, acc[r].x);
              acc[r].y = fmaf(-t.w, xv[3].y, acc[r].y);
              acc[r].z = fmaf(-t.w, xv[3].z, acc[r].z);
              acc[r].w = fmaf(-t.w, xv[3].w, acc[r].w);
            }
          }
#pragma unroll
          for (int r = 0; r < 4; r++) *(float4*)&X[(r0 + r) * XS + col4] = acc[r];
        }
      }
      __syncthreads();
    }
  }

  // ---- write Bt over this half's strip: Bt[col][i] = beta_i * X[i][col]
  // col = v&63 keeps the X reads 2-way bank-spread.
  for (int v = tid; v < 1536; v += 256) {
    const int c2 = v & 63, i0 = (v >> 6) * 8;
    __hip_bfloat16 tmp[8];
#pragma unroll
    for (int e = 0; e < 8; e++)
      tmp[e] = __float2bfloat16(bet[i0 + e] * X[(i0 + e) * XS + c2]);
    *(bf16x8*)(rhs + c2 * 192 + i0) = *(bf16x8*)tmp;
  }
}

// ---------------------------------------------------------------------------
// products: per ch. Out(128x128) = Astk(128x192) x Bt(128x192)^T-NT.
// ---------------------------------------------------------------------------
__global__ __launch_bounds__(256) void products(
    const __hip_bfloat16* __restrict__ Astk,
    const __hip_bfloat16* __restrict__ KP16, const __hip_bfloat16* __restrict__ VP16,
    const __hip_bfloat16* __restrict__ qpack, const float* __restrict__ decp,
    float* __restrict__ Tc, float* __restrict__ Qe,
    float* __restrict__ BcW, float* __restrict__ VoW) {
  const int ch = blockIdx.x;
  const int tid = threadIdx.x;
  const int w = tid >> 6, lane = tid & 63;
  __shared__ __hip_bfloat16 As[128 * 32];
  __shared__ __hip_bfloat16 Bs[128 * 32];
  __shared__ float cpre[64];

  if (tid < 64) cpre[tid] = decp[(size_t)ch * 64 + tid];
  __syncthreads();
  if (tid == 0) {
    float p = 1.f;
    for (int t = 0; t < 64; t++) { p *= cpre[t]; cpre[t] = p; }
  }

  const int sr = tid >> 2, sp = tid & 3;
  const int g0 = sp ^ ((sr >> 1) & 3);
  const __hip_bfloat16* a0 = Astk + (size_t)ch * 24576 + sr * 192 + g0 * 8;
  const __hip_bfloat16* a1 = a0 + 64 * 192;
  const __hip_bfloat16* b0 = KP16 + (size_t)ch * 12288 + sr * 192 + g0 * 8;
  const __hip_bfloat16* b1 = VP16 + (size_t)ch * 12288 + sr * 192 + g0 * 8;
  char* AsB = (char*)As + w * 1024;
  char* BsB = (char*)Bs + w * 1024;

  const int wr = w >> 1, wc = w & 1;
  const int fr = lane & 15, fc = lane >> 4;
  int aOff[4], bOff[4];
#pragma unroll
  for (int f = 0; f < 4; f++) {
    const int ra = wr * 64 + f * 16 + fr;
    aOff[f] = ra * 64 + ((fc ^ ((ra >> 1) & 3)) * 16);
    const int rb = wc * 64 + f * 16 + fr;
    bOff[f] = rb * 64 + ((fc ^ ((rb >> 1) & 3)) * 16);
  }

  f32x4 acc[4][4];
#pragma unroll
  for (int i = 0; i < 4; i++)
#pragma unroll
    for (int j = 0; j < 4; j++) acc[i][j] = (f32x4){0.f, 0.f, 0.f, 0.f};

  for (int k0 = 0; k0 < 192; k0 += 32) {
    __syncthreads();
    glds16(a0 + k0, AsB);
    glds16(a1 + k0, AsB + 4096);
    glds16(b0 + k0, BsB);
    glds16(b1 + k0, BsB + 4096);
    __syncthreads();

    bf16x8 af[4], bfr[4];
#pragma unroll
    for (int f = 0; f < 4; f++) af[f] = *(const bf16x8*)((const char*)As + aOff[f]);
#pragma unroll
    for (int f = 0; f < 4; f++) bfr[f] = *(const bf16x8*)((const char*)Bs + bOff[f]);
#pragma unroll
    for (int i = 0; i < 4; i++)
#pragma unroll
      for (int j = 0; j < 4; j++)
        acc[i][j] = __builtin_amdgcn_mfma_f32_16x16x32_bf16(af[i], bfr[j], acc[i][j], 0, 0, 0);
  }
  __syncthreads();

  const float cC = cpre[63];
#pragma unroll
  for (int i = 0; i < 4; i++)
#pragma unroll
    for (int j = 0; j < 4; j++)
#pragma unroll
      for (int e = 0; e < 4; e++) {
        const int rr = wr * 64 + i * 16 + fc * 4 + e;
        const int cc = wc * 64 + j * 16 + fr;
        const float val = acc[i][j][e];
        if (rr < 64) {
          if (cc < 64)
            Tc[(size_t)ch * 4096 + rr * 64 + cc] = cC * (((rr == cc) ? 1.f : 0.f) - val);
          else
            BcW[(size_t)ch * 6144 + rr * 64 + (cc - 64)] = cC * val;
        } else {
          const int t = rr - 64;
          const float ct = cpre[t];
          if (cc < 64) {
            const float qv = __bfloat162float(qpack[(size_t)ch * 4096 + t * 64 + cc]);
            Qe[(size_t)ch * 4096 + t * 64 + cc] = ct * (qv - val);
          } else {
            VoW[(size_t)ch * 6144 + t * 64 + (cc - 64)] = ct * val;
          }
        }
      }
}

// ---------------------------------------------------------------------------
// state_scan: 256 blocks = (b,h) x 8 v-slices. Sequential state pass only.
// ---------------------------------------------------------------------------
__global__ __launch_bounds__(256) void state_scan(
    const float* __restrict__ Tc, const float* __restrict__ BcS,
    const float* __restrict__ lwcb, float* __restrict__ S0g) {
  const int blk = blockIdx.x;       // bh*8 + vs
  const int bh = blk >> 3, vs = blk & 7;
  const int b = bh >> 4, h = bh & 15;
  const int vbase = vs * 8;
  const int tid = threadIdx.x;
  const int v = tid & 7;
  const int tg = tid >> 3;          // 0..31

  __shared__ float stL[6][64][8];
  __shared__ float S0s[8][68];
  __shared__ float Tt[64][68];
  __shared__ float Bt_[64][8];

  for (int idx = tid; idx < 6 * 512; idx += 256) ((float*)stL)[idx] = 0.f;

  float tReg[16], bReg[2];
  {
    const size_t ch0 = (size_t)bh * 32;
#pragma unroll
    for (int i = 0; i < 16; i++) tReg[i] = Tc[ch0 * 4096 + tid + i * 256];
#pragma unroll
    for (int i = 0; i < 2; i++) {
      const int idx = tid + i * 256;
      bReg[i] = BcS[ch0 * 6144 + (idx >> 3) * 64 + vbase + (idx & 7)];
    }
  }
  __syncthreads();

  for (int c = 0; c < 32; c++) {
    const size_t ch = (size_t)bh * 32 + c;
#pragma unroll
    for (int i = 0; i < 16; i++) {
      const int idx = tid + i * 256;
      Tt[idx >> 6][idx & 63] = tReg[i];
    }
#pragma unroll
    for (int i = 0; i < 2; i++) {
      const int idx = tid + i * 256;
      Bt_[idx >> 3][idx & 7] = bReg[i];
    }

    const float* lwp = lwcb + ((size_t)(b * kNc + c) * kH + h) * 16;
    float lw[6];
#pragma unroll
    for (int l = 0; l < 6; l++) lw[l] = lwp[l];
#pragma unroll
    for (int n = 0; n < 2; n++) {
      const int k = n * 32 + tg;
      float s = 0.f;
#pragma unroll
      for (int l = 0; l < 6; l++) s = fmaf(lw[l], stL[l][k][v], s);
      S0s[v][k] = s;
      S0g[ch * 4096 + k * 64 + vbase + v] = s;
    }
    __syncthreads();

    const size_t chn = (size_t)bh * 32 + (c < 31 ? c + 1 : 31);
#pragma unroll
    for (int i = 0; i < 16; i++) tReg[i] = Tc[chn * 4096 + tid + i * 256];
#pragma unroll
    for (int i = 0; i < 2; i++) {
      const int idx = tid + i * 256;
      bReg[i] = BcS[chn * 6144 + (idx >> 3) * 64 + vbase + (idx & 7)];
    }

    const int lev = __builtin_ctz(c + 1);
#pragma unroll
    for (int n = 0; n < 2; n++) {
      const int r = n * 32 + tg;
      float s = Bt_[r][v];
#pragma unroll
      for (int k4 = 0; k4 < 16; k4++) {
        const float4 t4 = *(const float4*)&Tt[r][k4 * 4];
        const float4 s4 = *(const float4*)&S0s[v][k4 * 4];
        s = fmaf(t4.x, s4.x, s);
        s = fmaf(t4.y, s4.y, s);
        s = fmaf(t4.z, s4.z, s);
        s = fmaf(t4.w, s4.w, s);
      }
      for (int l = 0; l < lev; l++) { s += stL[l][r][v]; stL[l][r][v] = 0.f; }
      stL[lev][r][v] = s;
    }
    __syncthreads();
  }
}

// ---------------------------------------------------------------------------
// o_gemm: 1024 parallel blocks. O = Qe * S0 + Vo.
// ---------------------------------------------------------------------------
__global__ __launch_bounds__(256) void o_gemm(
    const float* __restrict__ Qe, const float* __restrict__ S0g,
    const float* __restrict__ VoS, float* __restrict__ Obuf) {
  const int ch = blockIdx.x;
  const int tid = threadIdx.x;
  const int v = tid & 63;
  const int tg = tid >> 6;  // 0..3
  __shared__ float Qs[64][64];
  __shared__ float Ss[64][64];
  for (int idx = tid; idx < 4096; idx += 256) {
    ((float*)Qs)[idx] = Qe[(size_t)ch * 4096 + idx];
    ((float*)Ss)[idx] = S0g[(size_t)ch * 4096 + idx];
  }
  __syncthreads();
#pragma unroll
  for (int n = 0; n < 16; n++) {
    const int t = n * 4 + tg;
    float o = VoS[(size_t)ch * 6144 + t * 64 + v];
#pragma unroll 8
    for (int k = 0; k < 64; k++) o = fmaf(Qs[t][k], Ss[k][v], o);
    Obuf[(size_t)ch * 4096 + t * 64 + v] = o;
  }
}

// ---------------------------------------------------------------------------
// gn_stats1/2: two-phase deterministic group-norm statistics.
// ---------------------------------------------------------------------------
__global__ __launch_bounds__(256) void gn_stats1(const float* __restrict__ Obuf,
                                                 double* __restrict__ part) {
  const int blk = blockIdx.x;  // bh*8 + slice
  const size_t base = (size_t)blk * 16384;
  double sum = 0.0, sumsq = 0.0;
  for (int idx = threadIdx.x; idx < 16384; idx += 256) {
    const float val = Obuf[base + idx];
    sum += val;
    sumsq += (double)val * val;
  }
  __shared__ double sred[256], qred[256];
  sred[threadIdx.x] = sum;
  qred[threadIdx.x] = sumsq;
  __syncthreads();
  for (int stp = 128; stp > 0; stp >>= 1) {
    if (threadIdx.x < stp) {
      sred[threadIdx.x] += sred[threadIdx.x + stp];
      qred[threadIdx.x] += qred[threadIdx.x + stp];
    }
    __syncthreads();
  }
  if (threadIdx.x == 0) {
    part[blk * 2] = sred[0];
    part[blk * 2 + 1] = qred[0];
  }
}

__global__ void gn_stats2(const double* __restrict__ part, float* __restrict__ stats) {
  const int bh = threadIdx.x;
  if (bh >= 32) return;
  double s = 0.0, qq = 0.0;
  for (int i = 0; i < 8; i++) {
    s += part[(bh * 8 + i) * 2];
    qq += part[(bh * 8 + i) * 2 + 1];
  }
  const double n = (double)kT * 64.0;
  const double mu = s / n;
  const double var = qq / n - mu * mu;
  stats[bh * 2] = (float)mu;
  stats[bh * 2 + 1] = (float)(1.0 / sqrt(var + 1e-5));
}

__global__ void gate_kernel(const float* __restrict__ Obuf,
                            const __hip_bfloat16* __restrict__ og,
                            const float* __restrict__ gamma, const float* __restrict__ gbeta,
                            const float* __restrict__ stats, __hip_bfloat16* __restrict__ z) {
  const size_t idx = (size_t)blockIdx.x * 256 + threadIdx.x;
  if (idx >= (size_t)kM * 1024) return;
  const int cidx = (int)(idx & 1023);
  const int h = cidx >> 6, v = cidx & 63;
  const size_t m = idx >> 10;
  const int b = (int)(m >> 11);
  const int tok = (int)(m & 2047), c = tok >> 6, tt = tok & 63;
  const float o = Obuf[(size_t)((b * 16 + h) * 32 + c) * 4096 + tt * 64 + v];
  const float mu = stats[(b * 16 + h) * 2];
  const float rstd = stats[(b * 16 + h) * 2 + 1];
  const float val = (o - mu) * rstd * gamma[cidx] + gbeta[cidx];
  const float gt = __bfloat162float(og[idx]);
  z[idx] = __float2bfloat16(val * (1.f / (1.f + expf(-gt))));
}

// ---------------------------------------------------------------------------
extern "C" void kernel_launch(void* const* d_in, const int* in_sizes, int n_in,
                              void* d_out, int out_size, void* d_ws, size_t ws_size,
                              hipStream_t stream) {
  const float* x     = (const float*)d_in[0];
  const float* Wq    = (const float*)d_in[3];
  const float* Wk    = (const float*)d_in[4];
  const float* Wv    = (const float*)d_in[5];
  const float* Wb    = (const float*)d_in[6];
  const float* Wa    = (const float*)d_in[7];
  const float* Wg    = (const float*)d_in[8];
  const float* Wo    = (const float*)d_in[9];
  const float* Wl    = (const float*)d_in[10];
  const float* Lp    = (const float*)d_in[11];
  const float* gamma = (const float*)d_in[12];
  const float* gbeta = (const float*)d_in[13];
  float* out = (float*)d_out;
  (void)ws_size;  // peak usage < 181,469,440 proven in round 1

  char* base = (char*)d_ws;
  // P1: qpack -> zbf
  __hip_bfloat16* qpack = (__hip_bfloat16*)(base + 0);                 // 8,388,608
  __hip_bfloat16* zbf   = qpack;                                       // after products
  // P2/P3: kv packs -> Bt (in-place) -> Bc/Vo f32 (in-place)
  __hip_bfloat16* KP16 = (__hip_bfloat16*)(base + 8388608);            // 25,165,824
  __hip_bfloat16* VP16 = (__hip_bfloat16*)(base + 33554432);           // 25,165,824
  // P4 region (50,331,648): early = xb + weights; then G16; then Tc/Qe/Obuf
  char* P4 = base + 58720256;
  __hip_bfloat16* xb   = (__hip_bfloat16*)(P4 + 0);                    // 8,388,608
  __hip_bfloat16* Wqb  = (__hip_bfloat16*)(P4 + 8388608);              // 2,097,152
  __hip_bfloat16* Wkb  = (__hip_bfloat16*)(P4 + 10485760);             // 6,291,456
  __hip_bfloat16* Wvb  = (__hip_bfloat16*)(P4 + 16777216);             // 6,291,456
  __hip_bfloat16* Wgb  = (__hip_bfloat16*)(P4 + 23068672);             // 2,097,152
  __hip_bfloat16* Wlb  = (__hip_bfloat16*)(P4 + 25165824);             // 524,288
  __hip_bfloat16* Wbdb = (__hip_bfloat16*)(P4 + 25690112);             // 262,144
  __hip_bfloat16* G16  = (__hip_bfloat16*)P4;                          // full 50,331,648
  float* Tc   = (float*)(P4 + 0);                                      // 16,777,216
  float* Qe   = (float*)(P4 + 16777216);                               // 16,777,216
  float* Obuf = (float*)(P4 + 33554432);                               // 16,777,216
  // P5 region (50,331,648): early = lwb; then Astk; then S0g (Astk dead)
  char* P5 = base + 109051904;
  float* lwb = (float*)(P5 + 0);                                       // 4,194,304
  __hip_bfloat16* Astk = (__hip_bfloat16*)P5;                          // 50,331,648
  float* S0g = (float*)P5;                                             // 16,777,216
  // P6: persistent small
  char* P6 = base + 159383552;
  float* betp  = (float*)(P6 + 0);                                     // 786,432
  float* decp  = (float*)(P6 + 786432);                                // 262,144
  float* lwcb  = (float*)(P6 + 1048576);                               // 65,536
  float* statb = (float*)(P6 + 1114112);                               // 1,024
  __hip_bfloat16* Wob = (__hip_bfloat16*)(P6 + 1115136);               // 2,097,152
  __hip_bfloat16* ogb = (__hip_bfloat16*)(P6 + 3212288);               // 8,388,608
  double* gnpart = (double*)(base + 170984448);                        // 4,096

  const dim3 blk(256);

  // fused casts (x + all weights + bd pack)
  cast_all<<<dim3(14080), blk, 0, stream>>>(x, Wq, Wk, Wv, Wg, Wl, Wo, Wb, Wa,
                                            xb, Wqb, Wkb, Wvb, Wgb, Wlb, Wob, Wbdb);

  // projections
  gemm_bf16<6><<<dim3(8, 32),  blk, 0, stream>>>(xb, Wqb,  qpack, nullptr, 1024, nullptr);
  gemm_bf16<5><<<dim3(24, 32), blk, 0, stream>>>(xb, Wkb,  KP16,  nullptr, 3072, nullptr);
  gemm_bf16<5><<<dim3(24, 32), blk, 0, stream>>>(xb, Wvb,  VP16,  nullptr, 3072, nullptr);
  gemm_bf16<3><<<dim3(1, 32),  blk, 0, stream>>>(xb, Wbdb, betp,  decp,    128,  nullptr);
  gemm_bf16<4><<<dim3(2, 32),  blk, 0, stream>>>(xb, Wlb,  lwb,   nullptr, 256,  Lp);
  gemm_bf16<7><<<dim3(8, 32),  blk, 0, stream>>>(xb, Wgb,  ogb,   nullptr, 1024, nullptr);

  lwc_mean<<<dim3(64), blk, 0, stream>>>(lwb, lwcb);

  // chunk operators
  gram_phi<<<dim3(1024), blk, 0, stream>>>(KP16, qpack, G16, Astk);
  chunk_solve<<<dim3(1024, 2), blk, 0, stream>>>(G16, KP16, VP16, betp, decp);
  products<<<dim3(1024), blk, 0, stream>>>(Astk, KP16, VP16, qpack, decp,
                                           Tc, Qe, (float*)KP16, (float*)VP16);

  // sequential state scan (256 blocks) + parallel O gemm
  state_scan<<<dim3(256), blk, 0, stream>>>(Tc, (const float*)KP16, lwcb, S0g);
  o_gemm<<<dim3(1024), blk, 0, stream>>>(Qe, S0g, (const float*)VP16, Obuf);

  // group norm + gate
  gn_stats1<<<dim3(256), blk, 0, stream>>>(Obuf, gnpart);
  gn_stats2<<<dim3(1), dim3(64), 0, stream>>>(gnpart, statb);
  gate_kernel<<<dim3((kM * 1024 + 255) / 256), blk, 0, stream>>>(Obuf, ogb, gamma, gbeta,
                                                                 statb, zbf);

  // final projection
  gemm_bf16<0><<<dim3(8, 32), blk, 0, stream>>>(zbf, Wob, out, nullptr, 1024, nullptr);
}

// Round 13
// 643.874 us; speedup vs baseline: 9.8588x; 1.0542x over previous
//
#include <hip/hip_runtime.h>
#include <hip/hip_bf16.h>
#include <math.h>

// Problem constants
constexpr int kB   = 2;
constexpr int kT   = 2048;
constexpr int kH   = 16;
constexpr int kC   = 64;    // chunk size
constexpr int kNc  = 32;    // T / C
constexpr int kM   = kB * kT;   // 4096
constexpr int kK   = 1024;

using bf16x8 = __attribute__((ext_vector_type(8))) short;
using f32x4  = __attribute__((ext_vector_type(4))) float;

__device__ __forceinline__ void glds16(const void* g, void* l) {
  __builtin_amdgcn_global_load_lds(
      (const __attribute__((address_space(1))) unsigned int*)g,
      (__attribute__((address_space(3))) unsigned int*)l, 16, 0, 0);
}

// ---------------------------------------------------------------------------
// bf16 MFMA NT-GEMM (verified structure). MODE:
//  0: f32 plain [rr*N+cc]
//  3: beta(48)/dec(16) sigmoid -> betp [ch][192] f32, decp [ch][64] f32
//  4: softplus(Lp*x) f32 plain (lw)
//  5: silu -> bf16 pack [ch][i=tt*3+j3][d], coalesced via LDS tile epilogue
//  6: bf16 q pack [ch][t][d]
//  7: bf16 plain [rr*1024+cc] (og)
// ---------------------------------------------------------------------------
template <int MODE>
__global__ __launch_bounds__(256) void gemm_bf16(
    const __hip_bfloat16* __restrict__ A, const __hip_bfloat16* __restrict__ W,
    void* __restrict__ outA, void* __restrict__ outB, int N,
    const float* __restrict__ Lp) {
  __shared__ __hip_bfloat16 As[128 * 32];
  __shared__ __hip_bfloat16 Bs[128 * 32];
  const int tid = threadIdx.x;
  const int w = tid >> 6, lane = tid & 63;
  const int bm = blockIdx.y * 128, bn = blockIdx.x * 128;

  const int sr = tid >> 2, sp = tid & 3;
  const int g0 = sp ^ ((sr >> 1) & 3);
  const __hip_bfloat16* a0 = A + (size_t)(bm + sr) * kK + g0 * 8;
  const __hip_bfloat16* a1 = A + (size_t)(bm + sr + 64) * kK + g0 * 8;
  const __hip_bfloat16* b0 = W + (size_t)(bn + sr) * kK + g0 * 8;
  const __hip_bfloat16* b1 = W + (size_t)(bn + sr + 64) * kK + g0 * 8;
  char* AsB = (char*)As + w * 1024;
  char* BsB = (char*)Bs + w * 1024;

  const int wr = w >> 1, wc = w & 1;
  const int fr = lane & 15, fc = lane >> 4;
  int aOff[4], bOff[4];
#pragma unroll
  for (int f = 0; f < 4; f++) {
    const int ra = wr * 64 + f * 16 + fr;
    aOff[f] = ra * 64 + ((fc ^ ((ra >> 1) & 3)) * 16);
    const int rb = wc * 64 + f * 16 + fr;
    bOff[f] = rb * 64 + ((fc ^ ((rb >> 1) & 3)) * 16);
  }

  f32x4 acc[4][4];
#pragma unroll
  for (int i = 0; i < 4; i++)
#pragma unroll
    for (int j = 0; j < 4; j++) acc[i][j] = (f32x4){0.f, 0.f, 0.f, 0.f};

  for (int k0 = 0; k0 < kK; k0 += 32) {
    __syncthreads();
    glds16(a0 + k0, AsB);
    glds16(a1 + k0, AsB + 4096);
    glds16(b0 + k0, BsB);
    glds16(b1 + k0, BsB + 4096);
    __syncthreads();

    bf16x8 af[4], bfr[4];
#pragma unroll
    for (int f = 0; f < 4; f++) af[f] = *(const bf16x8*)((const char*)As + aOff[f]);
#pragma unroll
    for (int f = 0; f < 4; f++) bfr[f] = *(const bf16x8*)((const char*)Bs + bOff[f]);
#pragma unroll
    for (int i = 0; i < 4; i++)
#pragma unroll
      for (int j = 0; j < 4; j++)
        acc[i][j] = __builtin_amdgcn_mfma_f32_16x16x32_bf16(af[i], bfr[j], acc[i][j], 0, 0, 0);
  }

  if constexpr (MODE == 5) {
    // stage silu'd tile in LDS, then write destination-major coalesced runs
    __shared__ __hip_bfloat16 Ct[128][129];
#pragma unroll
    for (int i = 0; i < 4; i++)
#pragma unroll
      for (int j = 0; j < 4; j++)
#pragma unroll
        for (int e = 0; e < 4; e++) {
          const int rl = wr * 64 + i * 16 + fc * 4 + e;
          const int cl = wc * 64 + j * 16 + fr;
          float vx = acc[i][j][e];
          vx = vx / (1.f + expf(-vx));
          Ct[rl][cl] = __float2bfloat16(vx);
        }
    __syncthreads();
    const int cc0 = bn;
    const int hh0 = cc0 / 192;
    const int dl = tid & 31, rq = tid >> 5;
    for (int cmb = 0; cmb < 6; cmb++) {
      const int hh = hh0 + cmb / 3;
      if (hh >= 16) continue;
      const int j3 = cmb % 3;
      const int off = cc0 - hh * 192 - j3;     // cc = hh*192 + 3d + j3
      const int d_lo = (off <= 0) ? 0 : (off + 2) / 3;
      const int hi_num = off + 127;
      if (hi_num < 0) continue;
      const int d_hi = (hi_num / 3) > 63 ? 63 : (hi_num / 3);
      if (d_hi < d_lo) continue;
      for (int r0 = 0; r0 < 128; r0 += 8) {
        const int rl = r0 + rq;
        const int token = bm + rl;
        const int b = token >> 11, tok = token & 2047, chn = tok >> 6, tt = tok & 63;
        __hip_bfloat16* dst = (__hip_bfloat16*)outA +
            (size_t)((b * 16 + hh) * 32 + chn) * 12288 + (tt * 3 + j3) * 64;
        for (int dd = d_lo + dl; dd <= d_hi; dd += 32)
          dst[dd] = Ct[rl][hh * 192 + 3 * dd + j3 - cc0];
      }
    }
    return;
  }

  const int r0 = bm + wr * 64, c0 = bn + wc * 64;
#pragma unroll
  for (int i = 0; i < 4; i++)
#pragma unroll
    for (int j = 0; j < 4; j++)
#pragma unroll
      for (int e = 0; e < 4; e++) {
        const int rr = r0 + i * 16 + fc * 4 + e;
        const int cc = c0 + j * 16 + fr;
        float vx = acc[i][j][e];
        if constexpr (MODE == 0) {
          ((float*)outA)[(size_t)rr * N + cc] = vx;
        } else if constexpr (MODE == 4) {
          const float y = Lp[cc] * vx;
          vx = fmaxf(y, 0.f) + log1pf(expf(-fabsf(y)));
          ((float*)outA)[(size_t)rr * N + cc] = vx;
        } else if constexpr (MODE == 3) {
          const float s = 1.f / (1.f + expf(-vx));
          const int b = rr >> 11, tok = rr & 2047, chn = tok >> 6, tt = tok & 63;
          if (cc < 48) {
            const int hh = cc / 3, j3 = cc - hh * 3;
            ((float*)outA)[(size_t)((b * 16 + hh) * 32 + chn) * 192 + tt * 3 + j3] = s;
          } else if (cc < 64) {
            const int hh = cc - 48;
            ((float*)outB)[(size_t)((b * 16 + hh) * 32 + chn) * 64 + tt] = s;
          }
        } else if constexpr (MODE == 6) {
          const int b = rr >> 11, tok = rr & 2047, chn = tok >> 6, tt = tok & 63;
          const int hh = cc >> 6, d = cc & 63;
          ((__hip_bfloat16*)outA)[(size_t)((b * 16 + hh) * 32 + chn) * 4096 +
                                  tt * 64 + d] = __float2bfloat16(vx);
        } else if constexpr (MODE == 7) {
          ((__hip_bfloat16*)outA)[(size_t)rr * 1024 + cc] = __float2bfloat16(vx);
        }
      }
}

// ---------------------------------------------------------------------------
// cast_all: fused f32->bf16 casts for x + all weights + packed Wb/Wa tile.
// ---------------------------------------------------------------------------
__global__ void cast_all(const float* __restrict__ x, const float* __restrict__ Wq,
                         const float* __restrict__ Wk, const float* __restrict__ Wv,
                         const float* __restrict__ Wg, const float* __restrict__ Wl,
                         const float* __restrict__ Wo, const float* __restrict__ Wb,
                         const float* __restrict__ Wa,
                         __hip_bfloat16* __restrict__ xb, __hip_bfloat16* __restrict__ Wqb,
                         __hip_bfloat16* __restrict__ Wkb, __hip_bfloat16* __restrict__ Wvb,
                         __hip_bfloat16* __restrict__ Wgb, __hip_bfloat16* __restrict__ Wlb,
                         __hip_bfloat16* __restrict__ Wob, __hip_bfloat16* __restrict__ Wbdb) {
  const int gb = blockIdx.x, tid = threadIdx.x;
  const float* src; __hip_bfloat16* dst; int base;
  if (gb < 4096)       { src = x;  dst = xb;  base = gb; }
  else if (gb < 5120)  { src = Wq; dst = Wqb; base = gb - 4096; }
  else if (gb < 8192)  { src = Wk; dst = Wkb; base = gb - 5120; }
  else if (gb < 11264) { src = Wv; dst = Wvb; base = gb - 8192; }
  else if (gb < 12288) { src = Wg; dst = Wgb; base = gb - 11264; }
  else if (gb < 12544) { src = Wl; dst = Wlb; base = gb - 12288; }
  else if (gb < 13568) { src = Wo; dst = Wob; base = gb - 12544; }
  else {
    const int idx = (gb - 13568) * 256 + tid;
    if (idx < 128 * 1024) {
      const int r = idx >> 10, k = idx & 1023;
      const float val = (r < 48) ? Wb[r * 1024 + k]
                                 : ((r < 64) ? Wa[(r - 48) * 1024 + k] : 0.f);
      Wbdb[idx] = __float2bfloat16(val);
    }
    return;
  }
  const int i = (base * 256 + tid) * 4;
  const float4 v = *(const float4*)(src + i);
  __hip_bfloat16 tmp[4] = {__float2bfloat16(v.x), __float2bfloat16(v.y),
                           __float2bfloat16(v.z), __float2bfloat16(v.w)};
  *(ushort4*)(dst + i) = *(ushort4*)tmp;
}

__global__ void lwc_mean(const float* __restrict__ lw, float* __restrict__ lwc) {
  const int idx = blockIdx.x * 256 + threadIdx.x;
  if (idx >= kB * kNc * kH * 16) return;
  const int l = idx & 15, h = (idx >> 4) & 15, c = (idx >> 8) & 31, b = idx >> 13;
  size_t base = ((size_t)b * kT + (size_t)c * kC) * 256 + h * 16 + l;
  float s = 0.f;
  for (int tt = 0; tt < kC; tt++) s += lw[base + (size_t)tt * 256];
  lwc[idx] = s * (1.f / 64.f);
}

// ---------------------------------------------------------------------------
// gram_phi: per-chunk-head. S = [K(192); Q(64)] (256x64 bf16). Out = S*K^T.
// ---------------------------------------------------------------------------
__global__ __launch_bounds__(256, 1) void gram_phi(
    const __hip_bfloat16* __restrict__ KP16, const __hip_bfloat16* __restrict__ qpack,
    __hip_bfloat16* __restrict__ G16, __hip_bfloat16* __restrict__ Astk) {
  const int ch = blockIdx.x;
  const int tid = threadIdx.x;
  const int w = tid >> 6, lane = tid & 63;
  __shared__ __hip_bfloat16 Sa[256 * 64];  // row-swizzled

  for (int cidx = tid; cidx < 2048; cidx += 256) {
    const int r = cidx >> 3, cko = cidx & 7;
    const __hip_bfloat16* src =
        (r < 192) ? (KP16 + (size_t)ch * 12288 + r * 64 + cko * 8)
                  : (qpack + (size_t)ch * 4096 + (r - 192) * 64 + cko * 8);
    bf16x8 vv = *(const bf16x8*)src;
    *(bf16x8*)((char*)Sa + r * 128 + ((cko ^ ((r >> 1) & 3)) * 16)) = vv;
  }
  __syncthreads();

  const int fr = lane & 15, fc = lane >> 4;
  f32x4 acc[4][12];
#pragma unroll
  for (int i = 0; i < 4; i++)
#pragma unroll
    for (int j = 0; j < 12; j++) acc[i][j] = (f32x4){0.f, 0.f, 0.f, 0.f};

#pragma unroll
  for (int ks = 0; ks < 2; ks++) {
    bf16x8 af[4];
#pragma unroll
    for (int i = 0; i < 4; i++) {
      const int ra = w * 64 + i * 16 + fr;
      af[i] = *(const bf16x8*)((char*)Sa + ra * 128 + (((ks * 4 + fc) ^ ((ra >> 1) & 3)) * 16));
    }
#pragma unroll
    for (int j = 0; j < 12; j++) {
      const int rb = j * 16 + fr;
      bf16x8 bfv = *(const bf16x8*)((char*)Sa + rb * 128 + (((ks * 4 + fc) ^ ((rb >> 1) & 3)) * 16));
#pragma unroll
      for (int i = 0; i < 4; i++)
        acc[i][j] = __builtin_amdgcn_mfma_f32_16x16x32_bf16(af[i], bfv, acc[i][j], 0, 0, 0);
    }
  }

#pragma unroll
  for (int i = 0; i < 4; i++)
#pragma unroll
    for (int j = 0; j < 12; j++)
#pragma unroll
      for (int e = 0; e < 4; e++) {
        const int gr = w * 64 + i * 16 + fc * 4 + e;
        const int gc = j * 16 + fr;
        const float val = acc[i][j][e];
        if (gr < 192) {
          const int sbb = gr >> 6, jbb = gc >> 6;
          if (jbb <= sbb)
            G16[(size_t)ch * 24576 + (size_t)(sbb * (sbb + 1) / 2 + jbb) * 4096 +
                (gr & 63) * 64 + (gc & 63)] = __float2bfloat16(val);
        } else {
          const int t = gr - 192;
          const float mval = ((gc / 3) <= t) ? val : 0.f;
          Astk[(size_t)ch * 24576 + (size_t)(64 + t) * 192 + gc] = __float2bfloat16(mval);
        }
      }

  // KT rows: Astk[ch][d][i] = K[i][d] (from swizzled LDS)
  for (int s = tid; s < 1536; s += 256) {
    const int d = s / 24, i0 = (s % 24) * 8;
    __hip_bfloat16 tmp[8];
#pragma unroll
    for (int e = 0; e < 8; e++) {
      const int i = i0 + e;
      tmp[e] = *(const __hip_bfloat16*)((char*)Sa + i * 128 +
                                        (((d >> 3) ^ ((i >> 1) & 3)) * 16) + (d & 7) * 2);
    }
    *(bf16x8*)(Astk + (size_t)ch * 24576 + (size_t)d * 192 + i0) = *(bf16x8*)tmp;
  }
}

// ---------------------------------------------------------------------------
// chunk_solve: grid (1024, 2). Block (ch, half) solves (I + Ltil) Xt = Rt for
// its 64-column half (half 0: K, half 1: V/c); Ltil[i][j] = beta_j*G[i][j].
// 4x4 register-blocked updates; tile staging vectorized (bf16x8 loads +
// float4 LDS stores) with identical values and fma order -> bit-identical.
// In-place Bt write is safe: each block owns one whole buffer strip.
// ---------------------------------------------------------------------------
__global__ __launch_bounds__(256) void chunk_solve(
    const __hip_bfloat16* __restrict__ G16,
    __hip_bfloat16* __restrict__ KP16, __hip_bfloat16* __restrict__ VP16,
    const float* __restrict__ betp, const float* __restrict__ decp) {
  const int ch = blockIdx.x;
  const int half = blockIdx.y;
  const int tid = threadIdx.x;
  constexpr int XS = 68;   // X row stride (rows 16B-aligned; bank = 4r+c)
  constexpr int TS = 68;   // tile row stride
  __shared__ float X[192 * XS];      // 52,224 B
  __shared__ float tile[64 * TS];    // 17,408 B
  __shared__ float bet[192], cpre[64], rc[64];

  if (tid < 192) bet[tid] = betp[(size_t)ch * 192 + tid];
  if (tid < 64) cpre[tid] = decp[(size_t)ch * 64 + tid];
  __syncthreads();
  if (tid == 0) {
    float p = 1.f;
    for (int t = 0; t < 64; t++) { p *= cpre[t]; cpre[t] = p; }
  }
  __syncthreads();
  if (tid < 64) rc[tid] = 1.f / cpre[tid];
  __syncthreads();

  // stage RHS (this half's 64 columns): half 0 -> K, half 1 -> V / c_tau(i)
  __hip_bfloat16* rhs = (half ? VP16 : KP16) + (size_t)ch * 12288;
  for (int v = tid; v < 1536; v += 256) {
    const int i = v >> 3, d0 = (v & 7) * 8;
    bf16x8 vb8 = *(const bf16x8*)(rhs + i * 64 + d0);
    const float sc = half ? rc[i / 3] : 1.f;
#pragma unroll
    for (int e = 0; e < 8; e++)
      X[i * XS + d0 + e] = __bfloat162float(*(((const __hip_bfloat16*)&vb8) + e)) * sc;
  }
  __syncthreads();

  const int ty = tid >> 4, tx = tid & 15;   // 16 x 16 thread grid
  const int col4 = tx * 4;

  for (int sb = 0; sb < 3; sb++) {
    const int s = sb * 64;
    // ---- off-diagonal rank-64 updates (4x4 register blocked)
    for (int jb = 0; jb < sb; jb++) {
      const __hip_bfloat16* gt = G16 + (size_t)ch * 24576 +
                                 (size_t)(sb * (sb + 1) / 2 + jb) * 4096;
      for (int v = tid; v < 512; v += 256) {
        const int row = v >> 3, c0v = (v & 7) * 8;
        bf16x8 g8 = *(const bf16x8*)(gt + row * 64 + c0v);
        float tf[8];
#pragma unroll
        for (int e = 0; e < 8; e++)
          tf[e] = __bfloat162float(*(((const __hip_bfloat16*)&g8) + e)) *
                  bet[jb * 64 + c0v + e];
        *(float4*)&tile[row * TS + c0v] = *(float4*)&tf[0];
        *(float4*)&tile[row * TS + c0v + 4] = *(float4*)&tf[4];
      }
      __syncthreads();

      const int j0 = jb * 64;
      const int r0 = s + ty * 4;
      float4 acc[4];
#pragma unroll
      for (int r = 0; r < 4; r++) acc[r] = *(const float4*)&X[(r0 + r) * XS + col4];
#pragma unroll
      for (int k4 = 0; k4 < 16; k4++) {
        float4 xv[4];
#pragma unroll
        for (int e = 0; e < 4; e++)
          xv[e] = *(const float4*)&X[(j0 + k4 * 4 + e) * XS + col4];
#pragma unroll
        for (int r = 0; r < 4; r++) {
          const float4 t = *(const float4*)&tile[(ty * 4 + r) * TS + k4 * 4];
          acc[r].x = fmaf(-t.x, xv[0].x, acc[r].x);
          acc[r].y = fmaf(-t.x, xv[0].y, acc[r].y);
          acc[r].z = fmaf(-t.x, xv[0].z, acc[r].z);
          acc[r].w = fmaf(-t.x, xv[0].w, acc[r].w);
          acc[r].x = fmaf(-t.y, xv[1].x, acc[r].x);
          acc[r].y = fmaf(-t.y, xv[1].y, acc[r].y);
          acc[r].z = fmaf(-t.y, xv[1].z, acc[r].z);
          acc[r].w = fmaf(-t.y, xv[1].w, acc[r].w);
          acc[r].x = fmaf(-t.z, xv[2].x, acc[r].x);
          acc[r].y = fmaf(-t.z, xv[2].y, acc[r].y);
          acc[r].z = fmaf(-t.z, xv[2].z, acc[r].z);
          acc[r].w = fmaf(-t.z, xv[2].w, acc[r].w);
          acc[r].x = fmaf(-t.w, xv[3].x, acc[r].x);
          acc[r].y = fmaf(-t.w, xv[3].y, acc[r].y);
          acc[r].z = fmaf(-t.w, xv[3].z, acc[r].z);
          acc[r].w = fmaf(-t.w, xv[3].w, acc[r].w);
        }
      }
#pragma unroll
      for (int r = 0; r < 4; r++) *(float4*)&X[(r0 + r) * XS + col4] = acc[r];
      __syncthreads();
    }

    // ---- stage diagonal Ltil block (vectorized)
    {
      const __hip_bfloat16* gt = G16 + (size_t)ch * 24576 +
                                 (size_t)(sb * (sb + 1) / 2 + sb) * 4096;
      for (int v = tid; v < 512; v += 256) {
        const int row = v >> 3, c0v = (v & 7) * 8;
        bf16x8 g8 = *(const bf16x8*)(gt + row * 64 + c0v);
        float tf[8];
#pragma unroll
        for (int e = 0; e < 8; e++)
          tf[e] = __bfloat162float(*(((const __hip_bfloat16*)&g8) + e)) *
                  bet[s + c0v + e];
        *(float4*)&tile[row * TS + c0v] = *(float4*)&tf[0];
        *(float4*)&tile[row * TS + c0v + 4] = *(float4*)&tf[4];
      }
    }
    __syncthreads();

    // ---- 16-sub-blocked diagonal solve
    for (int db = 0; db < 4; db++) {
      const int l0 = db * 16;
      if (tid < 64) {  // one wave: serial 16-row solve entirely in registers
        float xd[16];
#pragma unroll
        for (int j = 0; j < 16; j++) xd[j] = X[(s + l0 + j) * XS + tid];
#pragma unroll
        for (int ii = 1; ii < 16; ii++)
          for (int jj = 0; jj < ii; jj++)
            xd[ii] = fmaf(-tile[(l0 + ii) * TS + l0 + jj], xd[jj], xd[ii]);
#pragma unroll
        for (int j = 1; j < 16; j++) X[(s + l0 + j) * XS + tid] = xd[j];
      }
      __syncthreads();
      // trailing rank-16 update on rows l0+16..63 (4x4 register blocked)
      const int rem = 48 - l0;
      if (rem > 0) {
        const int ng = rem >> 2;   // row-groups of 4: 12, 8, 4
        if (ty < ng) {
          const int r0 = s + l0 + 16 + ty * 4;
          float4 acc[4];
#pragma unroll
          for (int r = 0; r < 4; r++) acc[r] = *(const float4*)&X[(r0 + r) * XS + col4];
#pragma unroll
          for (int k4 = 0; k4 < 4; k4++) {
            float4 xv[4];
#pragma unroll
            for (int e = 0; e < 4; e++)
              xv[e] = *(const float4*)&X[(s + l0 + k4 * 4 + e) * XS + col4];
#pragma unroll
            for (int r = 0; r < 4; r++) {
              const float4 t = *(const float4*)&tile[(l0 + 16 + ty * 4 + r) * TS + l0 + k4 * 4];
              acc[r].x = fmaf(-t.x, xv[0].x, acc[r].x);
              acc[r].y = fmaf(-t.x, xv[0].y, acc[r].y);
              acc[r].z = fmaf(-t.x, xv[0].z, acc[r].z);
              acc[r].w = fmaf(-t.x, xv[0].w, acc[r].w);
              acc[r].x = fmaf(-t.y, xv[1].x, acc[r].x);
              acc[r].y = fmaf(-t.y, xv[1].y, acc[r].y);
              acc[r].z = fmaf(-t.y, xv[1].z, acc[r].z);
              acc[r].w = fmaf(-t.y, xv[1].w, acc[r].w);
              acc[r].x = fmaf(-t.z, xv[2].x, acc[r].x);
              acc[r].y = fmaf(-t.z, xv[2].y, acc[r].y);
              acc[r].z = fmaf(-t.z, xv[2].z, acc[r].z);
              acc[r].w = fmaf(-t.z, xv[2].w, acc[r].w);
              acc[r].x = fmaf(-t.w, xv[3].x, acc[r].x);
              acc[r].y = fmaf(-t.w, xv[3].y, acc[r].y);
              acc[r].z = fmaf(-t.w, xv[3].z, acc[r].z);
              acc[r].w = fmaf(-t.w, xv[3].w, acc[r].w);
            }
          }
#pragma unroll
          for (int r = 0; r < 4; r++) *(float4*)&X[(r0 + r) * XS + col4] = acc[r];
        }
      }
      __syncthreads();
    }
  }

  // ---- write Bt over this half's strip: Bt[col][i] = beta_i * X[i][col]
  for (int v = tid; v < 1536; v += 256) {
    const int c2 = v & 63, i0 = (v >> 6) * 8;
    __hip_bfloat16 tmp[8];
#pragma unroll
    for (int e = 0; e < 8; e++)
      tmp[e] = __float2bfloat16(bet[i0 + e] * X[(i0 + e) * XS + c2]);
    *(bf16x8*)(rhs + c2 * 192 + i0) = *(bf16x8*)tmp;
  }
}

// ---------------------------------------------------------------------------
// products: per ch. Out(128x128) = Astk(128x192) x Bt(128x192)^T-NT.
// ---------------------------------------------------------------------------
__global__ __launch_bounds__(256) void products(
    const __hip_bfloat16* __restrict__ Astk,
    const __hip_bfloat16* __restrict__ KP16, const __hip_bfloat16* __restrict__ VP16,
    const __hip_bfloat16* __restrict__ qpack, const float* __restrict__ decp,
    float* __restrict__ Tc, float* __restrict__ Qe,
    float* __restrict__ BcW, float* __restrict__ VoW) {
  const int ch = blockIdx.x;
  const int tid = threadIdx.x;
  const int w = tid >> 6, lane = tid & 63;
  __shared__ __hip_bfloat16 As[128 * 32];
  __shared__ __hip_bfloat16 Bs[128 * 32];
  __shared__ float cpre[64];

  if (tid < 64) cpre[tid] = decp[(size_t)ch * 64 + tid];
  __syncthreads();
  if (tid == 0) {
    float p = 1.f;
    for (int t = 0; t < 64; t++) { p *= cpre[t]; cpre[t] = p; }
  }

  const int sr = tid >> 2, sp = tid & 3;
  const int g0 = sp ^ ((sr >> 1) & 3);
  const __hip_bfloat16* a0 = Astk + (size_t)ch * 24576 + sr * 192 + g0 * 8;
  const __hip_bfloat16* a1 = a0 + 64 * 192;
  const __hip_bfloat16* b0 = KP16 + (size_t)ch * 12288 + sr * 192 + g0 * 8;
  const __hip_bfloat16* b1 = VP16 + (size_t)ch * 12288 + sr * 192 + g0 * 8;
  char* AsB = (char*)As + w * 1024;
  char* BsB = (char*)Bs + w * 1024;

  const int wr = w >> 1, wc = w & 1;
  const int fr = lane & 15, fc = lane >> 4;
  int aOff[4], bOff[4];
#pragma unroll
  for (int f = 0; f < 4; f++) {
    const int ra = wr * 64 + f * 16 + fr;
    aOff[f] = ra * 64 + ((fc ^ ((ra >> 1) & 3)) * 16);
    const int rb = wc * 64 + f * 16 + fr;
    bOff[f] = rb * 64 + ((fc ^ ((rb >> 1) & 3)) * 16);
  }

  f32x4 acc[4][4];
#pragma unroll
  for (int i = 0; i < 4; i++)
#pragma unroll
    for (int j = 0; j < 4; j++) acc[i][j] = (f32x4){0.f, 0.f, 0.f, 0.f};

  for (int k0 = 0; k0 < 192; k0 += 32) {
    __syncthreads();
    glds16(a0 + k0, AsB);
    glds16(a1 + k0, AsB + 4096);
    glds16(b0 + k0, BsB);
    glds16(b1 + k0, BsB + 4096);
    __syncthreads();

    bf16x8 af[4], bfr[4];
#pragma unroll
    for (int f = 0; f < 4; f++) af[f] = *(const bf16x8*)((const char*)As + aOff[f]);
#pragma unroll
    for (int f = 0; f < 4; f++) bfr[f] = *(const bf16x8*)((const char*)Bs + bOff[f]);
#pragma unroll
    for (int i = 0; i < 4; i++)
#pragma unroll
      for (int j = 0; j < 4; j++)
        acc[i][j] = __builtin_amdgcn_mfma_f32_16x16x32_bf16(af[i], bfr[j], acc[i][j], 0, 0, 0);
  }
  __syncthreads();

  const float cC = cpre[63];
#pragma unroll
  for (int i = 0; i < 4; i++)
#pragma unroll
    for (int j = 0; j < 4; j++)
#pragma unroll
      for (int e = 0; e < 4; e++) {
        const int rr = wr * 64 + i * 16 + fc * 4 + e;
        const int cc = wc * 64 + j * 16 + fr;
        const float val = acc[i][j][e];
        if (rr < 64) {
          if (cc < 64)
            Tc[(size_t)ch * 4096 + rr * 64 + cc] = cC * (((rr == cc) ? 1.f : 0.f) - val);
          else
            BcW[(size_t)ch * 6144 + rr * 64 + (cc - 64)] = cC * val;
        } else {
          const int t = rr - 64;
          const float ct = cpre[t];
          if (cc < 64) {
            const float qv = __bfloat162float(qpack[(size_t)ch * 4096 + t * 64 + cc]);
            Qe[(size_t)ch * 4096 + t * 64 + cc] = ct * (qv - val);
          } else {
            VoW[(size_t)ch * 6144 + t * 64 + (cc - 64)] = ct * val;
          }
        }
      }
}

// ---------------------------------------------------------------------------
// state_scan: 256 blocks = (b,h) x 8 v-slices. Sequential state pass only.
// ---------------------------------------------------------------------------
__global__ __launch_bounds__(256) void state_scan(
    const float* __restrict__ Tc, const float* __restrict__ BcS,
    const float* __restrict__ lwcb, float* __restrict__ S0g) {
  const int blk = blockIdx.x;       // bh*8 + vs
  const int bh = blk >> 3, vs = blk & 7;
  const int b = bh >> 4, h = bh & 15;
  const int vbase = vs * 8;
  const int tid = threadIdx.x;
  const int v = tid & 7;
  const int tg = tid >> 3;          // 0..31

  __shared__ float stL[6][64][8];
  __shared__ float S0s[8][68];
  __shared__ float Tt[64][68];
  __shared__ float Bt_[64][8];

  for (int idx = tid; idx < 6 * 512; idx += 256) ((float*)stL)[idx] = 0.f;

  float tReg[16], bReg[2];
  {
    const size_t ch0 = (size_t)bh * 32;
#pragma unroll
    for (int i = 0; i < 16; i++) tReg[i] = Tc[ch0 * 4096 + tid + i * 256];
#pragma unroll
    for (int i = 0; i < 2; i++) {
      const int idx = tid + i * 256;
      bReg[i] = BcS[ch0 * 6144 + (idx >> 3) * 64 + vbase + (idx & 7)];
    }
  }
  __syncthreads();

  for (int c = 0; c < 32; c++) {
    const size_t ch = (size_t)bh * 32 + c;
#pragma unroll
    for (int i = 0; i < 16; i++) {
      const int idx = tid + i * 256;
      Tt[idx >> 6][idx & 63] = tReg[i];
    }
#pragma unroll
    for (int i = 0; i < 2; i++) {
      const int idx = tid + i * 256;
      Bt_[idx >> 3][idx & 7] = bReg[i];
    }

    const float* lwp = lwcb + ((size_t)(b * kNc + c) * kH + h) * 16;
    float lw[6];
#pragma unroll
    for (int l = 0; l < 6; l++) lw[l] = lwp[l];
#pragma unroll
    for (int n = 0; n < 2; n++) {
      const int k = n * 32 + tg;
      float s = 0.f;
#pragma unroll
      for (int l = 0; l < 6; l++) s = fmaf(lw[l], stL[l][k][v], s);
      S0s[v][k] = s;
      S0g[ch * 4096 + k * 64 + vbase + v] = s;
    }
    __syncthreads();

    const size_t chn = (size_t)bh * 32 + (c < 31 ? c + 1 : 31);
#pragma unroll
    for (int i = 0; i < 16; i++) tReg[i] = Tc[chn * 4096 + tid + i * 256];
#pragma unroll
    for (int i = 0; i < 2; i++) {
      const int idx = tid + i * 256;
      bReg[i] = BcS[chn * 6144 + (idx >> 3) * 64 + vbase + (idx & 7)];
    }

    const int lev = __builtin_ctz(c + 1);
#pragma unroll
    for (int n = 0; n < 2; n++) {
      const int r = n * 32 + tg;
      float s = Bt_[r][v];
#pragma unroll
      for (int k4 = 0; k4 < 16; k4++) {
        const float4 t4 = *(const float4*)&Tt[r][k4 * 4];
        const float4 s4 = *(const float4*)&S0s[v][k4 * 4];
        s = fmaf(t4.x, s4.x, s);
        s = fmaf(t4.y, s4.y, s);
        s = fmaf(t4.z, s4.z, s);
        s = fmaf(t4.w, s4.w, s);
      }
      for (int l = 0; l < lev; l++) { s += stL[l][r][v]; stL[l][r][v] = 0.f; }
      stL[lev][r][v] = s;
    }
    __syncthreads();
  }
}

// ---------------------------------------------------------------------------
// o_gemm: 1024 parallel blocks. O = Qe * S0 + Vo, with fused per-ch groupnorm
// partial sums (double, fixed tree order -> deterministic).
// ---------------------------------------------------------------------------
__global__ __launch_bounds__(256) void o_gemm(
    const float* __restrict__ Qe, const float* __restrict__ S0g,
    const float* __restrict__ VoS, float* __restrict__ Obuf,
    double* __restrict__ part) {
  const int ch = blockIdx.x;
  const int tid = threadIdx.x;
  const int v = tid & 63;
  const int tg = tid >> 6;  // 0..3
  __shared__ float Qs[64][64];
  __shared__ float Ss[64][64];
  __shared__ double sred[256], qred[256];
  for (int idx = tid; idx < 4096; idx += 256) {
    ((float*)Qs)[idx] = Qe[(size_t)ch * 4096 + idx];
    ((float*)Ss)[idx] = S0g[(size_t)ch * 4096 + idx];
  }
  __syncthreads();
  double psum = 0.0, psq = 0.0;
#pragma unroll
  for (int n = 0; n < 16; n++) {
    const int t = n * 4 + tg;
    float o = VoS[(size_t)ch * 6144 + t * 64 + v];
#pragma unroll 8
    for (int k = 0; k < 64; k++) o = fmaf(Qs[t][k], Ss[k][v], o);
    Obuf[(size_t)ch * 4096 + t * 64 + v] = o;
    psum += o;
    psq += (double)o * o;
  }
  sred[tid] = psum;
  qred[tid] = psq;
  __syncthreads();
  for (int stp = 128; stp > 0; stp >>= 1) {
    if (tid < stp) {
      sred[tid] += sred[tid + stp];
      qred[tid] += qred[tid + stp];
    }
    __syncthreads();
  }
  if (tid == 0) {
    part[ch * 2] = sred[0];
    part[ch * 2 + 1] = qred[0];
  }
}

// ---------------------------------------------------------------------------
// gn_stats2: final deterministic reduction (32 chunk-partials per (b,h)).
// ---------------------------------------------------------------------------
__global__ void gn_stats2(const double* __restrict__ part, float* __restrict__ stats) {
  const int bh = threadIdx.x;
  if (bh >= 32) return;
  double s = 0.0, qq = 0.0;
  for (int i = 0; i < 32; i++) {
    s += part[(bh * 32 + i) * 2];
    qq += part[(bh * 32 + i) * 2 + 1];
  }
  const double n = (double)kT * 64.0;
  const double mu = s / n;
  const double var = qq / n - mu * mu;
  stats[bh * 2] = (float)mu;
  stats[bh * 2 + 1] = (float)(1.0 / sqrt(var + 1e-5));
}

__global__ void gate_kernel(const float* __restrict__ Obuf,
                            const __hip_bfloat16* __restrict__ og,
                            const float* __restrict__ gamma, const float* __restrict__ gbeta,
                            const float* __restrict__ stats, __hip_bfloat16* __restrict__ z) {
  const size_t idx = (size_t)blockIdx.x * 256 + threadIdx.x;
  if (idx >= (size_t)kM * 1024) return;
  const int cidx = (int)(idx & 1023);
  const int h = cidx >> 6, v = cidx & 63;
  const size_t m = idx >> 10;
  const int b = (int)(m >> 11);
  const int tok = (int)(m & 2047), c = tok >> 6, tt = tok & 63;
  const float o = Obuf[(size_t)((b * 16 + h) * 32 + c) * 4096 + tt * 64 + v];
  const float mu = stats[(b * 16 + h) * 2];
  const float rstd = stats[(b * 16 + h) * 2 + 1];
  const float val = (o - mu) * rstd * gamma[cidx] + gbeta[cidx];
  const float gt = __bfloat162float(og[idx]);
  z[idx] = __float2bfloat16(val * (1.f / (1.f + expf(-gt))));
}

// ---------------------------------------------------------------------------
extern "C" void kernel_launch(void* const* d_in, const int* in_sizes, int n_in,
                              void* d_out, int out_size, void* d_ws, size_t ws_size,
                              hipStream_t stream) {
  const float* x     = (const float*)d_in[0];
  const float* Wq    = (const float*)d_in[3];
  const float* Wk    = (const float*)d_in[4];
  const float* Wv    = (const float*)d_in[5];
  const float* Wb    = (const float*)d_in[6];
  const float* Wa    = (const float*)d_in[7];
  const float* Wg    = (const float*)d_in[8];
  const float* Wo    = (const float*)d_in[9];
  const float* Wl    = (const float*)d_in[10];
  const float* Lp    = (const float*)d_in[11];
  const float* gamma = (const float*)d_in[12];
  const float* gbeta = (const float*)d_in[13];
  float* out = (float*)d_out;
  (void)ws_size;  // peak usage < 181,469,440 proven in round 1

  char* base = (char*)d_ws;
  // P1: qpack -> zbf
  __hip_bfloat16* qpack = (__hip_bfloat16*)(base + 0);                 // 8,388,608
  __hip_bfloat16* zbf   = qpack;                                       // after products
  // P2/P3: kv packs -> Bt (in-place) -> Bc/Vo f32 (in-place)
  __hip_bfloat16* KP16 = (__hip_bfloat16*)(base + 8388608);            // 25,165,824
  __hip_bfloat16* VP16 = (__hip_bfloat16*)(base + 33554432);           // 25,165,824
  // P4 region (50,331,648): early = xb + weights; then G16; then Tc/Qe/Obuf
  char* P4 = base + 58720256;
  __hip_bfloat16* xb   = (__hip_bfloat16*)(P4 + 0);                    // 8,388,608
  __hip_bfloat16* Wqb  = (__hip_bfloat16*)(P4 + 8388608);              // 2,097,152
  __hip_bfloat16* Wkb  = (__hip_bfloat16*)(P4 + 10485760);             // 6,291,456
  __hip_bfloat16* Wvb  = (__hip_bfloat16*)(P4 + 16777216);             // 6,291,456
  __hip_bfloat16* Wgb  = (__hip_bfloat16*)(P4 + 23068672);             // 2,097,152
  __hip_bfloat16* Wlb  = (__hip_bfloat16*)(P4 + 25165824);             // 524,288
  __hip_bfloat16* Wbdb = (__hip_bfloat16*)(P4 + 25690112);             // 262,144
  __hip_bfloat16* G16  = (__hip_bfloat16*)P4;                          // full 50,331,648
  float* Tc   = (float*)(P4 + 0);                                      // 16,777,216
  float* Qe   = (float*)(P4 + 16777216);                               // 16,777,216
  float* Obuf = (float*)(P4 + 33554432);                               // 16,777,216
  // P5 region (50,331,648): early = lwb; then Astk; then S0g (Astk dead)
  char* P5 = base + 109051904;
  float* lwb = (float*)(P5 + 0);                                       // 4,194,304
  __hip_bfloat16* Astk = (__hip_bfloat16*)P5;                          // 50,331,648
  float* S0g = (float*)P5;                                             // 16,777,216
  // P6: persistent small
  char* P6 = base + 159383552;
  float* betp  = (float*)(P6 + 0);                                     // 786,432
  float* decp  = (float*)(P6 + 786432);                                // 262,144
  float* lwcb  = (float*)(P6 + 1048576);                               // 65,536
  float* statb = (float*)(P6 + 1114112);                               // 1,024
  __hip_bfloat16* Wob = (__hip_bfloat16*)(P6 + 1115136);               // 2,097,152
  __hip_bfloat16* ogb = (__hip_bfloat16*)(P6 + 3212288);               // 8,388,608
  double* gnpart = (double*)(base + 170984448);                        // 16,384

  const dim3 blk(256);

  // fused casts (x + all weights + bd pack)
  cast_all<<<dim3(14080), blk, 0, stream>>>(x, Wq, Wk, Wv, Wg, Wl, Wo, Wb, Wa,
                                            xb, Wqb, Wkb, Wvb, Wgb, Wlb, Wob, Wbdb);

  // projections
  gemm_bf16<6><<<dim3(8, 32),  blk, 0, stream>>>(xb, Wqb,  qpack, nullptr, 1024, nullptr);
  gemm_bf16<5><<<dim3(24, 32), blk, 0, stream>>>(xb, Wkb,  KP16,  nullptr, 3072, nullptr);
  gemm_bf16<5><<<dim3(24, 32), blk, 0, stream>>>(xb, Wvb,  VP16,  nullptr, 3072, nullptr);
  gemm_bf16<3><<<dim3(1, 32),  blk, 0, stream>>>(xb, Wbdb, betp,  decp,    128,  nullptr);
  gemm_bf16<4><<<dim3(2, 32),  blk, 0, stream>>>(xb, Wlb,  lwb,   nullptr, 256,  Lp);
  gemm_bf16<7><<<dim3(8, 32),  blk, 0, stream>>>(xb, Wgb,  ogb,   nullptr, 1024, nullptr);

  lwc_mean<<<dim3(64), blk, 0, stream>>>(lwb, lwcb);

  // chunk operators
  gram_phi<<<dim3(1024), blk, 0, stream>>>(KP16, qpack, G16, Astk);
  chunk_solve<<<dim3(1024, 2), blk, 0, stream>>>(G16, KP16, VP16, betp, decp);
  products<<<dim3(1024), blk, 0, stream>>>(Astk, KP16, VP16, qpack, decp,
                                           Tc, Qe, (float*)KP16, (float*)VP16);

  // sequential state scan (256 blocks) + parallel O gemm (+ fused gn partials)
  state_scan<<<dim3(256), blk, 0, stream>>>(Tc, (const float*)KP16, lwcb, S0g);
  o_gemm<<<dim3(1024), blk, 0, stream>>>(Qe, S0g, (const float*)VP16, Obuf, gnpart);

  // group norm + gate
  gn_stats2<<<dim3(1), dim3(64), 0, stream>>>(gnpart, statb);
  gate_kernel<<<dim3((kM * 1024 + 255) / 256), blk, 0, stream>>>(Obuf, ogb, gamma, gbeta,
                                                                 statb, zbf);

  // final projection
  gemm_bf16<0><<<dim3(8, 32), blk, 0, stream>>>(zbf, Wob, out, nullptr, 1024, nullptr);
}